// Round 1
// baseline (7199.472 us; speedup 1.0000x reference)
//
#include <hip/hip_runtime.h>
#include <math.h>

// ============================================================================
// fp32 tiled GEMM: C[M,N] = alpha * (A @ op(B)) [+ bias per col] [ReLU]
// BT=true : op(B)=B^T, B is N x K row-major; BT=false: op(B)=B, B is K x N.
// Batched via blockIdx.z with element strides sA/sB/sC.
// Requires M%128==0, N%128==0, K%16==0, rows 16B-aligned.
// Two-level accumulation (tacc per 16-wide K tile) for low rounding error --
// the top-k ORDER must match the np fp32 reference.
// ============================================================================
template<bool BT, bool RELU>
__global__ __launch_bounds__(256) void gemm_kernel(
    const float* __restrict__ A, int lda, long sA,
    const float* __restrict__ B, int ldb, long sB,
    float* __restrict__ C, int ldc, long sC,
    int K, float alpha, const float* __restrict__ bias)
{
    __shared__ float As[16][132];
    __shared__ float Bs[16][132];
    const int bz = blockIdx.z;
    A += (long)bz * sA; B += (long)bz * sB; C += (long)bz * sC;
    const int m0 = blockIdx.y * 128, n0 = blockIdx.x * 128;
    const int tid = threadIdx.x;
    const int tx = tid & 15, ty = tid >> 4;
    const int ar = tid >> 1, ac = (tid & 1) * 8;   // A/B(NT) tile loader coords

    float acc[8][8];
#pragma unroll
    for (int i = 0; i < 8; i++)
#pragma unroll
        for (int j = 0; j < 8; j++) acc[i][j] = 0.f;

    for (int k0 = 0; k0 < K; k0 += 16) {
        // ---- global loads ----
        const float* ap = A + (long)(m0 + ar) * lda + k0 + ac;
        float4 a0 = *(const float4*)ap;
        float4 a1 = *(const float4*)(ap + 4);
        float4 b0, b1;
        int f0 = 0, f1 = 0;
        if (BT) {
            const float* bp = B + (long)(n0 + ar) * ldb + k0 + ac;
            b0 = *(const float4*)bp;
            b1 = *(const float4*)(bp + 4);
        } else {
            f0 = tid * 2; f1 = f0 + 1;
            b0 = *(const float4*)(B + (long)(k0 + (f0 >> 5)) * ldb + n0 + (f0 & 31) * 4);
            b1 = *(const float4*)(B + (long)(k0 + (f1 >> 5)) * ldb + n0 + (f1 & 31) * 4);
        }
        // ---- LDS stores (transposed for A and NT-B) ----
        As[ac + 0][ar] = a0.x; As[ac + 1][ar] = a0.y; As[ac + 2][ar] = a0.z; As[ac + 3][ar] = a0.w;
        As[ac + 4][ar] = a1.x; As[ac + 5][ar] = a1.y; As[ac + 6][ar] = a1.z; As[ac + 7][ar] = a1.w;
        if (BT) {
            Bs[ac + 0][ar] = b0.x; Bs[ac + 1][ar] = b0.y; Bs[ac + 2][ar] = b0.z; Bs[ac + 3][ar] = b0.w;
            Bs[ac + 4][ar] = b1.x; Bs[ac + 5][ar] = b1.y; Bs[ac + 6][ar] = b1.z; Bs[ac + 7][ar] = b1.w;
        } else {
            *(float4*)&Bs[f0 >> 5][(f0 & 31) * 4] = b0;
            *(float4*)&Bs[f1 >> 5][(f1 & 31) * 4] = b1;
        }
        __syncthreads();
        // ---- compute this K tile into tacc, then fold into acc ----
        float tacc[8][8];
#pragma unroll
        for (int i = 0; i < 8; i++)
#pragma unroll
            for (int j = 0; j < 8; j++) tacc[i][j] = 0.f;
#pragma unroll
        for (int kk = 0; kk < 16; kk++) {
            float af[8], bf[8];
            *(float4*)&af[0] = *(const float4*)&As[kk][ty * 8];
            *(float4*)&af[4] = *(const float4*)&As[kk][ty * 8 + 4];
            *(float4*)&bf[0] = *(const float4*)&Bs[kk][tx * 8];
            *(float4*)&bf[4] = *(const float4*)&Bs[kk][tx * 8 + 4];
#pragma unroll
            for (int i = 0; i < 8; i++)
#pragma unroll
                for (int j = 0; j < 8; j++) tacc[i][j] += af[i] * bf[j];
        }
#pragma unroll
        for (int i = 0; i < 8; i++)
#pragma unroll
            for (int j = 0; j < 8; j++) acc[i][j] += tacc[i][j];
        __syncthreads();
    }
    // ---- epilogue ----
#pragma unroll
    for (int i = 0; i < 8; i++) {
        const long cb = (long)(m0 + ty * 8 + i) * ldc + n0 + tx * 8;
#pragma unroll
        for (int j = 0; j < 8; j++) {
            float v = acc[i][j] * alpha;
            if (bias) v += bias[n0 + tx * 8 + j];
            if (RELU) v = fmaxf(v, 0.f);
            C[cb + j] = v;
        }
    }
}

// ============================================================================
// softmax over rows (in place), matches jax.nn.softmax: exp(x-max)/sum
// ============================================================================
__global__ __launch_bounds__(256) void softmax_kernel(float* __restrict__ x, int cols)
{
    float* row = x + (long)blockIdx.x * cols;
    const int t = threadIdx.x;
    __shared__ float red[256];
    float mx = -INFINITY;
    for (int c = t; c < cols; c += 256) mx = fmaxf(mx, row[c]);
    red[t] = mx; __syncthreads();
    for (int off = 128; off; off >>= 1) { if (t < off) red[t] = fmaxf(red[t], red[t + off]); __syncthreads(); }
    mx = red[0]; __syncthreads();
    float s = 0.f;
    for (int c = t; c < cols; c += 256) { float e = expf(row[c] - mx); row[c] = e; s += e; }
    red[t] = s; __syncthreads();
    for (int off = 128; off; off >>= 1) { if (t < off) red[t] += red[t + off]; __syncthreads(); }
    s = red[0];
    for (int c = t; c < cols; c += 256) row[c] /= s;
}

// ============================================================================
// logits[r] = H[r,:2048] . w2 + b2   (one block per row)
// ============================================================================
__global__ __launch_bounds__(256) void gemv_kernel(
    const float* __restrict__ H, const float* __restrict__ w2,
    const float* __restrict__ b2, float* __restrict__ logits)
{
    const int r = blockIdx.x, t = threadIdx.x;
    const float* row = H + (long)r * 2048;
    float s = 0.f;
    for (int c = t; c < 2048; c += 256) s += row[c] * w2[c];
    __shared__ float red[256];
    red[t] = s; __syncthreads();
    for (int off = 128; off; off >>= 1) { if (t < off) red[t] += red[t + off]; __syncthreads(); }
    if (!t) logits[r] = red[0] + b2[0];
}

// ============================================================================
// exact lax.top_k: bitonic full sort of (val, idx), desc by val, ties idx asc.
// launch with blockDim == n (n is a power of two, <= 1024)
// ============================================================================
__global__ void topk_kernel(const float* __restrict__ vals, int n, int k, int* __restrict__ out)
{
    __shared__ float sv[1024];
    __shared__ int   si[1024];
    const int t = threadIdx.x;
    sv[t] = vals[t]; si[t] = t;
    for (int size = 2; size <= n; size <<= 1) {
        for (int stride = size >> 1; stride > 0; stride >>= 1) {
            __syncthreads();
            const int j = t ^ stride;
            if (j > t) {
                float av = sv[t], bv = sv[j];
                int ai = si[t], bi = si[j];
                const bool before = (av > bv) || (av == bv && ai < bi);
                const bool dir = ((t & size) == 0);
                if (dir ? !before : before) { sv[t] = bv; si[t] = bi; sv[j] = av; si[j] = ai; }
            }
        }
    }
    __syncthreads();
    if (t < k) out[t] = si[t];
}

// sel_idx[i] = idx1[idx2[i]]
__global__ void gather_sel_kernel(const int* __restrict__ idx1, const int* __restrict__ idx2,
                                  int* __restrict__ selidx)
{
    const int t = threadIdx.x;
    if (t < 256) selidx[t] = idx1[idx2[t]];
}

// complement of 256 selected indices within [0,1024), ascending -> remidx[768]
__global__ void complement_kernel(const int* __restrict__ selidx, int* __restrict__ remidx)
{
    __shared__ int mask[1024];
    __shared__ int scan[1024];
    const int t = threadIdx.x;
    mask[t] = 0;
    __syncthreads();
    if (t < 256) mask[selidx[t]] = 1;
    __syncthreads();
    const int keep = 1 - mask[t];
    scan[t] = keep;
    __syncthreads();
    for (int off = 1; off < 1024; off <<= 1) {
        int v = scan[t];
        if (t >= off) v += scan[t - off];
        __syncthreads();
        scan[t] = v;
        __syncthreads();
    }
    if (keep) remidx[scan[t] - 1] = t;
}

// dst[r,:] = src[map[r],:]   (ncols floats, float4 copies)
__global__ __launch_bounds__(256) void gather_rows_kernel(
    float* __restrict__ dst, const float* __restrict__ src,
    const int* __restrict__ map, int ncols)
{
    const int r = blockIdx.x;
    const int sr = map[r];
    const float4* s = (const float4*)(src + (long)sr * ncols);
    float4* d = (float4*)(dst + (long)r * ncols);
    for (int i = threadIdx.x; i < ncols / 4; i += 256) d[i] = s[i];
}

// out[r] = ||x[r,:4096]||_2
__global__ __launch_bounds__(256) void rownorm_kernel(
    const float* __restrict__ x, float* __restrict__ out)
{
    const int r = blockIdx.x, t = threadIdx.x;
    const float* row = x + (long)r * 4096;
    float s = 0.f;
    for (int c = t; c < 4096; c += 256) { float v = row[c]; s += v * v; }
    __shared__ float red[256];
    red[t] = s; __syncthreads();
    for (int off = 128; off; off >>= 1) { if (t < off) red[t] += red[t + off]; __syncthreads(); }
    if (!t) out[r] = sqrtf(red[0]);
}

// best[r] = argmax_j S[r,j]/max(nr[r]*ns[j],1e-8), ties -> lowest j
__global__ __launch_bounds__(256) void argmax_kernel(
    const float* __restrict__ S, const float* __restrict__ nr,
    const float* __restrict__ ns, int* __restrict__ best)
{
    const int r = blockIdx.x, t = threadIdx.x;
    float v = S[(long)r * 256 + t] / fmaxf(nr[r] * ns[t], 1e-8f);
    __shared__ float bv[256];
    __shared__ int bi[256];
    bv[t] = v; bi[t] = t; __syncthreads();
    for (int off = 128; off; off >>= 1) {
        if (t < off) {
            float ov = bv[t + off]; int oi = bi[t + off];
            if (ov > bv[t] || (ov == bv[t] && oi < bi[t])) { bv[t] = ov; bi[t] = oi; }
        }
        __syncthreads();
    }
    if (!t) best[r] = bi[0];
}

// per-cluster merge: one block per cluster j, 256 threads x 16 dims
__global__ __launch_bounds__(256) void merge_kernel(
    const float* __restrict__ selb, const float* __restrict__ rem,
    const int* __restrict__ best, const float* __restrict__ nr,
    const float* __restrict__ ns, float* __restrict__ out)
{
    const int j = blockIdx.x, t = threadIdx.x;
    __shared__ int sbest[768];
    __shared__ float snr[768];
    __shared__ float red[256];
    for (int i = t; i < 768; i += 256) { sbest[i] = best[i]; snr[i] = nr[i]; }
    __syncthreads();
    float acc[16];
#pragma unroll
    for (int d = 0; d < 16; d++) acc[d] = 0.f;
    int cnt = 0; float smax = 0.f;
    const int base = t * 16;
    for (int i = 0; i < 768; i++) {
        if (sbest[i] == j) {
            cnt++;
            smax = fmaxf(smax, snr[i]);
            const float* rp = rem + (long)i * 4096 + base;
#pragma unroll
            for (int d = 0; d < 16; d += 4) {
                float4 x4 = *(const float4*)(rp + d);
                acc[d] += x4.x; acc[d + 1] += x4.y; acc[d + 2] += x4.z; acc[d + 3] += x4.w;
            }
        }
    }
    const float* sp = selb + (long)j * 4096 + base;
    float mean[16]; float ss = 0.f;
    const float denom = (float)(cnt + 1);
#pragma unroll
    for (int d = 0; d < 16; d++) { mean[d] = (sp[d] + acc[d]) / denom; ss += mean[d] * mean[d]; }
    red[t] = ss; __syncthreads();
    for (int off = 128; off; off >>= 1) { if (t < off) red[t] += red[t + off]; __syncthreads(); }
    const float nm = sqrtf(red[0]);
    const float mx = fmaxf(ns[j], cnt > 0 ? smax : 0.f);
    float* op = out + (long)j * 4096 + base;
#pragma unroll
    for (int d = 0; d < 16; d++) op[d] = (cnt > 0) ? (mean[d] / nm) * mx : sp[d];
}

// ============================================================================
// host orchestration
// ============================================================================
extern "C" void kernel_launch(void* const* d_in, const int* in_sizes, int n_in,
                              void* d_out, int out_size, void* d_ws, size_t ws_size,
                              hipStream_t stream)
{
    const float* vf   = (const float*)d_in[0];   // 1024 x 4096
    const float* te   = (const float*)d_in[1];   // 128 x 4096
    const float* inw  = (const float*)d_in[3];   // 4 x 12288 x 4096
    const float* inb  = (const float*)d_in[4];   // 4 x 12288
    const float* outw = (const float*)d_in[5];   // 4 x 4096 x 4096
    const float* outb = (const float*)d_in[6];   // 4 x 4096
    const float* w1   = (const float*)d_in[7];   // 2 x 2048 x 4096
    const float* b1   = (const float*)d_in[8];   // 2 x 2048
    const float* w2   = (const float*)d_in[9];   // 2 x 2048
    const float* b2   = (const float*)d_in[10];  // 2
    float* out = (float*)d_out;                  // 256 x 4096
    float* ws = (float*)d_ws;

    // workspace layout (floats); total 27,795,456 floats = 111.2 MB
    float* comb = ws + 0;               // 1152*4096
    float* qbuf = ws + 4718592;         // 1024*4096   (o aliases q)
    float* kbuf = ws + 8912896;         // 1152*4096   (g aliases k)
    float* vbuf = ws + 13631488;        // 1152*4096   (h aliases v)
    float* scor = ws + 18350080;        // 8*1024*1152 (rem/sel/S alias here)
    float* smalls = ws + 27787264;      // 8192 floats
    float* obuf = qbuf;
    float* gbuf = kbuf;
    float* hbuf = vbuf;
    float* logits = smalls;                     // 1024
    float* nr     = smalls + 1024;              // 768
    float* ns     = smalls + 1792;              // 256
    int* idx1   = (int*)(smalls + 2048);        // 512
    int* idx2   = (int*)(smalls + 2560);        // 256
    int* selidx = (int*)(smalls + 2816);        // 256
    int* remidx = (int*)(smalls + 3072);        // 768
    int* best   = (int*)(smalls + 3840);        // 768
    float* rem  = scor;                         // 768*4096
    float* selb = scor + 3145728;               // 256*4096
    float* Smat = selb + 1048576;               // 768*256

    const float scl = (float)(1.0 / sqrt(512.0));  // 1/sqrt(dh)

    for (int m = 0; m < 2; m++) {
        const int Mq  = m ? 512 : 1024;
        const int Mkv = m ? 640 : 1152;
        const float* qw = inw + (size_t)(2 * m) * 12288 * 4096;
        const float* kw = qw + (size_t)4096 * 4096;
        const float* vw = qw + (size_t)8192 * 4096;
        const float* qb = inb + (size_t)(2 * m) * 12288;
        const float* kb = qb + 4096;
        const float* vb = qb + 8192;
        const float* ow = outw + (size_t)(2 * m) * 4096 * 4096;
        const float* ob = outb + (size_t)(2 * m) * 4096;

        // comb = [x ; te], x = vf (m=0) or vf[idx1] (m=1)
        if (m == 0) {
            hipMemcpyAsync(comb, vf, (size_t)1024 * 4096 * 4, hipMemcpyDeviceToDevice, stream);
            hipMemcpyAsync(comb + (size_t)1024 * 4096, te, (size_t)128 * 4096 * 4,
                           hipMemcpyDeviceToDevice, stream);
        } else {
            gather_rows_kernel<<<512, 256, 0, stream>>>(comb, vf, idx1, 4096);
            hipMemcpyAsync(comb + (size_t)512 * 4096, te, (size_t)128 * 4096 * 4,
                           hipMemcpyDeviceToDevice, stream);
        }
        // q = x @ qw^T + qb        (Mq x 4096)
        gemm_kernel<true, false><<<dim3(32, Mq / 128, 1), 256, 0, stream>>>(
            comb, 4096, 0, qw, 4096, 0, qbuf, 4096, 0, 4096, 1.f, qb);
        // k,v = comb @ {kw,vw}^T   (Mkv x 4096)
        gemm_kernel<true, false><<<dim3(32, Mkv / 128, 1), 256, 0, stream>>>(
            comb, 4096, 0, kw, 4096, 0, kbuf, 4096, 0, 4096, 1.f, kb);
        gemm_kernel<true, false><<<dim3(32, Mkv / 128, 1), 256, 0, stream>>>(
            comb, 4096, 0, vw, 4096, 0, vbuf, 4096, 0, 4096, 1.f, vb);
        // scores[h] = (1/sqrt(512)) * q_h @ k_h^T   (8 x Mq x Mkv)
        gemm_kernel<true, false><<<dim3(Mkv / 128, Mq / 128, 8), 256, 0, stream>>>(
            qbuf, 4096, 512, kbuf, 4096, 512, scor, Mkv, (long)Mq * Mkv, 512, scl, nullptr);
        softmax_kernel<<<8 * Mq, 256, 0, stream>>>(scor, Mkv);
        // o[h] = probs_h @ v_h     (Mq x 512 per head, packed into Mq x 4096)
        gemm_kernel<false, false><<<dim3(4, Mq / 128, 8), 256, 0, stream>>>(
            scor, Mkv, (long)Mq * Mkv, vbuf, 4096, 512, obuf, 4096, 512, Mkv, 1.f, nullptr);
        // g = o @ ow^T + ob
        gemm_kernel<true, false><<<dim3(32, Mq / 128, 1), 256, 0, stream>>>(
            obuf, 4096, 0, ow, 4096, 0, gbuf, 4096, 0, 4096, 1.f, ob);
        // h = relu(g @ w1^T + b1)  (Mq x 2048)
        gemm_kernel<true, true><<<dim3(16, Mq / 128, 1), 256, 0, stream>>>(
            gbuf, 4096, 0, w1 + (size_t)m * 2048 * 4096, 4096, 0, hbuf, 2048, 0,
            4096, 1.f, b1 + (size_t)m * 2048);
        // logits = h . w2 + b2
        gemv_kernel<<<Mq, 256, 0, stream>>>(hbuf, w2 + (size_t)m * 2048, b2 + m, logits);
        // top-k
        if (m == 0) topk_kernel<<<1, 1024, 0, stream>>>(logits, 1024, 512, idx1);
        else        topk_kernel<<<1, 512, 0, stream>>>(logits, 512, 256, idx2);
    }

    gather_sel_kernel<<<1, 256, 0, stream>>>(idx1, idx2, selidx);
    complement_kernel<<<1, 1024, 0, stream>>>(selidx, remidx);
    gather_rows_kernel<<<768, 256, 0, stream>>>(rem, vf, remidx, 4096);
    gather_rows_kernel<<<256, 256, 0, stream>>>(selb, vf, selidx, 4096);
    rownorm_kernel<<<768, 256, 0, stream>>>(rem, nr);
    rownorm_kernel<<<256, 256, 0, stream>>>(selb, ns);
    // S = rem @ selb^T  (768 x 256)
    gemm_kernel<true, false><<<dim3(2, 6, 1), 256, 0, stream>>>(
        rem, 4096, 0, selb, 4096, 0, Smat, 256, 0, 4096, 1.f, nullptr);
    argmax_kernel<<<768, 256, 0, stream>>>(Smat, nr, ns, best);
    merge_kernel<<<256, 256, 0, stream>>>(selb, rem, best, nr, ns, out);
}

// Round 2
// 4294.802 us; speedup vs baseline: 1.6763x; 1.6763x over previous
//
#include <hip/hip_runtime.h>
#include <hip/hip_bf16.h>
#include <math.h>

typedef __attribute__((ext_vector_type(4))) float f32x4;
typedef __attribute__((ext_vector_type(8))) short s16x8;
typedef __attribute__((ext_vector_type(4))) short s16x4;

// ---------------------------------------------------------------------------
// fp32 -> bf16 hi/lo split (RTNE both; residual subtraction is exact in fp32)
// ---------------------------------------------------------------------------
__device__ __forceinline__ void splitf(float x, short& hi, short& lo)
{
    unsigned u = __float_as_uint(x);
    unsigned r = (u + 0x7fffu + ((u >> 16) & 1u)) & 0xffff0000u;
    hi = (short)(r >> 16);
    float res = x - __uint_as_float(r);
    unsigned u2 = __float_as_uint(res);
    unsigned r2 = u2 + 0x7fffu + ((u2 >> 16) & 1u);
    lo = (short)(r2 >> 16);
}

__device__ __forceinline__ void split4(float a, float b, float c, float d,
                                       s16x4& hi, s16x4& lo)
{
    short h0,h1,h2,h3,l0,l1,l2,l3;
    splitf(a,h0,l0); splitf(b,h1,l1); splitf(c,h2,l2); splitf(d,h3,l3);
    hi = (s16x4){h0,h1,h2,h3};
    lo = (s16x4){l0,l1,l2,l3};
}

// swizzled short-index: tile is [128 rows][32 cols] bf16, rows of 4 chunks of
// 8; chunk' = chunk ^ ((row>>1)&3) spreads frag reads across all bank groups.
__device__ __forceinline__ int swz4(int row, int cf)
{
    return row * 32 + ((((cf >> 3) ^ ((row >> 1) & 3)) << 3) + ((cf >> 2) & 1) * 4);
}

// ============================================================================
// split-bf16 MFMA GEMM: C[M,N] = alpha*(A @ op(B)) [+bias] [ReLU]
// BT: op(B)=B^T (B is N x K). A,B,C fp32 in global. M%128==0, N%128==0,
// K%32==0, 16B-aligned rows. Batched via blockIdx.z (element strides).
// 3 MFMAs per logical fp32 product: hi*hi + hi*lo + lo*hi (fp32 acc).
// ============================================================================
template<bool BT, bool RELU>
__global__ __launch_bounds__(256, 2) void mfma_gemm(
    const float* __restrict__ A, int lda, long sA,
    const float* __restrict__ B, int ldb, long sB,
    float* __restrict__ C, int ldc, long sC,
    int K, float alpha, const float* __restrict__ bias)
{
    __shared__ short Ah[128 * 32], Al[128 * 32], Bh[128 * 32], Bl[128 * 32];
    const int bz = blockIdx.z;
    A += (long)bz * sA; B += (long)bz * sB; C += (long)bz * sC;
    const int m0 = blockIdx.y * 128, n0 = blockIdx.x * 128;
    const int tid = threadIdx.x;
    const int lane = tid & 63, wave = tid >> 6;
    const int wr = (wave >> 1) * 64, wc = (wave & 1) * 64;
    const int lrow = lane & 15, lk = lane >> 4;
    // frag-read chunk swizzle is lane-constant: (row>>1)&3 == (lrow>>1)&3
    const int cswz8 = (lk ^ ((lrow >> 1) & 3)) << 3;

    const int sr = tid >> 3, scf = (tid & 7) * 4;       // BT staging coords
    const int nk4 = (tid & 7) * 4, nnf = (tid >> 3) * 4; // NT-B staging coords

    f32x4 acc[4][4];
#pragma unroll
    for (int i = 0; i < 4; i++)
#pragma unroll
        for (int j = 0; j < 4; j++) acc[i][j] = (f32x4){0.f, 0.f, 0.f, 0.f};

    for (int k0 = 0; k0 < K; k0 += 32) {
        // ---- stage A (rows sr+32i, fp32 cols scf..scf+3) ----
#pragma unroll
        for (int i = 0; i < 4; i++) {
            const int row = sr + 32 * i;
            float4 f = *(const float4*)(A + (long)(m0 + row) * lda + k0 + scf);
            s16x4 hi, lo; split4(f.x, f.y, f.z, f.w, hi, lo);
            const int idx = swz4(row, scf);
            *(s16x4*)&Ah[idx] = hi;
            *(s16x4*)&Al[idx] = lo;
        }
        // ---- stage B ----
        if (BT) {
#pragma unroll
            for (int i = 0; i < 4; i++) {
                const int row = sr + 32 * i;
                float4 f = *(const float4*)(B + (long)(n0 + row) * ldb + k0 + scf);
                s16x4 hi, lo; split4(f.x, f.y, f.z, f.w, hi, lo);
                const int idx = swz4(row, scf);
                *(s16x4*)&Bh[idx] = hi;
                *(s16x4*)&Bl[idx] = lo;
            }
        } else {
            // B is K x N: load 4x4 block [nk4..+3][nnf..+3], transpose in regs
            float4 rb[4];
#pragma unroll
            for (int i = 0; i < 4; i++)
                rb[i] = *(const float4*)(B + (long)(k0 + nk4 + i) * ldb + n0 + nnf);
#pragma unroll
            for (int jn = 0; jn < 4; jn++) {
                const int row = nnf + jn;
                const float x0 = ((const float*)&rb[0])[jn];
                const float x1 = ((const float*)&rb[1])[jn];
                const float x2 = ((const float*)&rb[2])[jn];
                const float x3 = ((const float*)&rb[3])[jn];
                s16x4 hi, lo; split4(x0, x1, x2, x3, hi, lo);
                const int idx = swz4(row, nk4);
                *(s16x4*)&Bh[idx] = hi;
                *(s16x4*)&Bl[idx] = lo;
            }
        }
        __syncthreads();
        // ---- MFMA phase: 4x4 frags x {hihi, hilo, lohi} ----
        s16x8 ah[4], al[4];
#pragma unroll
        for (int m = 0; m < 4; m++) {
            const int idx = (wr + m * 16 + lrow) * 32 + cswz8;
            ah[m] = *(const s16x8*)&Ah[idx];
            al[m] = *(const s16x8*)&Al[idx];
        }
#pragma unroll
        for (int n = 0; n < 4; n++) {
            const int idx = (wc + n * 16 + lrow) * 32 + cswz8;
            const s16x8 bh = *(const s16x8*)&Bh[idx];
            const s16x8 bl = *(const s16x8*)&Bl[idx];
#pragma unroll
            for (int m = 0; m < 4; m++) {
                acc[m][n] = __builtin_amdgcn_mfma_f32_16x16x32_bf16(ah[m], bh, acc[m][n], 0, 0, 0);
                acc[m][n] = __builtin_amdgcn_mfma_f32_16x16x32_bf16(ah[m], bl, acc[m][n], 0, 0, 0);
                acc[m][n] = __builtin_amdgcn_mfma_f32_16x16x32_bf16(al[m], bh, acc[m][n], 0, 0, 0);
            }
        }
        __syncthreads();
    }
    // ---- epilogue: C/D layout col=lane&15, row=(lane>>4)*4+r ----
#pragma unroll
    for (int n = 0; n < 4; n++) {
        const int col = n0 + wc + n * 16 + lrow;
        const float bv = bias ? bias[col] : 0.f;
#pragma unroll
        for (int m = 0; m < 4; m++) {
            const int row = m0 + wr + m * 16 + lk * 4;
#pragma unroll
            for (int r = 0; r < 4; r++) {
                float v = acc[m][n][r] * alpha + bv;
                if (RELU) v = fmaxf(v, 0.f);
                C[(long)(row + r) * ldc + col] = v;
            }
        }
    }
}

// ============================================================================
// softmax over rows (in place), matches jax.nn.softmax: exp(x-max)/sum
// ============================================================================
__global__ __launch_bounds__(256) void softmax_kernel(float* __restrict__ x, int cols)
{
    float* row = x + (long)blockIdx.x * cols;
    const int t = threadIdx.x;
    __shared__ float red[256];
    float mx = -INFINITY;
    for (int c = t; c < cols; c += 256) mx = fmaxf(mx, row[c]);
    red[t] = mx; __syncthreads();
    for (int off = 128; off; off >>= 1) { if (t < off) red[t] = fmaxf(red[t], red[t + off]); __syncthreads(); }
    mx = red[0]; __syncthreads();
    float s = 0.f;
    for (int c = t; c < cols; c += 256) { float e = expf(row[c] - mx); row[c] = e; s += e; }
    red[t] = s; __syncthreads();
    for (int off = 128; off; off >>= 1) { if (t < off) red[t] += red[t + off]; __syncthreads(); }
    s = red[0];
    for (int c = t; c < cols; c += 256) row[c] /= s;
}

// logits[r] = H[r,:2048] . w2 + b2
__global__ __launch_bounds__(256) void gemv_kernel(
    const float* __restrict__ H, const float* __restrict__ w2,
    const float* __restrict__ b2, float* __restrict__ logits)
{
    const int r = blockIdx.x, t = threadIdx.x;
    const float* row = H + (long)r * 2048;
    float s = 0.f;
    for (int c = t; c < 2048; c += 256) s += row[c] * w2[c];
    __shared__ float red[256];
    red[t] = s; __syncthreads();
    for (int off = 128; off; off >>= 1) { if (t < off) red[t] += red[t + off]; __syncthreads(); }
    if (!t) logits[r] = red[0] + b2[0];
}

// exact lax.top_k: bitonic full sort, desc by val, ties idx asc. blockDim==n.
__global__ void topk_kernel(const float* __restrict__ vals, int n, int k, int* __restrict__ out)
{
    __shared__ float sv[1024];
    __shared__ int   si[1024];
    const int t = threadIdx.x;
    sv[t] = vals[t]; si[t] = t;
    for (int size = 2; size <= n; size <<= 1) {
        for (int stride = size >> 1; stride > 0; stride >>= 1) {
            __syncthreads();
            const int j = t ^ stride;
            if (j > t) {
                float av = sv[t], bv = sv[j];
                int ai = si[t], bi = si[j];
                const bool before = (av > bv) || (av == bv && ai < bi);
                const bool dir = ((t & size) == 0);
                if (dir ? !before : before) { sv[t] = bv; si[t] = bi; sv[j] = av; si[j] = ai; }
            }
        }
    }
    __syncthreads();
    if (t < k) out[t] = si[t];
}

__global__ void gather_sel_kernel(const int* __restrict__ idx1, const int* __restrict__ idx2,
                                  int* __restrict__ selidx)
{
    const int t = threadIdx.x;
    if (t < 256) selidx[t] = idx1[idx2[t]];
}

// complement of 256 selected indices within [0,1024), ascending
__global__ void complement_kernel(const int* __restrict__ selidx, int* __restrict__ remidx)
{
    __shared__ int mask[1024];
    __shared__ int scan[1024];
    const int t = threadIdx.x;
    mask[t] = 0;
    __syncthreads();
    if (t < 256) mask[selidx[t]] = 1;
    __syncthreads();
    const int keep = 1 - mask[t];
    scan[t] = keep;
    __syncthreads();
    for (int off = 1; off < 1024; off <<= 1) {
        int v = scan[t];
        if (t >= off) v += scan[t - off];
        __syncthreads();
        scan[t] = v;
        __syncthreads();
    }
    if (keep) remidx[scan[t] - 1] = t;
}

__global__ __launch_bounds__(256) void gather_rows_kernel(
    float* __restrict__ dst, const float* __restrict__ src,
    const int* __restrict__ map, int ncols)
{
    const int r = blockIdx.x;
    const int sr = map[r];
    const float4* s = (const float4*)(src + (long)sr * ncols);
    float4* d = (float4*)(dst + (long)r * ncols);
    for (int i = threadIdx.x; i < ncols / 4; i += 256) d[i] = s[i];
}

__global__ __launch_bounds__(256) void rownorm_kernel(
    const float* __restrict__ x, float* __restrict__ out)
{
    const int r = blockIdx.x, t = threadIdx.x;
    const float* row = x + (long)r * 4096;
    float s = 0.f;
    for (int c = t; c < 4096; c += 256) { float v = row[c]; s += v * v; }
    __shared__ float red[256];
    red[t] = s; __syncthreads();
    for (int off = 128; off; off >>= 1) { if (t < off) red[t] += red[t + off]; __syncthreads(); }
    if (!t) out[r] = sqrtf(red[0]);
}

__global__ __launch_bounds__(256) void argmax_kernel(
    const float* __restrict__ S, const float* __restrict__ nr,
    const float* __restrict__ ns, int* __restrict__ best)
{
    const int r = blockIdx.x, t = threadIdx.x;
    float v = S[(long)r * 256 + t] / fmaxf(nr[r] * ns[t], 1e-8f);
    __shared__ float bv[256];
    __shared__ int bi[256];
    bv[t] = v; bi[t] = t; __syncthreads();
    for (int off = 128; off; off >>= 1) {
        if (t < off) {
            float ov = bv[t + off]; int oi = bi[t + off];
            if (ov > bv[t] || (ov == bv[t] && oi < bi[t])) { bv[t] = ov; bi[t] = oi; }
        }
        __syncthreads();
    }
    if (!t) best[r] = bi[0];
}

__global__ __launch_bounds__(256) void merge_kernel(
    const float* __restrict__ selb, const float* __restrict__ rem,
    const int* __restrict__ best, const float* __restrict__ nr,
    const float* __restrict__ ns, float* __restrict__ out)
{
    const int j = blockIdx.x, t = threadIdx.x;
    __shared__ int sbest[768];
    __shared__ float snr[768];
    __shared__ float red[256];
    for (int i = t; i < 768; i += 256) { sbest[i] = best[i]; snr[i] = nr[i]; }
    __syncthreads();
    float acc[16];
#pragma unroll
    for (int d = 0; d < 16; d++) acc[d] = 0.f;
    int cnt = 0; float smax = 0.f;
    const int base = t * 16;
    for (int i = 0; i < 768; i++) {
        if (sbest[i] == j) {
            cnt++;
            smax = fmaxf(smax, snr[i]);
            const float* rp = rem + (long)i * 4096 + base;
#pragma unroll
            for (int d = 0; d < 16; d += 4) {
                float4 x4 = *(const float4*)(rp + d);
                acc[d] += x4.x; acc[d + 1] += x4.y; acc[d + 2] += x4.z; acc[d + 3] += x4.w;
            }
        }
    }
    const float* sp = selb + (long)j * 4096 + base;
    float mean[16]; float ss = 0.f;
    const float denom = (float)(cnt + 1);
#pragma unroll
    for (int d = 0; d < 16; d++) { mean[d] = (sp[d] + acc[d]) / denom; ss += mean[d] * mean[d]; }
    red[t] = ss; __syncthreads();
    for (int off = 128; off; off >>= 1) { if (t < off) red[t] += red[t + off]; __syncthreads(); }
    const float nm = sqrtf(red[0]);
    const float mx = fmaxf(ns[j], cnt > 0 ? smax : 0.f);
    float* op = out + (long)j * 4096 + base;
#pragma unroll
    for (int d = 0; d < 16; d++) op[d] = (cnt > 0) ? (mean[d] / nm) * mx : sp[d];
}

// ============================================================================
// host orchestration
// ============================================================================
extern "C" void kernel_launch(void* const* d_in, const int* in_sizes, int n_in,
                              void* d_out, int out_size, void* d_ws, size_t ws_size,
                              hipStream_t stream)
{
    const float* vf   = (const float*)d_in[0];   // 1024 x 4096
    const float* te   = (const float*)d_in[1];   // 128 x 4096
    const float* inw  = (const float*)d_in[3];   // 4 x 12288 x 4096
    const float* inb  = (const float*)d_in[4];   // 4 x 12288
    const float* outw = (const float*)d_in[5];   // 4 x 4096 x 4096
    const float* outb = (const float*)d_in[6];   // 4 x 4096
    const float* w1   = (const float*)d_in[7];   // 2 x 2048 x 4096
    const float* b1   = (const float*)d_in[8];   // 2 x 2048
    const float* w2   = (const float*)d_in[9];   // 2 x 2048
    const float* b2   = (const float*)d_in[10];  // 2
    float* out = (float*)d_out;                  // 256 x 4096
    float* ws = (float*)d_ws;

    // workspace layout (floats), total 27,787,264 = 111.1 MB (round-1 proven)
    // region 0 [0, 4194304): comb (m1, 640x4096) / obuf (1024x4096)
    // region 1 [4194304, 18350080): qkv (1152x12288) / gbuf
    // region 2 [18350080, 27787264): scores / hbuf / rem+selb+Smat; smalls top
    float* comb = ws;
    float* obuf = ws;
    float* qkv  = ws + 4194304;
    float* gbuf = qkv;
    float* scor = ws + 18350080;
    float* hbuf = scor;
    float* rem  = scor;                          // 768*4096 = 3,145,728
    float* selb = scor + 3145728;                // 256*4096 = 1,048,576
    float* Smat = scor + 4194304;                // 768*256  =   196,608
    float* smalls = ws + 27787264 - 8192;        // top 8192 floats of region 2
    float* logits = smalls;                      // 1024
    float* nr     = smalls + 1024;               // 768
    float* ns     = smalls + 1792;               // 256
    int* idx1   = (int*)(smalls + 2048);         // 512
    int* idx2   = (int*)(smalls + 2560);         // 256
    int* selidx = (int*)(smalls + 2816);         // 256
    int* remidx = (int*)(smalls + 3072);         // 768
    int* best   = (int*)(smalls + 3840);         // 768

    const float scl = (float)(1.0 / sqrt(512.0));  // 1/sqrt(dh)

    for (int m = 0; m < 2; m++) {
        const int Mq  = m ? 512 : 1024;
        const int Mkv = m ? 640 : 1152;
        const float* Wqkv = inw + (size_t)(2 * m) * 12288 * 4096;
        const float* bqkv = inb + (size_t)(2 * m) * 12288;
        const float* ow = outw + (size_t)(2 * m) * 4096 * 4096;
        const float* ob = outb + (size_t)(2 * m) * 4096;

        // fused in-proj: qkv[:, 0:4096]=q, [4096:8192]=k, [8192:12288]=v
        if (m == 0) {
            mfma_gemm<true, false><<<dim3(96, 8, 1), 256, 0, stream>>>(
                vf, 4096, 0, Wqkv, 4096, 0, qkv, 12288, 0, 4096, 1.f, bqkv);
            mfma_gemm<true, false><<<dim3(96, 1, 1), 256, 0, stream>>>(
                te, 4096, 0, Wqkv, 4096, 0, qkv + (size_t)1024 * 12288, 12288, 0,
                4096, 1.f, bqkv);
        } else {
            gather_rows_kernel<<<512, 256, 0, stream>>>(comb, vf, idx1, 4096);
            hipMemcpyAsync(comb + (size_t)512 * 4096, te, (size_t)128 * 4096 * 4,
                           hipMemcpyDeviceToDevice, stream);
            mfma_gemm<true, false><<<dim3(96, 5, 1), 256, 0, stream>>>(
                comb, 4096, 0, Wqkv, 4096, 0, qkv, 12288, 0, 4096, 1.f, bqkv);
        }
        // scores[h] = scl * q_h @ k_h^T   (8 x Mq x Mkv)
        mfma_gemm<true, false><<<dim3(Mkv / 128, Mq / 128, 8), 256, 0, stream>>>(
            qkv, 12288, 512, qkv + 4096, 12288, 512, scor, Mkv, (long)Mq * Mkv,
            512, scl, nullptr);
        softmax_kernel<<<8 * Mq, 256, 0, stream>>>(scor, Mkv);
        // o[h] = probs_h @ v_h   (Mq x 512 per head, packed into Mq x 4096)
        mfma_gemm<false, false><<<dim3(4, Mq / 128, 8), 256, 0, stream>>>(
            scor, Mkv, (long)Mq * Mkv, qkv + 8192, 12288, 512, obuf, 4096, 512,
            Mkv, 1.f, nullptr);
        // g = o @ ow^T + ob
        mfma_gemm<true, false><<<dim3(32, Mq / 128, 1), 256, 0, stream>>>(
            obuf, 4096, 0, ow, 4096, 0, gbuf, 4096, 0, 4096, 1.f, ob);
        // h = relu(g @ w1^T + b1)
        mfma_gemm<true, true><<<dim3(16, Mq / 128, 1), 256, 0, stream>>>(
            gbuf, 4096, 0, w1 + (size_t)m * 2048 * 4096, 4096, 0, hbuf, 2048, 0,
            4096, 1.f, b1 + (size_t)m * 2048);
        gemv_kernel<<<Mq, 256, 0, stream>>>(hbuf, w2 + (size_t)m * 2048, b2 + m, logits);
        if (m == 0) topk_kernel<<<1, 1024, 0, stream>>>(logits, 1024, 512, idx1);
        else        topk_kernel<<<1, 512, 0, stream>>>(logits, 512, 256, idx2);
    }

    gather_sel_kernel<<<1, 256, 0, stream>>>(idx1, idx2, selidx);
    complement_kernel<<<1, 1024, 0, stream>>>(selidx, remidx);
    gather_rows_kernel<<<768, 256, 0, stream>>>(rem, vf, remidx, 4096);
    gather_rows_kernel<<<256, 256, 0, stream>>>(selb, vf, selidx, 4096);
    rownorm_kernel<<<768, 256, 0, stream>>>(rem, nr);
    rownorm_kernel<<<256, 256, 0, stream>>>(selb, ns);
    // S = rem @ selb^T  (768 x 256)
    mfma_gemm<true, false><<<dim3(2, 6, 1), 256, 0, stream>>>(
        rem, 4096, 0, selb, 4096, 0, Smat, 256, 0, 4096, 1.f, nullptr);
    argmax_kernel<<<768, 256, 0, stream>>>(Smat, nr, ns, best);
    merge_kernel<<<256, 256, 0, stream>>>(selb, rem, best, nr, ns, out);
}

// Round 4
// 2632.641 us; speedup vs baseline: 2.7347x; 1.6314x over previous
//
#include <hip/hip_runtime.h>
#include <hip/hip_bf16.h>
#include <math.h>

typedef __attribute__((ext_vector_type(4))) float f32x4;
typedef __attribute__((ext_vector_type(8))) short s16x8;
typedef __attribute__((ext_vector_type(4))) short s16x4;

struct sh2 { short hi, lo; };

// ---------------------------------------------------------------------------
// fp32 -> bf16 hi/lo split. hi = bf16(x) (RNE), lo = bf16(x - hi).
// ---------------------------------------------------------------------------
__device__ __forceinline__ sh2 splitf(float x)
{
    __hip_bfloat16 h = __float2bfloat16(x);
    float hf = __bfloat162float(h);
    __hip_bfloat16 l = __float2bfloat16(x - hf);
    sh2 r;
    r.hi = __builtin_bit_cast(short, h);
    r.lo = __builtin_bit_cast(short, l);
    return r;
}

// ============================================================================
// split-bf16 MFMA GEMM: C = alpha*(A @ B^T) [+bias] [ReLU]
// A is pre-split (Ahi/Alo bf16, row-major M x K, ld in elements).
// BF=0: B = fp32 weights (N x K), split inline.  BF=1: B pre-split (N x K).
// EPI=0: write fp32 C [RELU].  EPI=1: write split C (Chi/Clo).
// EPI=2: in-proj mode: cols <8192 -> split to Chi/Clo (ldc); cols >=8192 ->
//        split TRANSPOSED to Thi/Tlo (vT, ld ldT) for the PV GEMM.
// M%128==0, N%128==0, K%32==0. Batched via blockIdx.z (element strides).
// 3 MFMAs per product: hi*hi + hi*lo + lo*hi (fp32 acc).
// ============================================================================
template<int BF, int EPI, bool RELU>
__global__ __launch_bounds__(256, 2) void mfma_gemm(
    const short* __restrict__ Ahi, const short* __restrict__ Alo, int lda, long sA,
    const float* __restrict__ Bf, const short* __restrict__ Bhi,
    const short* __restrict__ Blo, int ldb, long sB,
    float* __restrict__ Cf, short* __restrict__ Chi, short* __restrict__ Clo,
    short* __restrict__ Thi, short* __restrict__ Tlo, int ldc, int ldT, long sC,
    int K, float alpha, const float* __restrict__ bias)
{
    __shared__ short AhS[4096], AlS[4096], BhS[4096], BlS[4096];
    const int bz = blockIdx.z;
    Ahi += (long)bz * sA; Alo += (long)bz * sA;
    if (BF == 0) Bf += (long)bz * sB; else { Bhi += (long)bz * sB; Blo += (long)bz * sB; }
    const long cofs = (long)bz * sC;
    const int m0 = blockIdx.y * 128, n0 = blockIdx.x * 128;
    const int tid = threadIdx.x;
    const int lane = tid & 63, wave = tid >> 6;
    const int wr = (wave >> 1) * 64, wc = (wave & 1) * 64;
    const int lrow = lane & 15, lk = lane >> 4;
    const int cswz8 = (lk ^ ((lrow >> 1) & 3)) << 3;   // frag-read chunk swizzle

    f32x4 acc[4][4];
#pragma unroll
    for (int i = 0; i < 4; i++)
#pragma unroll
        for (int j = 0; j < 4; j++) acc[i][j] = (f32x4){0.f, 0.f, 0.f, 0.f};

    for (int k0 = 0; k0 < K; k0 += 32) {
        // ---- stage A (pre-split): 2 x 8-wide chunks per thread ----
        {
            int c = tid;
#pragma unroll
            for (int i = 0; i < 2; i++, c += 256) {
                const int row = c & 127, kc = (c >> 7) * 8;
                const long g = (long)(m0 + row) * lda + k0 + kc;
                s16x8 h = *(const s16x8*)(Ahi + g);
                s16x8 l = *(const s16x8*)(Alo + g);
                const int widx = row * 32 + (((kc >> 3) ^ ((row >> 1) & 3)) << 3);
                *(s16x8*)&AhS[widx] = h;
                *(s16x8*)&AlS[widx] = l;
            }
        }
        // ---- stage B ----
        if constexpr (BF == 1) {
            int c = tid;
#pragma unroll
            for (int i = 0; i < 2; i++, c += 256) {
                const int row = c & 127, kc = (c >> 7) * 8;
                const long g = (long)(n0 + row) * ldb + k0 + kc;
                s16x8 h = *(const s16x8*)(Bhi + g);
                s16x8 l = *(const s16x8*)(Blo + g);
                const int widx = row * 32 + (((kc >> 3) ^ ((row >> 1) & 3)) << 3);
                *(s16x8*)&BhS[widx] = h;
                *(s16x8*)&BlS[widx] = l;
            }
        } else {
            int c = tid;
#pragma unroll
            for (int i = 0; i < 2; i++, c += 256) {
                const int row = c & 127, kc = (c >> 7) * 8;
                const float* bp = Bf + (long)(n0 + row) * ldb + k0 + kc;
                float4 f0 = *(const float4*)bp;
                float4 f1 = *(const float4*)(bp + 4);
                s16x8 h, l;
                sh2 p;
                p = splitf(f0.x); h[0] = p.hi; l[0] = p.lo;
                p = splitf(f0.y); h[1] = p.hi; l[1] = p.lo;
                p = splitf(f0.z); h[2] = p.hi; l[2] = p.lo;
                p = splitf(f0.w); h[3] = p.hi; l[3] = p.lo;
                p = splitf(f1.x); h[4] = p.hi; l[4] = p.lo;
                p = splitf(f1.y); h[5] = p.hi; l[5] = p.lo;
                p = splitf(f1.z); h[6] = p.hi; l[6] = p.lo;
                p = splitf(f1.w); h[7] = p.hi; l[7] = p.lo;
                const int widx = row * 32 + (((kc >> 3) ^ ((row >> 1) & 3)) << 3);
                *(s16x8*)&BhS[widx] = h;
                *(s16x8*)&BlS[widx] = l;
            }
        }
        __syncthreads();
        // ---- MFMA: 4x4 frags x {hihi, hilo, lohi} ----
        s16x8 ah[4], al[4];
#pragma unroll
        for (int m = 0; m < 4; m++) {
            const int idx = (wr + m * 16 + lrow) * 32 + cswz8;
            ah[m] = *(const s16x8*)&AhS[idx];
            al[m] = *(const s16x8*)&AlS[idx];
        }
#pragma unroll
        for (int n = 0; n < 4; n++) {
            const int idx = (wc + n * 16 + lrow) * 32 + cswz8;
            const s16x8 bh = *(const s16x8*)&BhS[idx];
            const s16x8 bl = *(const s16x8*)&BlS[idx];
#pragma unroll
            for (int m = 0; m < 4; m++) {
                acc[m][n] = __builtin_amdgcn_mfma_f32_16x16x32_bf16(ah[m], bh, acc[m][n], 0, 0, 0);
                acc[m][n] = __builtin_amdgcn_mfma_f32_16x16x32_bf16(ah[m], bl, acc[m][n], 0, 0, 0);
                acc[m][n] = __builtin_amdgcn_mfma_f32_16x16x32_bf16(al[m], bh, acc[m][n], 0, 0, 0);
            }
        }
        __syncthreads();
    }
    // ---- epilogue: C/D layout col=lane&15, row=(lane>>4)*4+r ----
#pragma unroll
    for (int n = 0; n < 4; n++) {
        const int col = n0 + wc + n * 16 + lrow;
        const float bv = bias ? bias[col] : 0.f;
#pragma unroll
        for (int m = 0; m < 4; m++) {
            const int row = m0 + wr + m * 16 + lk * 4;
            if constexpr (EPI == 0) {
#pragma unroll
                for (int r = 0; r < 4; r++) {
                    float v = acc[m][n][r] * alpha + bv;
                    if (RELU) v = fmaxf(v, 0.f);
                    Cf[cofs + (long)(row + r) * ldc + col] = v;
                }
            } else if constexpr (EPI == 1) {
#pragma unroll
                for (int r = 0; r < 4; r++) {
                    float v = acc[m][n][r] * alpha + bv;
                    sh2 p = splitf(v);
                    Chi[cofs + (long)(row + r) * ldc + col] = p.hi;
                    Clo[cofs + (long)(row + r) * ldc + col] = p.lo;
                }
            } else {
                if (n0 < 8192) {
#pragma unroll
                    for (int r = 0; r < 4; r++) {
                        float v = acc[m][n][r] + bv;
                        sh2 p = splitf(v);
                        Chi[(long)(row + r) * ldc + col] = p.hi;
                        Clo[(long)(row + r) * ldc + col] = p.lo;
                    }
                } else {
                    s16x4 h4, l4;
#pragma unroll
                    for (int r = 0; r < 4; r++) {
                        float v = acc[m][n][r] + bv;
                        sh2 p = splitf(v);
                        h4[r] = p.hi; l4[r] = p.lo;
                    }
                    const long tof = (long)(col - 8192) * ldT + row;
                    *(s16x4*)&Thi[tof] = h4;
                    *(s16x4*)&Tlo[tof] = l4;
                }
            }
        }
    }
}

// ============================================================================
// split rows: dhi/dlo[r,:4096] = split(src[map? map[r] : r, :4096])
// ============================================================================
__global__ __launch_bounds__(256) void split_rows(
    const float* __restrict__ src, const int* __restrict__ map,
    short* __restrict__ dhi, short* __restrict__ dlo)
{
    const int r = blockIdx.x;
    const int sr = map ? map[r] : r;
    const float4* s = (const float4*)(src + (long)sr * 4096);
    const long db = (long)r * 4096;
    for (int i = threadIdx.x; i < 1024; i += 256) {
        float4 f = s[i];
        s16x4 h, l;
        sh2 p;
        p = splitf(f.x); h[0] = p.hi; l[0] = p.lo;
        p = splitf(f.y); h[1] = p.hi; l[1] = p.lo;
        p = splitf(f.z); h[2] = p.hi; l[2] = p.lo;
        p = splitf(f.w); h[3] = p.hi; l[3] = p.lo;
        *(s16x4*)&dhi[db + i * 4] = h;
        *(s16x4*)&dlo[db + i * 4] = l;
    }
}

// ============================================================================
// row softmax (jax.nn.softmax: exp(x-max)/sum, exact div) -> split probs
// cols <= 2048, cols % 4 == 0
// ============================================================================
__global__ __launch_bounds__(256) void softmax_split(
    const float* __restrict__ x, short* __restrict__ phi, short* __restrict__ plo,
    int cols)
{
    const long rb = (long)blockIdx.x * cols;
    const float4* xr = (const float4*)(x + rb);
    const int t = threadIdx.x;
    const int n4 = cols >> 2;
    __shared__ float red[256];
    float mx = -INFINITY;
    for (int i = t; i < n4; i += 256) {
        float4 f = xr[i];
        mx = fmaxf(fmaxf(mx, fmaxf(f.x, f.y)), fmaxf(f.z, f.w));
    }
    red[t] = mx; __syncthreads();
    for (int off = 128; off; off >>= 1) { if (t < off) red[t] = fmaxf(red[t], red[t + off]); __syncthreads(); }
    mx = red[0]; __syncthreads();
    float4 ebuf[2];
    float s = 0.f;
    int nb = 0;
    for (int i = t; i < n4; i += 256) {
        float4 f = xr[i];
        f.x = expf(f.x - mx); f.y = expf(f.y - mx); f.z = expf(f.z - mx); f.w = expf(f.w - mx);
        ebuf[nb++] = f;
        s += f.x + f.y + f.z + f.w;
    }
    red[t] = s; __syncthreads();
    for (int off = 128; off; off >>= 1) { if (t < off) red[t] += red[t + off]; __syncthreads(); }
    s = red[0];
    nb = 0;
    for (int i = t; i < n4; i += 256) {
        float4 f = ebuf[nb++];
        f.x /= s; f.y /= s; f.z /= s; f.w /= s;
        s16x4 h, l;
        sh2 p;
        p = splitf(f.x); h[0] = p.hi; l[0] = p.lo;
        p = splitf(f.y); h[1] = p.hi; l[1] = p.lo;
        p = splitf(f.z); h[2] = p.hi; l[2] = p.lo;
        p = splitf(f.w); h[3] = p.hi; l[3] = p.lo;
        *(s16x4*)&phi[rb + i * 4] = h;
        *(s16x4*)&plo[rb + i * 4] = l;
    }
}

// logits[r] = H[r,:2048] . w2 + b2
__global__ __launch_bounds__(256) void gemv_kernel(
    const float* __restrict__ H, const float* __restrict__ w2,
    const float* __restrict__ b2, float* __restrict__ logits)
{
    const int r = blockIdx.x, t = threadIdx.x;
    const float* row = H + (long)r * 2048;
    float s = 0.f;
    for (int c = t; c < 2048; c += 256) s += row[c] * w2[c];
    __shared__ float red[256];
    red[t] = s; __syncthreads();
    for (int off = 128; off; off >>= 1) { if (t < off) red[t] += red[t + off]; __syncthreads(); }
    if (!t) logits[r] = red[0] + b2[0];
}

// exact lax.top_k: bitonic full sort, desc by val, ties idx asc. blockDim==n.
__global__ void topk_kernel(const float* __restrict__ vals, int n, int k, int* __restrict__ out)
{
    __shared__ float sv[1024];
    __shared__ int   si[1024];
    const int t = threadIdx.x;
    sv[t] = vals[t]; si[t] = t;
    for (int size = 2; size <= n; size <<= 1) {
        for (int stride = size >> 1; stride > 0; stride >>= 1) {
            __syncthreads();
            const int j = t ^ stride;
            if (j > t) {
                float av = sv[t], bv = sv[j];
                int ai = si[t], bi = si[j];
                const bool before = (av > bv) || (av == bv && ai < bi);
                const bool dir = ((t & size) == 0);
                if (dir ? !before : before) { sv[t] = bv; si[t] = bi; sv[j] = av; si[j] = ai; }
            }
        }
    }
    __syncthreads();
    if (t < k) out[t] = si[t];
}

__global__ void gather_sel_kernel(const int* __restrict__ idx1, const int* __restrict__ idx2,
                                  int* __restrict__ selidx)
{
    const int t = threadIdx.x;
    if (t < 256) selidx[t] = idx1[idx2[t]];
}

// complement of 256 selected indices within [0,1024), ascending
__global__ void complement_kernel(const int* __restrict__ selidx, int* __restrict__ remidx)
{
    __shared__ int mask[1024];
    __shared__ int scan[1024];
    const int t = threadIdx.x;
    mask[t] = 0;
    __syncthreads();
    if (t < 256) mask[selidx[t]] = 1;
    __syncthreads();
    const int keep = 1 - mask[t];
    scan[t] = keep;
    __syncthreads();
    for (int off = 1; off < 1024; off <<= 1) {
        int v = scan[t];
        if (t >= off) v += scan[t - off];
        __syncthreads();
        scan[t] = v;
        __syncthreads();
    }
    if (keep) remidx[scan[t] - 1] = t;
}

__global__ __launch_bounds__(256) void gather_rows_kernel(
    float* __restrict__ dst, const float* __restrict__ src,
    const int* __restrict__ map, int ncols)
{
    const int r = blockIdx.x;
    const int sr = map[r];
    const float4* s = (const float4*)(src + (long)sr * ncols);
    float4* d = (float4*)(dst + (long)r * ncols);
    for (int i = threadIdx.x; i < ncols / 4; i += 256) d[i] = s[i];
}

__global__ __launch_bounds__(256) void rownorm_kernel(
    const float* __restrict__ x, float* __restrict__ out)
{
    const int r = blockIdx.x, t = threadIdx.x;
    const float* row = x + (long)r * 4096;
    float s = 0.f;
    for (int c = t; c < 4096; c += 256) { float v = row[c]; s += v * v; }
    __shared__ float red[256];
    red[t] = s; __syncthreads();
    for (int off = 128; off; off >>= 1) { if (t < off) red[t] += red[t + off]; __syncthreads(); }
    if (!t) out[r] = sqrtf(red[0]);
}

__global__ __launch_bounds__(256) void argmax_kernel(
    const float* __restrict__ S, const float* __restrict__ nr,
    const float* __restrict__ ns, int* __restrict__ best)
{
    const int r = blockIdx.x, t = threadIdx.x;
    float v = S[(long)r * 256 + t] / fmaxf(nr[r] * ns[t], 1e-8f);
    __shared__ float bv[256];
    __shared__ int bi[256];
    bv[t] = v; bi[t] = t; __syncthreads();
    for (int off = 128; off; off >>= 1) {
        if (t < off) {
            float ov = bv[t + off]; int oi = bi[t + off];
            if (ov > bv[t] || (ov == bv[t] && oi < bi[t])) { bv[t] = ov; bi[t] = oi; }
        }
        __syncthreads();
    }
    if (!t) best[r] = bi[0];
}

__global__ __launch_bounds__(256) void merge_kernel(
    const float* __restrict__ selb, const float* __restrict__ rem,
    const int* __restrict__ best, const float* __restrict__ nr,
    const float* __restrict__ ns, float* __restrict__ out)
{
    const int j = blockIdx.x, t = threadIdx.x;
    __shared__ int sbest[768];
    __shared__ float snr[768];
    __shared__ float red[256];
    for (int i = t; i < 768; i += 256) { sbest[i] = best[i]; snr[i] = nr[i]; }
    __syncthreads();
    float acc[16];
#pragma unroll
    for (int d = 0; d < 16; d++) acc[d] = 0.f;
    int cnt = 0; float smax = 0.f;
    const int base = t * 16;
    for (int i = 0; i < 768; i++) {
        if (sbest[i] == j) {
            cnt++;
            smax = fmaxf(smax, snr[i]);
            const float* rp = rem + (long)i * 4096 + base;
#pragma unroll
            for (int d = 0; d < 16; d += 4) {
                float4 x4 = *(const float4*)(rp + d);
                acc[d] += x4.x; acc[d + 1] += x4.y; acc[d + 2] += x4.z; acc[d + 3] += x4.w;
            }
        }
    }
    const float* sp = selb + (long)j * 4096 + base;
    float mean[16]; float ss = 0.f;
    const float denom = (float)(cnt + 1);
#pragma unroll
    for (int d = 0; d < 16; d++) { mean[d] = (sp[d] + acc[d]) / denom; ss += mean[d] * mean[d]; }
    red[t] = ss; __syncthreads();
    for (int off = 128; off; off >>= 1) { if (t < off) red[t] += red[t + off]; __syncthreads(); }
    const float nm = sqrtf(red[0]);
    const float mx = fmaxf(ns[j], cnt > 0 ? smax : 0.f);
    float* op = out + (long)j * 4096 + base;
#pragma unroll
    for (int d = 0; d < 16; d++) op[d] = (cnt > 0) ? (mean[d] / nm) * mx : sp[d];
}

// ============================================================================
// host orchestration
// ============================================================================
extern "C" void kernel_launch(void* const* d_in, const int* in_sizes, int n_in,
                              void* d_out, int out_size, void* d_ws, size_t ws_size,
                              hipStream_t stream)
{
    const float* vf   = (const float*)d_in[0];   // 1024 x 4096
    const float* te   = (const float*)d_in[1];   // 128 x 4096
    const float* inw  = (const float*)d_in[3];   // 4 x 12288 x 4096
    const float* inb  = (const float*)d_in[4];   // 4 x 12288
    const float* outw = (const float*)d_in[5];   // 4 x 4096 x 4096
    const float* outb = (const float*)d_in[6];   // 4 x 4096
    const float* w1   = (const float*)d_in[7];   // 2 x 2048 x 4096
    const float* b1   = (const float*)d_in[8];   // 2 x 2048
    const float* w2   = (const float*)d_in[9];   // 2 x 2048
    const float* b2   = (const float*)d_in[10];  // 2
    float* out = (float*)d_out;                  // 256 x 4096
    char* base = (char*)d_ws;

    // regions (bytes): total 94,404,608 <= proven ws capacity
    char* qkR = base;                 // 37,748,736 : qk split / probs split / hbuf
    char* vTR = base + 37748736;      // 18,874,368 : vT split
    char* scR = vTR + 18874368;       // 37,748,736 : comb/scor/obuf/gbuf/final
    float* smalls = (float*)(scR + 37748736);    // 32 KiB of small buffers

    short* qkhi = (short*)qkR;
    short* qklo = (short*)(qkR + 18874368);
    short* vThi = (short*)vTR;
    short* vTlo = (short*)(vTR + 9437184);
    float* hbuf = (float*)qkR;

    float* logits = smalls;                      // 1024
    float* nr     = smalls + 1024;               // 768
    float* ns     = smalls + 1792;               // 256
    int* idx1   = (int*)(smalls + 2048);         // 512
    int* idx2   = (int*)(smalls + 2560);         // 256
    int* selidx = (int*)(smalls + 2816);         // 256
    int* remidx = (int*)(smalls + 3072);         // 768
    int* best   = (int*)(smalls + 3840);         // 768

    const float scl = (float)(1.0 / sqrt(512.0));

    for (int m = 0; m < 2; m++) {
        const int Mq  = m ? 512 : 1024;
        const int Mkv = m ? 640 : 1152;
        const float* Wqkv = inw + (size_t)(2 * m) * 12288 * 4096;
        const float* bqkv = inb + (size_t)(2 * m) * 12288;
        const float* ow = outw + (size_t)(2 * m) * 4096 * 4096;
        const float* ob = outb + (size_t)(2 * m) * 4096;

        // ---- comb split (A of in-proj), lives at scR head ----
        short* chi = (short*)scR;
        short* clo = (short*)(scR + (size_t)Mkv * 4096 * 2);
        if (m == 0) {
            split_rows<<<1024, 256, 0, stream>>>(vf, nullptr, chi, clo);
            split_rows<<<128, 256, 0, stream>>>(te, nullptr,
                chi + (size_t)1024 * 4096, clo + (size_t)1024 * 4096);
        } else {
            split_rows<<<512, 256, 0, stream>>>(vf, idx1, chi, clo);
            split_rows<<<128, 256, 0, stream>>>(te, nullptr,
                chi + (size_t)512 * 4096, clo + (size_t)512 * 4096);
        }
        // ---- fused in-proj: q,k -> qk split; v -> vT split (transposed) ----
        mfma_gemm<0, 2, false><<<dim3(96, Mkv / 128, 1), 256, 0, stream>>>(
            chi, clo, 4096, 0, Wqkv, nullptr, nullptr, 4096, 0,
            nullptr, qkhi, qklo, vThi, vTlo, 8192, 1152, 0, 4096, 1.f, bqkv);
        // ---- scores[h] = scl * q_h @ k_h^T (fp32) ----
        float* scor = (float*)(m ? (scR + 10485760) : scR);
        mfma_gemm<1, 0, false><<<dim3(Mkv / 128, Mq / 128, 8), 256, 0, stream>>>(
            qkhi, qklo, 8192, 512, nullptr, qkhi + 4096, qklo + 4096, 8192, 512,
            scor, nullptr, nullptr, nullptr, nullptr, Mkv, 0, (long)Mq * Mkv,
            512, scl, nullptr);
        // ---- softmax -> split probs (over qk region, qk now dead) ----
        short* phi = (short*)qkR;
        short* plo = (short*)(qkR + (size_t)8 * Mq * Mkv * 2);
        softmax_split<<<8 * Mq, 256, 0, stream>>>(scor, phi, plo, Mkv);
        // ---- PV: o = probs @ vT^T -> obuf split ----
        short* ohi = (short*)scR;
        short* olo = (short*)(scR + (size_t)Mq * 4096 * 2);
        mfma_gemm<1, 1, false><<<dim3(4, Mq / 128, 8), 256, 0, stream>>>(
            phi, plo, Mkv, (long)Mq * Mkv, nullptr, vThi, vTlo, 1152, 512L * 1152,
            nullptr, ohi, olo, nullptr, nullptr, 4096, 0, 512, Mkv, 1.f, nullptr);
        // ---- out-proj: g = o @ ow^T + ob -> gbuf split ----
        short* ghi = (short*)(scR + (size_t)Mq * 4096 * 4);
        short* glo = (short*)(scR + (size_t)Mq * 4096 * 6);
        mfma_gemm<0, 1, false><<<dim3(32, Mq / 128, 1), 256, 0, stream>>>(
            ohi, olo, 4096, 0, ow, nullptr, nullptr, 4096, 0,
            nullptr, ghi, glo, nullptr, nullptr, 4096, 0, 0, 4096, 1.f, ob);
        // ---- MLP: h = relu(g @ w1^T + b1) -> hbuf fp32 (qk region) ----
        mfma_gemm<0, 0, true><<<dim3(16, Mq / 128, 1), 256, 0, stream>>>(
            ghi, glo, 4096, 0, w1 + (size_t)m * 2048 * 4096, nullptr, nullptr, 4096, 0,
            hbuf, nullptr, nullptr, nullptr, nullptr, 2048, 0, 0, 4096, 1.f,
            b1 + (size_t)m * 2048);
        gemv_kernel<<<Mq, 256, 0, stream>>>(hbuf, w2 + (size_t)m * 2048, b2 + m, logits);
        if (m == 0) topk_kernel<<<1, 1024, 0, stream>>>(logits, 1024, 512, idx1);
        else        topk_kernel<<<1, 512, 0, stream>>>(logits, 512, 256, idx2);
    }

    // ---- merge phase ----
    short* remhi = (short*)scR;
    short* remlo = (short*)(scR + 6291456);
    short* selhi = (short*)(scR + 12582912);
    short* sello = (short*)(scR + 14680064);
    float* rem_f = (float*)(scR + 16777216);
    float* sel_f = (float*)(scR + 29360128);
    float* Smat  = (float*)(scR + 33554432);

    gather_sel_kernel<<<1, 256, 0, stream>>>(idx1, idx2, selidx);
    complement_kernel<<<1, 1024, 0, stream>>>(selidx, remidx);
    split_rows<<<768, 256, 0, stream>>>(vf, remidx, remhi, remlo);
    split_rows<<<256, 256, 0, stream>>>(vf, selidx, selhi, sello);
    gather_rows_kernel<<<768, 256, 0, stream>>>(rem_f, vf, remidx, 4096);
    gather_rows_kernel<<<256, 256, 0, stream>>>(sel_f, vf, selidx, 4096);
    rownorm_kernel<<<768, 256, 0, stream>>>(rem_f, nr);
    rownorm_kernel<<<256, 256, 0, stream>>>(sel_f, ns);
    mfma_gemm<1, 0, false><<<dim3(2, 6, 1), 256, 0, stream>>>(
        remhi, remlo, 4096, 0, nullptr, selhi, sello, 4096, 0,
        Smat, nullptr, nullptr, nullptr, nullptr, 256, 0, 0, 4096, 1.f, nullptr);
    argmax_kernel<<<768, 256, 0, stream>>>(Smat, nr, ns, best);
    merge_kernel<<<256, 256, 0, stream>>>(sel_f, rem_f, best, nr, ns, out);
}

// Round 5
// 2117.897 us; speedup vs baseline: 3.3993x; 1.2430x over previous
//
#include <hip/hip_runtime.h>
#include <hip/hip_bf16.h>
#include <math.h>
#include <stdint.h>

typedef __attribute__((ext_vector_type(4))) float f32x4;
typedef __attribute__((ext_vector_type(8))) short s16x8;
typedef __attribute__((ext_vector_type(4))) short s16x4;

struct sh2 { short hi, lo; };

// fp32 -> bf16 hi/lo split. hi = bf16(x) (RNE), lo = bf16(x - hi).
__device__ __forceinline__ sh2 splitf(float x)
{
    __hip_bfloat16 h = __float2bfloat16(x);
    float hf = __bfloat162float(h);
    __hip_bfloat16 l = __float2bfloat16(x - hf);
    sh2 r;
    r.hi = __builtin_bit_cast(short, h);
    r.lo = __builtin_bit_cast(short, l);
    return r;
}

// async global->LDS 16B copy (CK-style addrspace casts; LDS dest must be
// wave-uniform base; each lane writes base + lane*16; global src is per-lane)
typedef const __attribute__((address_space(1))) void gvoid_t;
typedef __attribute__((address_space(3))) void lvoid_t;
__device__ __forceinline__ void gld_lds16(const void* g, void* l)
{
    __builtin_amdgcn_global_load_lds((gvoid_t*)(uintptr_t)g,
                                     (lvoid_t*)(uintptr_t)l, 16, 0, 0);
}

// ============================================================================
// split-bf16 MFMA GEMM: C = alpha*(A @ B^T) [+bias] [ReLU]
// A pre-split (Ahi/Alo bf16, M x K). BF=0: B fp32 (N x K), split inline.
// BF=1: B pre-split. EPI=0 fp32 C [RELU]; EPI=1 split C; EPI=2 in-proj
// (cols<8192 -> split C; cols>=8192 -> split TRANSPOSED vT).
// Staging: pre-split operands via global_load_lds w16, linear LDS dest,
// chunk-XOR swizzle applied on the SOURCE address (involution; frag reads
// apply the same XOR). XCD-chunked block swizzle for B-panel L2 reuse.
// ============================================================================
template<int BF, int EPI, bool RELU>
__global__ __launch_bounds__(256, 2) void mfma_gemm(
    const short* __restrict__ Ahi, const short* __restrict__ Alo, int lda, long sA,
    const float* __restrict__ Bf, const short* __restrict__ Bhi,
    const short* __restrict__ Blo, int ldb, long sB,
    float* __restrict__ Cf, short* __restrict__ Chi, short* __restrict__ Clo,
    short* __restrict__ Thi, short* __restrict__ Tlo, int ldc, int ldT, long sC,
    int K, float alpha, const float* __restrict__ bias)
{
    __shared__ short AhS[4096], AlS[4096], BhS[4096], BlS[4096];
    const int bz = blockIdx.z;
    Ahi += (long)bz * sA; Alo += (long)bz * sA;
    if (BF == 0) Bf += (long)bz * sB; else { Bhi += (long)bz * sB; Blo += (long)bz * sB; }
    const long cofs = (long)bz * sC;

    // ---- bijective XCD-chunked swizzle, x-major decode (B-panel reuse) ----
    const int GX = gridDim.x, GY = gridDim.y;
    const int nwg = GX * GY;
    const int bid = blockIdx.x + GX * blockIdx.y;
    const int q8 = nwg >> 3, r8 = nwg & 7;
    const int xcd = bid & 7, sl = bid >> 3;
    const int t = (xcd < r8) ? (xcd * (q8 + 1) + sl)
                             : (r8 * (q8 + 1) + (xcd - r8) * q8 + sl);
    const int m0 = (t % GY) * 128, n0 = (t / GY) * 128;

    const int tid = threadIdx.x;
    const int lane = tid & 63, wave = tid >> 6;
    const int wr = (wave >> 1) * 64, wc = (wave & 1) * 64;
    const int lrow = lane & 15, lk = lane >> 4;
    const int cswz8 = (lk ^ ((lrow >> 1) & 3)) << 3;   // frag-read chunk swizzle

    // ---- gload_lds staging geometry: per wave-call 64 lanes x 16B = 1024B;
    // tile (128 rows x 32 shorts = 8192B) = 4 waves x 2 calls. Linear LDS;
    // source chunk pre-XORed so LDS[row][c] = global chunk c^f(row). ----
    const int rA0 = wave * 16 + (lane >> 2);   // call-0 row (0..63)
    const int rA1 = rA0 + 64;                  // call-1 row (64..127)
    const int sc0 = ((lane & 3) ^ ((rA0 >> 1) & 3)) * 8;
    const int sc1 = ((lane & 3) ^ ((rA1 >> 1) & 3)) * 8;
    const long gA0 = (long)(m0 + rA0) * lda + sc0;
    const long gA1 = (long)(m0 + rA1) * lda + sc1;
    long gB0 = 0, gB1 = 0;
    if (BF == 1) {
        gB0 = (long)(n0 + rA0) * ldb + sc0;
        gB1 = (long)(n0 + rA1) * ldb + sc1;
    }
    const int lw0 = wave * 512, lw1 = wave * 512 + 2048;  // LDS short idx

    f32x4 acc[4][4];
#pragma unroll
    for (int i = 0; i < 4; i++)
#pragma unroll
        for (int j = 0; j < 4; j++) acc[i][j] = (f32x4){0.f, 0.f, 0.f, 0.f};

    for (int k0 = 0; k0 < K; k0 += 32) {
        // ---- stage A via global_load_lds ----
        gld_lds16(Ahi + gA0 + k0, &AhS[lw0]);
        gld_lds16(Ahi + gA1 + k0, &AhS[lw1]);
        gld_lds16(Alo + gA0 + k0, &AlS[lw0]);
        gld_lds16(Alo + gA1 + k0, &AlS[lw1]);
        // ---- stage B ----
        if constexpr (BF == 1) {
            gld_lds16(Bhi + gB0 + k0, &BhS[lw0]);
            gld_lds16(Bhi + gB1 + k0, &BhS[lw1]);
            gld_lds16(Blo + gB0 + k0, &BlS[lw0]);
            gld_lds16(Blo + gB1 + k0, &BlS[lw1]);
        } else {
            int c = tid;
#pragma unroll
            for (int i = 0; i < 2; i++, c += 256) {
                const int row = c & 127, kc = (c >> 7) * 8;
                const float* bp = Bf + (long)(n0 + row) * ldb + k0 + kc;
                float4 f0 = *(const float4*)bp;
                float4 f1 = *(const float4*)(bp + 4);
                s16x8 h, l;
                sh2 p;
                p = splitf(f0.x); h[0] = p.hi; l[0] = p.lo;
                p = splitf(f0.y); h[1] = p.hi; l[1] = p.lo;
                p = splitf(f0.z); h[2] = p.hi; l[2] = p.lo;
                p = splitf(f0.w); h[3] = p.hi; l[3] = p.lo;
                p = splitf(f1.x); h[4] = p.hi; l[4] = p.lo;
                p = splitf(f1.y); h[5] = p.hi; l[5] = p.lo;
                p = splitf(f1.z); h[6] = p.hi; l[6] = p.lo;
                p = splitf(f1.w); h[7] = p.hi; l[7] = p.lo;
                const int widx = row * 32 + (((kc >> 3) ^ ((row >> 1) & 3)) << 3);
                *(s16x8*)&BhS[widx] = h;
                *(s16x8*)&BlS[widx] = l;
            }
        }
        __syncthreads();   // drains vmcnt (gload_lds) + lgkm (ds_write)
        // ---- MFMA: 4x4 frags x {hihi, hilo, lohi} ----
        s16x8 ah[4], al[4];
#pragma unroll
        for (int m = 0; m < 4; m++) {
            const int idx = (wr + m * 16 + lrow) * 32 + cswz8;
            ah[m] = *(const s16x8*)&AhS[idx];
            al[m] = *(const s16x8*)&AlS[idx];
        }
#pragma unroll
        for (int n = 0; n < 4; n++) {
            const int idx = (wc + n * 16 + lrow) * 32 + cswz8;
            const s16x8 bh = *(const s16x8*)&BhS[idx];
            const s16x8 bl = *(const s16x8*)&BlS[idx];
#pragma unroll
            for (int m = 0; m < 4; m++) {
                acc[m][n] = __builtin_amdgcn_mfma_f32_16x16x32_bf16(ah[m], bh, acc[m][n], 0, 0, 0);
                acc[m][n] = __builtin_amdgcn_mfma_f32_16x16x32_bf16(ah[m], bl, acc[m][n], 0, 0, 0);
                acc[m][n] = __builtin_amdgcn_mfma_f32_16x16x32_bf16(al[m], bh, acc[m][n], 0, 0, 0);
            }
        }
        __syncthreads();
    }
    // ---- epilogue: C/D layout col=lane&15, row=(lane>>4)*4+r ----
#pragma unroll
    for (int n = 0; n < 4; n++) {
        const int col = n0 + wc + n * 16 + lrow;
        const float bv = bias ? bias[col] : 0.f;
#pragma unroll
        for (int m = 0; m < 4; m++) {
            const int row = m0 + wr + m * 16 + lk * 4;
            if constexpr (EPI == 0) {
#pragma unroll
                for (int r = 0; r < 4; r++) {
                    float v = acc[m][n][r] * alpha + bv;
                    if (RELU) v = fmaxf(v, 0.f);
                    Cf[cofs + (long)(row + r) * ldc + col] = v;
                }
            } else if constexpr (EPI == 1) {
#pragma unroll
                for (int r = 0; r < 4; r++) {
                    float v = acc[m][n][r] * alpha + bv;
                    sh2 p = splitf(v);
                    Chi[cofs + (long)(row + r) * ldc + col] = p.hi;
                    Clo[cofs + (long)(row + r) * ldc + col] = p.lo;
                }
            } else {
                if (n0 < 8192) {
#pragma unroll
                    for (int r = 0; r < 4; r++) {
                        float v = acc[m][n][r] + bv;
                        sh2 p = splitf(v);
                        Chi[(long)(row + r) * ldc + col] = p.hi;
                        Clo[(long)(row + r) * ldc + col] = p.lo;
                    }
                } else {
                    s16x4 h4, l4;
#pragma unroll
                    for (int r = 0; r < 4; r++) {
                        float v = acc[m][n][r] + bv;
                        sh2 p = splitf(v);
                        h4[r] = p.hi; l4[r] = p.lo;
                    }
                    const long tof = (long)(col - 8192) * ldT + row;
                    *(s16x4*)&Thi[tof] = h4;
                    *(s16x4*)&Tlo[tof] = l4;
                }
            }
        }
    }
}

// ============================================================================
// split rows: dhi/dlo[r,:4096] = split(src[map? map[r] : r, :4096])
// ============================================================================
__global__ __launch_bounds__(256) void split_rows(
    const float* __restrict__ src, const int* __restrict__ map,
    short* __restrict__ dhi, short* __restrict__ dlo)
{
    const int r = blockIdx.x;
    const int sr = map ? map[r] : r;
    const float4* s = (const float4*)(src + (long)sr * 4096);
    const long db = (long)r * 4096;
    for (int i = threadIdx.x; i < 1024; i += 256) {
        float4 f = s[i];
        s16x4 h, l;
        sh2 p;
        p = splitf(f.x); h[0] = p.hi; l[0] = p.lo;
        p = splitf(f.y); h[1] = p.hi; l[1] = p.lo;
        p = splitf(f.z); h[2] = p.hi; l[2] = p.lo;
        p = splitf(f.w); h[3] = p.hi; l[3] = p.lo;
        *(s16x4*)&dhi[db + i * 4] = h;
        *(s16x4*)&dlo[db + i * 4] = l;
    }
}

// ============================================================================
// row softmax (jax.nn.softmax: exp(x-max)/sum, exact div) -> split probs
// ============================================================================
__global__ __launch_bounds__(256) void softmax_split(
    const float* __restrict__ x, short* __restrict__ phi, short* __restrict__ plo,
    int cols)
{
    const long rb = (long)blockIdx.x * cols;
    const float4* xr = (const float4*)(x + rb);
    const int t = threadIdx.x;
    const int n4 = cols >> 2;
    __shared__ float red[256];
    float mx = -INFINITY;
    for (int i = t; i < n4; i += 256) {
        float4 f = xr[i];
        mx = fmaxf(fmaxf(mx, fmaxf(f.x, f.y)), fmaxf(f.z, f.w));
    }
    red[t] = mx; __syncthreads();
    for (int off = 128; off; off >>= 1) { if (t < off) red[t] = fmaxf(red[t], red[t + off]); __syncthreads(); }
    mx = red[0]; __syncthreads();
    float4 ebuf[2];
    float s = 0.f;
    int nb = 0;
    for (int i = t; i < n4; i += 256) {
        float4 f = xr[i];
        f.x = expf(f.x - mx); f.y = expf(f.y - mx); f.z = expf(f.z - mx); f.w = expf(f.w - mx);
        ebuf[nb++] = f;
        s += f.x + f.y + f.z + f.w;
    }
    red[t] = s; __syncthreads();
    for (int off = 128; off; off >>= 1) { if (t < off) red[t] += red[t + off]; __syncthreads(); }
    s = red[0];
    nb = 0;
    for (int i = t; i < n4; i += 256) {
        float4 f = ebuf[nb++];
        f.x /= s; f.y /= s; f.z /= s; f.w /= s;
        s16x4 h, l;
        sh2 p;
        p = splitf(f.x); h[0] = p.hi; l[0] = p.lo;
        p = splitf(f.y); h[1] = p.hi; l[1] = p.lo;
        p = splitf(f.z); h[2] = p.hi; l[2] = p.lo;
        p = splitf(f.w); h[3] = p.hi; l[3] = p.lo;
        *(s16x4*)&phi[rb + i * 4] = h;
        *(s16x4*)&plo[rb + i * 4] = l;
    }
}

// logits[r] = H[r,:2048] . w2 + b2
__global__ __launch_bounds__(256) void gemv_kernel(
    const float* __restrict__ H, const float* __restrict__ w2,
    const float* __restrict__ b2, float* __restrict__ logits)
{
    const int r = blockIdx.x, t = threadIdx.x;
    const float* row = H + (long)r * 2048;
    float s = 0.f;
    for (int c = t; c < 2048; c += 256) s += row[c] * w2[c];
    __shared__ float red[256];
    red[t] = s; __syncthreads();
    for (int off = 128; off; off >>= 1) { if (t < off) red[t] += red[t + off]; __syncthreads(); }
    if (!t) logits[r] = red[0] + b2[0];
}

// exact lax.top_k: bitonic full sort, desc by val, ties idx asc. blockDim==n.
__global__ void topk_kernel(const float* __restrict__ vals, int n, int k, int* __restrict__ out)
{
    __shared__ float sv[1024];
    __shared__ int   si[1024];
    const int t = threadIdx.x;
    sv[t] = vals[t]; si[t] = t;
    for (int size = 2; size <= n; size <<= 1) {
        for (int stride = size >> 1; stride > 0; stride >>= 1) {
            __syncthreads();
            const int j = t ^ stride;
            if (j > t) {
                float av = sv[t], bv = sv[j];
                int ai = si[t], bi = si[j];
                const bool before = (av > bv) || (av == bv && ai < bi);
                const bool dir = ((t & size) == 0);
                if (dir ? !before : before) { sv[t] = bv; si[t] = bi; sv[j] = av; si[j] = ai; }
            }
        }
    }
    __syncthreads();
    if (t < k) out[t] = si[t];
}

__global__ void gather_sel_kernel(const int* __restrict__ idx1, const int* __restrict__ idx2,
                                  int* __restrict__ selidx)
{
    const int t = threadIdx.x;
    if (t < 256) selidx[t] = idx1[idx2[t]];
}

// complement of 256 selected indices within [0,1024), ascending
__global__ void complement_kernel(const int* __restrict__ selidx, int* __restrict__ remidx)
{
    __shared__ int mask[1024];
    __shared__ int scan[1024];
    const int t = threadIdx.x;
    mask[t] = 0;
    __syncthreads();
    if (t < 256) mask[selidx[t]] = 1;
    __syncthreads();
    const int keep = 1 - mask[t];
    scan[t] = keep;
    __syncthreads();
    for (int off = 1; off < 1024; off <<= 1) {
        int v = scan[t];
        if (t >= off) v += scan[t - off];
        __syncthreads();
        scan[t] = v;
        __syncthreads();
    }
    if (keep) remidx[scan[t] - 1] = t;
}

__global__ __launch_bounds__(256) void gather_rows_kernel(
    float* __restrict__ dst, const float* __restrict__ src,
    const int* __restrict__ map, int ncols)
{
    const int r = blockIdx.x;
    const int sr = map[r];
    const float4* s = (const float4*)(src + (long)sr * ncols);
    float4* d = (float4*)(dst + (long)r * ncols);
    for (int i = threadIdx.x; i < ncols / 4; i += 256) d[i] = s[i];
}

__global__ __launch_bounds__(256) void rownorm_kernel(
    const float* __restrict__ x, float* __restrict__ out)
{
    const int r = blockIdx.x, t = threadIdx.x;
    const float* row = x + (long)r * 4096;
    float s = 0.f;
    for (int c = t; c < 4096; c += 256) { float v = row[c]; s += v * v; }
    __shared__ float red[256];
    red[t] = s; __syncthreads();
    for (int off = 128; off; off >>= 1) { if (t < off) red[t] += red[t + off]; __syncthreads(); }
    if (!t) out[r] = sqrtf(red[0]);
}

__global__ __launch_bounds__(256) void argmax_kernel(
    const float* __restrict__ S, const float* __restrict__ nr,
    const float* __restrict__ ns, int* __restrict__ best)
{
    const int r = blockIdx.x, t = threadIdx.x;
    float v = S[(long)r * 256 + t] / fmaxf(nr[r] * ns[t], 1e-8f);
    __shared__ float bv[256];
    __shared__ int bi[256];
    bv[t] = v; bi[t] = t; __syncthreads();
    for (int off = 128; off; off >>= 1) {
        if (t < off) {
            float ov = bv[t + off]; int oi = bi[t + off];
            if (ov > bv[t] || (ov == bv[t] && oi < bi[t])) { bv[t] = ov; bi[t] = oi; }
        }
        __syncthreads();
    }
    if (!t) best[r] = bi[0];
}

__global__ __launch_bounds__(256) void merge_kernel(
    const float* __restrict__ selb, const float* __restrict__ rem,
    const int* __restrict__ best, const float* __restrict__ nr,
    const float* __restrict__ ns, float* __restrict__ out)
{
    const int j = blockIdx.x, t = threadIdx.x;
    __shared__ int sbest[768];
    __shared__ float snr[768];
    __shared__ float red[256];
    for (int i = t; i < 768; i += 256) { sbest[i] = best[i]; snr[i] = nr[i]; }
    __syncthreads();
    float acc[16];
#pragma unroll
    for (int d = 0; d < 16; d++) acc[d] = 0.f;
    int cnt = 0; float smax = 0.f;
    const int base = t * 16;
    for (int i = 0; i < 768; i++) {
        if (sbest[i] == j) {
            cnt++;
            smax = fmaxf(smax, snr[i]);
            const float* rp = rem + (long)i * 4096 + base;
#pragma unroll
            for (int d = 0; d < 16; d += 4) {
                float4 x4 = *(const float4*)(rp + d);
                acc[d] += x4.x; acc[d + 1] += x4.y; acc[d + 2] += x4.z; acc[d + 3] += x4.w;
            }
        }
    }
    const float* sp = selb + (long)j * 4096 + base;
    float mean[16]; float ss = 0.f;
    const float denom = (float)(cnt + 1);
#pragma unroll
    for (int d = 0; d < 16; d++) { mean[d] = (sp[d] + acc[d]) / denom; ss += mean[d] * mean[d]; }
    red[t] = ss; __syncthreads();
    for (int off = 128; off; off >>= 1) { if (t < off) red[t] += red[t + off]; __syncthreads(); }
    const float nm = sqrtf(red[0]);
    const float mx = fmaxf(ns[j], cnt > 0 ? smax : 0.f);
    float* op = out + (long)j * 4096 + base;
#pragma unroll
    for (int d = 0; d < 16; d++) op[d] = (cnt > 0) ? (mean[d] / nm) * mx : sp[d];
}

// ============================================================================
// host orchestration
// ============================================================================
extern "C" void kernel_launch(void* const* d_in, const int* in_sizes, int n_in,
                              void* d_out, int out_size, void* d_ws, size_t ws_size,
                              hipStream_t stream)
{
    const float* vf   = (const float*)d_in[0];   // 1024 x 4096
    const float* te   = (const float*)d_in[1];   // 128 x 4096
    const float* inw  = (const float*)d_in[3];   // 4 x 12288 x 4096
    const float* inb  = (const float*)d_in[4];   // 4 x 12288
    const float* outw = (const float*)d_in[5];   // 4 x 4096 x 4096
    const float* outb = (const float*)d_in[6];   // 4 x 4096
    const float* w1   = (const float*)d_in[7];   // 2 x 2048 x 4096
    const float* b1   = (const float*)d_in[8];   // 2 x 2048
    const float* w2   = (const float*)d_in[9];   // 2 x 2048
    const float* b2   = (const float*)d_in[10];  // 2
    float* out = (float*)d_out;                  // 256 x 4096
    char* base = (char*)d_ws;

    // regions (bytes): total 94,404,608 <= proven ws capacity
    char* qkR = base;                 // 37,748,736 : qk split / probs split / hbuf
    char* vTR = base + 37748736;      // 18,874,368 : vT split
    char* scR = vTR + 18874368;       // 37,748,736 : comb/scor/obuf/gbuf/final
    float* smalls = (float*)(scR + 37748736);    // 32 KiB of small buffers

    short* qkhi = (short*)qkR;
    short* qklo = (short*)(qkR + 18874368);
    short* vThi = (short*)vTR;
    short* vTlo = (short*)(vTR + 9437184);
    float* hbuf = (float*)qkR;

    float* logits = smalls;                      // 1024
    float* nr     = smalls + 1024;               // 768
    float* ns     = smalls + 1792;               // 256
    int* idx1   = (int*)(smalls + 2048);         // 512
    int* idx2   = (int*)(smalls + 2560);         // 256
    int* selidx = (int*)(smalls + 2816);         // 256
    int* remidx = (int*)(smalls + 3072);         // 768
    int* best   = (int*)(smalls + 3840);         // 768

    const float scl = (float)(1.0 / sqrt(512.0));

    for (int m = 0; m < 2; m++) {
        const int Mq  = m ? 512 : 1024;
        const int Mkv = m ? 640 : 1152;
        const float* Wqkv = inw + (size_t)(2 * m) * 12288 * 4096;
        const float* bqkv = inb + (size_t)(2 * m) * 12288;
        const float* ow = outw + (size_t)(2 * m) * 4096 * 4096;
        const float* ob = outb + (size_t)(2 * m) * 4096;

        // ---- comb split (A of in-proj), lives at scR head ----
        short* chi = (short*)scR;
        short* clo = (short*)(scR + (size_t)Mkv * 4096 * 2);
        if (m == 0) {
            split_rows<<<1024, 256, 0, stream>>>(vf, nullptr, chi, clo);
            split_rows<<<128, 256, 0, stream>>>(te, nullptr,
                chi + (size_t)1024 * 4096, clo + (size_t)1024 * 4096);
        } else {
            split_rows<<<512, 256, 0, stream>>>(vf, idx1, chi, clo);
            split_rows<<<128, 256, 0, stream>>>(te, nullptr,
                chi + (size_t)512 * 4096, clo + (size_t)512 * 4096);
        }
        // ---- fused in-proj: q,k -> qk split; v -> vT split (transposed) ----
        mfma_gemm<0, 2, false><<<dim3(96, Mkv / 128, 1), 256, 0, stream>>>(
            chi, clo, 4096, 0, Wqkv, nullptr, nullptr, 4096, 0,
            nullptr, qkhi, qklo, vThi, vTlo, 8192, 1152, 0, 4096, 1.f, bqkv);
        // ---- scores[h] = scl * q_h @ k_h^T (fp32) ----
        float* scor = (float*)(m ? (scR + 10485760) : scR);
        mfma_gemm<1, 0, false><<<dim3(Mkv / 128, Mq / 128, 8), 256, 0, stream>>>(
            qkhi, qklo, 8192, 512, nullptr, qkhi + 4096, qklo + 4096, 8192, 512,
            scor, nullptr, nullptr, nullptr, nullptr, Mkv, 0, (long)Mq * Mkv,
            512, scl, nullptr);
        // ---- softmax -> split probs (over qk region, qk now dead) ----
        short* phi = (short*)qkR;
        short* plo = (short*)(qkR + (size_t)8 * Mq * Mkv * 2);
        softmax_split<<<8 * Mq, 256, 0, stream>>>(scor, phi, plo, Mkv);
        // ---- PV: o = probs @ vT^T -> obuf split ----
        short* ohi = (short*)scR;
        short* olo = (short*)(scR + (size_t)Mq * 4096 * 2);
        mfma_gemm<1, 1, false><<<dim3(4, Mq / 128, 8), 256, 0, stream>>>(
            phi, plo, Mkv, (long)Mq * Mkv, nullptr, vThi, vTlo, 1152, 512L * 1152,
            nullptr, ohi, olo, nullptr, nullptr, 4096, 0, 512, Mkv, 1.f, nullptr);
        // ---- out-proj: g = o @ ow^T + ob -> gbuf split ----
        short* ghi = (short*)(scR + (size_t)Mq * 4096 * 4);
        short* glo = (short*)(scR + (size_t)Mq * 4096 * 6);
        mfma_gemm<0, 1, false><<<dim3(32, Mq / 128, 1), 256, 0, stream>>>(
            ohi, olo, 4096, 0, ow, nullptr, nullptr, 4096, 0,
            nullptr, ghi, glo, nullptr, nullptr, 4096, 0, 0, 4096, 1.f, ob);
        // ---- MLP: h = relu(g @ w1^T + b1) -> hbuf fp32 (qk region) ----
        mfma_gemm<0, 0, true><<<dim3(16, Mq / 128, 1), 256, 0, stream>>>(
            ghi, glo, 4096, 0, w1 + (size_t)m * 2048 * 4096, nullptr, nullptr, 4096, 0,
            hbuf, nullptr, nullptr, nullptr, nullptr, 2048, 0, 0, 4096, 1.f,
            b1 + (size_t)m * 2048);
        gemv_kernel<<<Mq, 256, 0, stream>>>(hbuf, w2 + (size_t)m * 2048, b2 + m, logits);
        if (m == 0) topk_kernel<<<1, 1024, 0, stream>>>(logits, 1024, 512, idx1);
        else        topk_kernel<<<1, 512, 0, stream>>>(logits, 512, 256, idx2);
    }

    // ---- merge phase ----
    short* remhi = (short*)scR;
    short* remlo = (short*)(scR + 6291456);
    short* selhi = (short*)(scR + 12582912);
    short* sello = (short*)(scR + 14680064);
    float* rem_f = (float*)(scR + 16777216);
    float* sel_f = (float*)(scR + 29360128);
    float* Smat  = (float*)(scR + 33554432);

    gather_sel_kernel<<<1, 256, 0, stream>>>(idx1, idx2, selidx);
    complement_kernel<<<1, 1024, 0, stream>>>(selidx, remidx);
    split_rows<<<768, 256, 0, stream>>>(vf, remidx, remhi, remlo);
    split_rows<<<256, 256, 0, stream>>>(vf, selidx, selhi, sello);
    gather_rows_kernel<<<768, 256, 0, stream>>>(rem_f, vf, remidx, 4096);
    gather_rows_kernel<<<256, 256, 0, stream>>>(sel_f, vf, selidx, 4096);
    rownorm_kernel<<<768, 256, 0, stream>>>(rem_f, nr);
    rownorm_kernel<<<256, 256, 0, stream>>>(sel_f, ns);
    mfma_gemm<1, 0, false><<<dim3(2, 6, 1), 256, 0, stream>>>(
        remhi, remlo, 4096, 0, nullptr, selhi, sello, 4096, 0,
        Smat, nullptr, nullptr, nullptr, nullptr, 256, 0, 0, 4096, 1.f, nullptr);
    argmax_kernel<<<768, 256, 0, stream>>>(Smat, nr, ns, best);
    merge_kernel<<<256, 256, 0, stream>>>(sel_f, rem_f, best, nr, ns, out);
}

// Round 6
// 1765.410 us; speedup vs baseline: 4.0781x; 1.1997x over previous
//
#include <hip/hip_runtime.h>
#include <hip/hip_bf16.h>
#include <math.h>
#include <stdint.h>

typedef __attribute__((ext_vector_type(4))) float f32x4;
typedef __attribute__((ext_vector_type(8))) short s16x8;
typedef __attribute__((ext_vector_type(4))) short s16x4;

struct sh2 { short hi, lo; };

// fp32 -> bf16 hi/lo split. hi = bf16(x) (RNE), lo = bf16(x - hi).
__device__ __forceinline__ sh2 splitf(float x)
{
    __hip_bfloat16 h = __float2bfloat16(x);
    float hf = __bfloat162float(h);
    __hip_bfloat16 l = __float2bfloat16(x - hf);
    sh2 r;
    r.hi = __builtin_bit_cast(short, h);
    r.lo = __builtin_bit_cast(short, l);
    return r;
}

// async global->LDS 16B copy (wave-uniform LDS base; lane writes base+lane*16)
typedef const __attribute__((address_space(1))) void gvoid_t;
typedef __attribute__((address_space(3))) void lvoid_t;
__device__ __forceinline__ void gld_lds16(const void* g, void* l)
{
    __builtin_amdgcn_global_load_lds((gvoid_t*)(uintptr_t)g,
                                     (lvoid_t*)(uintptr_t)l, 16, 0, 0);
}

// ============================================================================
// split-bf16 MFMA GEMM: C = alpha*(A @ B^T) [+bias] [ReLU]
// A pre-split (Ahi/Alo bf16, M x K). BF=0: B fp32 (N x K), split inline.
// BF=1: B pre-split. EPI=0 fp32 C [RELU]; EPI=1 split C; EPI=2 in-proj
// (cols<8192 -> split C; cols>=8192 -> split TRANSPOSED vT).
// 2-phase double-buffered pipeline (T3-minimum): stage tile k+1 (async
// gload_lds / issue-early reg loads) while MFMAing tile k; BF=0 split+ds_write
// placed AFTER the MFMAs (T14 issue-early/write-late); ONE barrier per K-step.
// Chunk-XOR bank swizzle applied on the SOURCE address (involution).
// XCD-chunked block swizzle for B-panel L2 reuse.
// ============================================================================
template<int BF, int EPI, bool RELU>
__global__ __launch_bounds__(256, 2) void mfma_gemm(
    const short* __restrict__ Ahi, const short* __restrict__ Alo, int lda, long sA,
    const float* __restrict__ Bf, const short* __restrict__ Bhi,
    const short* __restrict__ Blo, int ldb, long sB,
    float* __restrict__ Cf, short* __restrict__ Chi, short* __restrict__ Clo,
    short* __restrict__ Thi, short* __restrict__ Tlo, int ldc, int ldT, long sC,
    int K, float alpha, const float* __restrict__ bias)
{
    // double-buffered LDS: per buf {Ah 4096 | Al 4096 | Bh 4096 | Bl 4096} shorts
    __shared__ short SH[2][16384];
    const int bz = blockIdx.z;
    Ahi += (long)bz * sA; Alo += (long)bz * sA;
    if (BF == 0) Bf += (long)bz * sB; else { Bhi += (long)bz * sB; Blo += (long)bz * sB; }
    const long cofs = (long)bz * sC;

    // ---- bijective XCD-chunked swizzle, x-major decode (B-panel reuse) ----
    const int GX = gridDim.x, GY = gridDim.y;
    const int nwg = GX * GY;
    const int bid = blockIdx.x + GX * blockIdx.y;
    const int q8 = nwg >> 3, r8 = nwg & 7;
    const int xcd = bid & 7, sl = bid >> 3;
    const int t = (xcd < r8) ? (xcd * (q8 + 1) + sl)
                             : (r8 * (q8 + 1) + (xcd - r8) * q8 + sl);
    const int m0 = (t % GY) * 128, n0 = (t / GY) * 128;

    const int tid = threadIdx.x;
    const int lane = tid & 63, wave = tid >> 6;
    const int wr = (wave >> 1) * 64, wc = (wave & 1) * 64;
    const int lrow = lane & 15, lk = lane >> 4;
    const int cswz8 = (lk ^ ((lrow >> 1) & 3)) << 3;   // frag-read chunk swizzle

    // ---- gload_lds staging geometry (pre-split operands) ----
    const int rA0 = wave * 16 + (lane >> 2);   // call-0 row (0..63)
    const int rA1 = rA0 + 64;                  // call-1 row (64..127)
    const int sc0 = ((lane & 3) ^ ((rA0 >> 1) & 3)) * 8;
    const int sc1 = ((lane & 3) ^ ((rA1 >> 1) & 3)) * 8;
    const long gA0 = (long)(m0 + rA0) * lda + sc0;
    const long gA1 = (long)(m0 + rA1) * lda + sc1;
    long gB0 = 0, gB1 = 0;
    if (BF == 1) {
        gB0 = (long)(n0 + rA0) * ldb + sc0;
        gB1 = (long)(n0 + rA1) * ldb + sc1;
    }
    const int lw0 = wave * 512, lw1 = wave * 512 + 2048;  // LDS short idx in-region

    // ---- BF=0 fp32-B staging coords (reg round-trip, issue-early/write-late)
    const int brow = tid & 127;
    const int bkc0 = (tid >> 7) * 8;           // 0 or 8
    const int bkc1 = bkc0 + 16;                // 16 or 24
    const int bw0 = brow * 32 + (((bkc0 >> 3) ^ ((brow >> 1) & 3)) << 3);
    const int bw1 = brow * 32 + (((bkc1 >> 3) ^ ((brow >> 1) & 3)) << 3);
    const float* bpr = (BF == 0) ? Bf + (long)(n0 + brow) * ldb : nullptr;

    f32x4 acc[4][4];
#pragma unroll
    for (int i = 0; i < 4; i++)
#pragma unroll
        for (int j = 0; j < 4; j++) acc[i][j] = (f32x4){0.f, 0.f, 0.f, 0.f};

    float4 rb0a, rb0b, rb1a, rb1b;   // BF=0 in-flight B regs

    // ================= prologue: stage tile 0 into buf 0 =================
    {
        short* S = &SH[0][0];
        gld_lds16(Ahi + gA0, S + lw0);
        gld_lds16(Ahi + gA1, S + lw1);
        gld_lds16(Alo + gA0, S + 4096 + lw0);
        gld_lds16(Alo + gA1, S + 4096 + lw1);
        if constexpr (BF == 1) {
            gld_lds16(Bhi + gB0, S + 8192 + lw0);
            gld_lds16(Bhi + gB1, S + 8192 + lw1);
            gld_lds16(Blo + gB0, S + 12288 + lw0);
            gld_lds16(Blo + gB1, S + 12288 + lw1);
        } else {
            rb0a = *(const float4*)(bpr + bkc0);
            rb0b = *(const float4*)(bpr + bkc0 + 4);
            rb1a = *(const float4*)(bpr + bkc1);
            rb1b = *(const float4*)(bpr + bkc1 + 4);
            s16x8 h, l; sh2 p;
            p = splitf(rb0a.x); h[0] = p.hi; l[0] = p.lo;
            p = splitf(rb0a.y); h[1] = p.hi; l[1] = p.lo;
            p = splitf(rb0a.z); h[2] = p.hi; l[2] = p.lo;
            p = splitf(rb0a.w); h[3] = p.hi; l[3] = p.lo;
            p = splitf(rb0b.x); h[4] = p.hi; l[4] = p.lo;
            p = splitf(rb0b.y); h[5] = p.hi; l[5] = p.lo;
            p = splitf(rb0b.z); h[6] = p.hi; l[6] = p.lo;
            p = splitf(rb0b.w); h[7] = p.hi; l[7] = p.lo;
            *(s16x8*)&S[8192 + bw0] = h;
            *(s16x8*)&S[12288 + bw0] = l;
            p = splitf(rb1a.x); h[0] = p.hi; l[0] = p.lo;
            p = splitf(rb1a.y); h[1] = p.hi; l[1] = p.lo;
            p = splitf(rb1a.z); h[2] = p.hi; l[2] = p.lo;
            p = splitf(rb1a.w); h[3] = p.hi; l[3] = p.lo;
            p = splitf(rb1b.x); h[4] = p.hi; l[4] = p.lo;
            p = splitf(rb1b.y); h[5] = p.hi; l[5] = p.lo;
            p = splitf(rb1b.z); h[6] = p.hi; l[6] = p.lo;
            p = splitf(rb1b.w); h[7] = p.hi; l[7] = p.lo;
            *(s16x8*)&S[8192 + bw1] = h;
            *(s16x8*)&S[12288 + bw1] = l;
        }
    }
    __syncthreads();

    // ========================== main K loop ==========================
    int cur = 0;
    for (int k0 = 0; k0 < K; k0 += 32) {
        const int kn = k0 + 32;
        const bool nx = (kn < K);
        short* SN = &SH[cur ^ 1][0];
        // ---- issue next-tile loads (async / into regs) ----
        if (nx) {
            gld_lds16(Ahi + gA0 + kn, SN + lw0);
            gld_lds16(Ahi + gA1 + kn, SN + lw1);
            gld_lds16(Alo + gA0 + kn, SN + 4096 + lw0);
            gld_lds16(Alo + gA1 + kn, SN + 4096 + lw1);
            if constexpr (BF == 1) {
                gld_lds16(Bhi + gB0 + kn, SN + 8192 + lw0);
                gld_lds16(Bhi + gB1 + kn, SN + 8192 + lw1);
                gld_lds16(Blo + gB0 + kn, SN + 12288 + lw0);
                gld_lds16(Blo + gB1 + kn, SN + 12288 + lw1);
            } else {
                rb0a = *(const float4*)(bpr + kn + bkc0);
                rb0b = *(const float4*)(bpr + kn + bkc0 + 4);
                rb1a = *(const float4*)(bpr + kn + bkc1);
                rb1b = *(const float4*)(bpr + kn + bkc1 + 4);
            }
        }
        // ---- MFMA on current buffer ----
        const short* S = &SH[cur][0];
        s16x8 ah[4], al[4];
#pragma unroll
        for (int m = 0; m < 4; m++) {
            const int idx = (wr + m * 16 + lrow) * 32 + cswz8;
            ah[m] = *(const s16x8*)&S[idx];
            al[m] = *(const s16x8*)&S[4096 + idx];
        }
#pragma unroll
        for (int n = 0; n < 4; n++) {
            const int idx = (wc + n * 16 + lrow) * 32 + cswz8;
            const s16x8 bh = *(const s16x8*)&S[8192 + idx];
            const s16x8 bl = *(const s16x8*)&S[12288 + idx];
#pragma unroll
            for (int m = 0; m < 4; m++) {
                acc[m][n] = __builtin_amdgcn_mfma_f32_16x16x32_bf16(ah[m], bh, acc[m][n], 0, 0, 0);
                acc[m][n] = __builtin_amdgcn_mfma_f32_16x16x32_bf16(ah[m], bl, acc[m][n], 0, 0, 0);
                acc[m][n] = __builtin_amdgcn_mfma_f32_16x16x32_bf16(al[m], bh, acc[m][n], 0, 0, 0);
            }
        }
        // ---- BF=0: split + ds_write of next B tile (late, after MFMAs) ----
        if (BF == 0 && nx) {
            s16x8 h, l; sh2 p;
            p = splitf(rb0a.x); h[0] = p.hi; l[0] = p.lo;
            p = splitf(rb0a.y); h[1] = p.hi; l[1] = p.lo;
            p = splitf(rb0a.z); h[2] = p.hi; l[2] = p.lo;
            p = splitf(rb0a.w); h[3] = p.hi; l[3] = p.lo;
            p = splitf(rb0b.x); h[4] = p.hi; l[4] = p.lo;
            p = splitf(rb0b.y); h[5] = p.hi; l[5] = p.lo;
            p = splitf(rb0b.z); h[6] = p.hi; l[6] = p.lo;
            p = splitf(rb0b.w); h[7] = p.hi; l[7] = p.lo;
            *(s16x8*)&SN[8192 + bw0] = h;
            *(s16x8*)&SN[12288 + bw0] = l;
            p = splitf(rb1a.x); h[0] = p.hi; l[0] = p.lo;
            p = splitf(rb1a.y); h[1] = p.hi; l[1] = p.lo;
            p = splitf(rb1a.z); h[2] = p.hi; l[2] = p.lo;
            p = splitf(rb1a.w); h[3] = p.hi; l[3] = p.lo;
            p = splitf(rb1b.x); h[4] = p.hi; l[4] = p.lo;
            p = splitf(rb1b.y); h[5] = p.hi; l[5] = p.lo;
            p = splitf(rb1b.z); h[6] = p.hi; l[6] = p.lo;
            p = splitf(rb1b.w); h[7] = p.hi; l[7] = p.lo;
            *(s16x8*)&SN[8192 + bw1] = h;
            *(s16x8*)&SN[12288 + bw1] = l;
        }
        __syncthreads();   // next tile staged (vmcnt+lgkm drained), cur free
        cur ^= 1;
    }
    // ---- epilogue: C/D layout col=lane&15, row=(lane>>4)*4+r ----
#pragma unroll
    for (int n = 0; n < 4; n++) {
        const int col = n0 + wc + n * 16 + lrow;
        const float bv = bias ? bias[col] : 0.f;
#pragma unroll
        for (int m = 0; m < 4; m++) {
            const int row = m0 + wr + m * 16 + lk * 4;
            if constexpr (EPI == 0) {
#pragma unroll
                for (int r = 0; r < 4; r++) {
                    float v = acc[m][n][r] * alpha + bv;
                    if (RELU) v = fmaxf(v, 0.f);
                    Cf[cofs + (long)(row + r) * ldc + col] = v;
                }
            } else if constexpr (EPI == 1) {
#pragma unroll
                for (int r = 0; r < 4; r++) {
                    float v = acc[m][n][r] * alpha + bv;
                    sh2 p = splitf(v);
                    Chi[cofs + (long)(row + r) * ldc + col] = p.hi;
                    Clo[cofs + (long)(row + r) * ldc + col] = p.lo;
                }
            } else {
                if (n0 < 8192) {
#pragma unroll
                    for (int r = 0; r < 4; r++) {
                        float v = acc[m][n][r] + bv;
                        sh2 p = splitf(v);
                        Chi[(long)(row + r) * ldc + col] = p.hi;
                        Clo[(long)(row + r) * ldc + col] = p.lo;
                    }
                } else {
                    s16x4 h4, l4;
#pragma unroll
                    for (int r = 0; r < 4; r++) {
                        float v = acc[m][n][r] + bv;
                        sh2 p = splitf(v);
                        h4[r] = p.hi; l4[r] = p.lo;
                    }
                    const long tof = (long)(col - 8192) * ldT + row;
                    *(s16x4*)&Thi[tof] = h4;
                    *(s16x4*)&Tlo[tof] = l4;
                }
            }
        }
    }
}

// ============================================================================
// split rows: dhi/dlo[r,:4096] = split(src[map? map[r] : r, :4096])
// ============================================================================
__global__ __launch_bounds__(256) void split_rows(
    const float* __restrict__ src, const int* __restrict__ map,
    short* __restrict__ dhi, short* __restrict__ dlo)
{
    const int r = blockIdx.x;
    const int sr = map ? map[r] : r;
    const float4* s = (const float4*)(src + (long)sr * 4096);
    const long db = (long)r * 4096;
    for (int i = threadIdx.x; i < 1024; i += 256) {
        float4 f = s[i];
        s16x4 h, l;
        sh2 p;
        p = splitf(f.x); h[0] = p.hi; l[0] = p.lo;
        p = splitf(f.y); h[1] = p.hi; l[1] = p.lo;
        p = splitf(f.z); h[2] = p.hi; l[2] = p.lo;
        p = splitf(f.w); h[3] = p.hi; l[3] = p.lo;
        *(s16x4*)&dhi[db + i * 4] = h;
        *(s16x4*)&dlo[db + i * 4] = l;
    }
}

// ============================================================================
// row softmax (jax.nn.softmax: exp(x-max)/sum, exact div) -> split probs
// ============================================================================
__global__ __launch_bounds__(256) void softmax_split(
    const float* __restrict__ x, short* __restrict__ phi, short* __restrict__ plo,
    int cols)
{
    const long rb = (long)blockIdx.x * cols;
    const float4* xr = (const float4*)(x + rb);
    const int t = threadIdx.x;
    const int n4 = cols >> 2;
    __shared__ float red[256];
    float mx = -INFINITY;
    for (int i = t; i < n4; i += 256) {
        float4 f = xr[i];
        mx = fmaxf(fmaxf(mx, fmaxf(f.x, f.y)), fmaxf(f.z, f.w));
    }
    red[t] = mx; __syncthreads();
    for (int off = 128; off; off >>= 1) { if (t < off) red[t] = fmaxf(red[t], red[t + off]); __syncthreads(); }
    mx = red[0]; __syncthreads();
    float4 ebuf[2];
    float s = 0.f;
    int nb = 0;
    for (int i = t; i < n4; i += 256) {
        float4 f = xr[i];
        f.x = expf(f.x - mx); f.y = expf(f.y - mx); f.z = expf(f.z - mx); f.w = expf(f.w - mx);
        ebuf[nb++] = f;
        s += f.x + f.y + f.z + f.w;
    }
    red[t] = s; __syncthreads();
    for (int off = 128; off; off >>= 1) { if (t < off) red[t] += red[t + off]; __syncthreads(); }
    s = red[0];
    nb = 0;
    for (int i = t; i < n4; i += 256) {
        float4 f = ebuf[nb++];
        f.x /= s; f.y /= s; f.z /= s; f.w /= s;
        s16x4 h, l;
        sh2 p;
        p = splitf(f.x); h[0] = p.hi; l[0] = p.lo;
        p = splitf(f.y); h[1] = p.hi; l[1] = p.lo;
        p = splitf(f.z); h[2] = p.hi; l[2] = p.lo;
        p = splitf(f.w); h[3] = p.hi; l[3] = p.lo;
        *(s16x4*)&phi[rb + i * 4] = h;
        *(s16x4*)&plo[rb + i * 4] = l;
    }
}

// logits[r] = H[r,:2048] . w2 + b2
__global__ __launch_bounds__(256) void gemv_kernel(
    const float* __restrict__ H, const float* __restrict__ w2,
    const float* __restrict__ b2, float* __restrict__ logits)
{
    const int r = blockIdx.x, t = threadIdx.x;
    const float* row = H + (long)r * 2048;
    float s = 0.f;
    for (int c = t; c < 2048; c += 256) s += row[c] * w2[c];
    __shared__ float red[256];
    red[t] = s; __syncthreads();
    for (int off = 128; off; off >>= 1) { if (t < off) red[t] += red[t + off]; __syncthreads(); }
    if (!t) logits[r] = red[0] + b2[0];
}

// exact lax.top_k: bitonic full sort, desc by val, ties idx asc. blockDim==n.
__global__ void topk_kernel(const float* __restrict__ vals, int n, int k, int* __restrict__ out)
{
    __shared__ float sv[1024];
    __shared__ int   si[1024];
    const int t = threadIdx.x;
    sv[t] = vals[t]; si[t] = t;
    for (int size = 2; size <= n; size <<= 1) {
        for (int stride = size >> 1; stride > 0; stride >>= 1) {
            __syncthreads();
            const int j = t ^ stride;
            if (j > t) {
                float av = sv[t], bv = sv[j];
                int ai = si[t], bi = si[j];
                const bool before = (av > bv) || (av == bv && ai < bi);
                const bool dir = ((t & size) == 0);
                if (dir ? !before : before) { sv[t] = bv; si[t] = bi; sv[j] = av; si[j] = ai; }
            }
        }
    }
    __syncthreads();
    if (t < k) out[t] = si[t];
}

__global__ void gather_sel_kernel(const int* __restrict__ idx1, const int* __restrict__ idx2,
                                  int* __restrict__ selidx)
{
    const int t = threadIdx.x;
    if (t < 256) selidx[t] = idx1[idx2[t]];
}

// complement of 256 selected indices within [0,1024), ascending
__global__ void complement_kernel(const int* __restrict__ selidx, int* __restrict__ remidx)
{
    __shared__ int mask[1024];
    __shared__ int scan[1024];
    const int t = threadIdx.x;
    mask[t] = 0;
    __syncthreads();
    if (t < 256) mask[selidx[t]] = 1;
    __syncthreads();
    const int keep = 1 - mask[t];
    scan[t] = keep;
    __syncthreads();
    for (int off = 1; off < 1024; off <<= 1) {
        int v = scan[t];
        if (t >= off) v += scan[t - off];
        __syncthreads();
        scan[t] = v;
        __syncthreads();
    }
    if (keep) remidx[scan[t] - 1] = t;
}

__global__ __launch_bounds__(256) void gather_rows_kernel(
    float* __restrict__ dst, const float* __restrict__ src,
    const int* __restrict__ map, int ncols)
{
    const int r = blockIdx.x;
    const int sr = map[r];
    const float4* s = (const float4*)(src + (long)sr * ncols);
    float4* d = (float4*)(dst + (long)r * ncols);
    for (int i = threadIdx.x; i < ncols / 4; i += 256) d[i] = s[i];
}

__global__ __launch_bounds__(256) void rownorm_kernel(
    const float* __restrict__ x, float* __restrict__ out)
{
    const int r = blockIdx.x, t = threadIdx.x;
    const float* row = x + (long)r * 4096;
    float s = 0.f;
    for (int c = t; c < 4096; c += 256) { float v = row[c]; s += v * v; }
    __shared__ float red[256];
    red[t] = s; __syncthreads();
    for (int off = 128; off; off >>= 1) { if (t < off) red[t] += red[t + off]; __syncthreads(); }
    if (!t) out[r] = sqrtf(red[0]);
}

__global__ __launch_bounds__(256) void argmax_kernel(
    const float* __restrict__ S, const float* __restrict__ nr,
    const float* __restrict__ ns, int* __restrict__ best)
{
    const int r = blockIdx.x, t = threadIdx.x;
    float v = S[(long)r * 256 + t] / fmaxf(nr[r] * ns[t], 1e-8f);
    __shared__ float bv[256];
    __shared__ int bi[256];
    bv[t] = v; bi[t] = t; __syncthreads();
    for (int off = 128; off; off >>= 1) {
        if (t < off) {
            float ov = bv[t + off]; int oi = bi[t + off];
            if (ov > bv[t] || (ov == bv[t] && oi < bi[t])) { bv[t] = ov; bi[t] = oi; }
        }
        __syncthreads();
    }
    if (!t) best[r] = bi[0];
}

__global__ __launch_bounds__(256) void merge_kernel(
    const float* __restrict__ selb, const float* __restrict__ rem,
    const int* __restrict__ best, const float* __restrict__ nr,
    const float* __restrict__ ns, float* __restrict__ out)
{
    const int j = blockIdx.x, t = threadIdx.x;
    __shared__ int sbest[768];
    __shared__ float snr[768];
    __shared__ float red[256];
    for (int i = t; i < 768; i += 256) { sbest[i] = best[i]; snr[i] = nr[i]; }
    __syncthreads();
    float acc[16];
#pragma unroll
    for (int d = 0; d < 16; d++) acc[d] = 0.f;
    int cnt = 0; float smax = 0.f;
    const int base = t * 16;
    for (int i = 0; i < 768; i++) {
        if (sbest[i] == j) {
            cnt++;
            smax = fmaxf(smax, snr[i]);
            const float* rp = rem + (long)i * 4096 + base;
#pragma unroll
            for (int d = 0; d < 16; d += 4) {
                float4 x4 = *(const float4*)(rp + d);
                acc[d] += x4.x; acc[d + 1] += x4.y; acc[d + 2] += x4.z; acc[d + 3] += x4.w;
            }
        }
    }
    const float* sp = selb + (long)j * 4096 + base;
    float mean[16]; float ss = 0.f;
    const float denom = (float)(cnt + 1);
#pragma unroll
    for (int d = 0; d < 16; d++) { mean[d] = (sp[d] + acc[d]) / denom; ss += mean[d] * mean[d]; }
    red[t] = ss; __syncthreads();
    for (int off = 128; off; off >>= 1) { if (t < off) red[t] += red[t + off]; __syncthreads(); }
    const float nm = sqrtf(red[0]);
    const float mx = fmaxf(ns[j], cnt > 0 ? smax : 0.f);
    float* op = out + (long)j * 4096 + base;
#pragma unroll
    for (int d = 0; d < 16; d++) op[d] = (cnt > 0) ? (mean[d] / nm) * mx : sp[d];
}

// ============================================================================
// host orchestration
// ============================================================================
extern "C" void kernel_launch(void* const* d_in, const int* in_sizes, int n_in,
                              void* d_out, int out_size, void* d_ws, size_t ws_size,
                              hipStream_t stream)
{
    const float* vf   = (const float*)d_in[0];   // 1024 x 4096
    const float* te   = (const float*)d_in[1];   // 128 x 4096
    const float* inw  = (const float*)d_in[3];   // 4 x 12288 x 4096
    const float* inb  = (const float*)d_in[4];   // 4 x 12288
    const float* outw = (const float*)d_in[5];   // 4 x 4096 x 4096
    const float* outb = (const float*)d_in[6];   // 4 x 4096
    const float* w1   = (const float*)d_in[7];   // 2 x 2048 x 4096
    const float* b1   = (const float*)d_in[8];   // 2 x 2048
    const float* w2   = (const float*)d_in[9];   // 2 x 2048
    const float* b2   = (const float*)d_in[10];  // 2
    float* out = (float*)d_out;                  // 256 x 4096
    char* base = (char*)d_ws;

    // regions (bytes): total 94,404,608 <= proven ws capacity
    char* qkR = base;                 // 37,748,736 : qk split / probs split / hbuf
    char* vTR = base + 37748736;      // 18,874,368 : vT split
    char* scR = vTR + 18874368;       // 37,748,736 : comb/scor/obuf/gbuf/final
    float* smalls = (float*)(scR + 37748736);    // 32 KiB of small buffers

    short* qkhi = (short*)qkR;
    short* qklo = (short*)(qkR + 18874368);
    short* vThi = (short*)vTR;
    short* vTlo = (short*)(vTR + 9437184);
    float* hbuf = (float*)qkR;

    float* logits = smalls;                      // 1024
    float* nr     = smalls + 1024;               // 768
    float* ns     = smalls + 1792;               // 256
    int* idx1   = (int*)(smalls + 2048);         // 512
    int* idx2   = (int*)(smalls + 2560);         // 256
    int* selidx = (int*)(smalls + 2816);         // 256
    int* remidx = (int*)(smalls + 3072);         // 768
    int* best   = (int*)(smalls + 3840);         // 768

    const float scl = (float)(1.0 / sqrt(512.0));

    for (int m = 0; m < 2; m++) {
        const int Mq  = m ? 512 : 1024;
        const int Mkv = m ? 640 : 1152;
        const float* Wqkv = inw + (size_t)(2 * m) * 12288 * 4096;
        const float* bqkv = inb + (size_t)(2 * m) * 12288;
        const float* ow = outw + (size_t)(2 * m) * 4096 * 4096;
        const float* ob = outb + (size_t)(2 * m) * 4096;

        // ---- comb split (A of in-proj), lives at scR head ----
        short* chi = (short*)scR;
        short* clo = (short*)(scR + (size_t)Mkv * 4096 * 2);
        if (m == 0) {
            split_rows<<<1024, 256, 0, stream>>>(vf, nullptr, chi, clo);
            split_rows<<<128, 256, 0, stream>>>(te, nullptr,
                chi + (size_t)1024 * 4096, clo + (size_t)1024 * 4096);
        } else {
            split_rows<<<512, 256, 0, stream>>>(vf, idx1, chi, clo);
            split_rows<<<128, 256, 0, stream>>>(te, nullptr,
                chi + (size_t)512 * 4096, clo + (size_t)512 * 4096);
        }
        // ---- fused in-proj: q,k -> qk split; v -> vT split (transposed) ----
        mfma_gemm<0, 2, false><<<dim3(96, Mkv / 128, 1), 256, 0, stream>>>(
            chi, clo, 4096, 0, Wqkv, nullptr, nullptr, 4096, 0,
            nullptr, qkhi, qklo, vThi, vTlo, 8192, 1152, 0, 4096, 1.f, bqkv);
        // ---- scores[h] = scl * q_h @ k_h^T (fp32) ----
        float* scor = (float*)(m ? (scR + 10485760) : scR);
        mfma_gemm<1, 0, false><<<dim3(Mkv / 128, Mq / 128, 8), 256, 0, stream>>>(
            qkhi, qklo, 8192, 512, nullptr, qkhi + 4096, qklo + 4096, 8192, 512,
            scor, nullptr, nullptr, nullptr, nullptr, Mkv, 0, (long)Mq * Mkv,
            512, scl, nullptr);
        // ---- softmax -> split probs (over qk region, qk now dead) ----
        short* phi = (short*)qkR;
        short* plo = (short*)(qkR + (size_t)8 * Mq * Mkv * 2);
        softmax_split<<<8 * Mq, 256, 0, stream>>>(scor, phi, plo, Mkv);
        // ---- PV: o = probs @ vT^T -> obuf split ----
        short* ohi = (short*)scR;
        short* olo = (short*)(scR + (size_t)Mq * 4096 * 2);
        mfma_gemm<1, 1, false><<<dim3(4, Mq / 128, 8), 256, 0, stream>>>(
            phi, plo, Mkv, (long)Mq * Mkv, nullptr, vThi, vTlo, 1152, 512L * 1152,
            nullptr, ohi, olo, nullptr, nullptr, 4096, 0, 512, Mkv, 1.f, nullptr);
        // ---- out-proj: g = o @ ow^T + ob -> gbuf split ----
        short* ghi = (short*)(scR + (size_t)Mq * 4096 * 4);
        short* glo = (short*)(scR + (size_t)Mq * 4096 * 6);
        mfma_gemm<0, 1, false><<<dim3(32, Mq / 128, 1), 256, 0, stream>>>(
            ohi, olo, 4096, 0, ow, nullptr, nullptr, 4096, 0,
            nullptr, ghi, glo, nullptr, nullptr, 4096, 0, 0, 4096, 1.f, ob);
        // ---- MLP: h = relu(g @ w1^T + b1) -> hbuf fp32 (qk region) ----
        mfma_gemm<0, 0, true><<<dim3(16, Mq / 128, 1), 256, 0, stream>>>(
            ghi, glo, 4096, 0, w1 + (size_t)m * 2048 * 4096, nullptr, nullptr, 4096, 0,
            hbuf, nullptr, nullptr, nullptr, nullptr, 2048, 0, 0, 4096, 1.f,
            b1 + (size_t)m * 2048);
        gemv_kernel<<<Mq, 256, 0, stream>>>(hbuf, w2 + (size_t)m * 2048, b2 + m, logits);
        if (m == 0) topk_kernel<<<1, 1024, 0, stream>>>(logits, 1024, 512, idx1);
        else        topk_kernel<<<1, 512, 0, stream>>>(logits, 512, 256, idx2);
    }

    // ---- merge phase ----
    short* remhi = (short*)scR;
    short* remlo = (short*)(scR + 6291456);
    short* selhi = (short*)(scR + 12582912);
    short* sello = (short*)(scR + 14680064);
    float* rem_f = (float*)(scR + 16777216);
    float* sel_f = (float*)(scR + 29360128);
    float* Smat  = (float*)(scR + 33554432);

    gather_sel_kernel<<<1, 256, 0, stream>>>(idx1, idx2, selidx);
    complement_kernel<<<1, 1024, 0, stream>>>(selidx, remidx);
    split_rows<<<768, 256, 0, stream>>>(vf, remidx, remhi, remlo);
    split_rows<<<256, 256, 0, stream>>>(vf, selidx, selhi, sello);
    gather_rows_kernel<<<768, 256, 0, stream>>>(rem_f, vf, remidx, 4096);
    gather_rows_kernel<<<256, 256, 0, stream>>>(sel_f, vf, selidx, 4096);
    rownorm_kernel<<<768, 256, 0, stream>>>(rem_f, nr);
    rownorm_kernel<<<256, 256, 0, stream>>>(sel_f, ns);
    mfma_gemm<1, 0, false><<<dim3(2, 6, 1), 256, 0, stream>>>(
        remhi, remlo, 4096, 0, nullptr, selhi, sello, 4096, 0,
        Smat, nullptr, nullptr, nullptr, nullptr, 256, 0, 0, 4096, 1.f, nullptr);
    argmax_kernel<<<768, 256, 0, stream>>>(Smat, nr, ns, best);
    merge_kernel<<<256, 256, 0, stream>>>(sel_f, rem_f, best, nr, ns, out);
}

// Round 7
// 1399.374 us; speedup vs baseline: 5.1448x; 1.2616x over previous
//
#include <hip/hip_runtime.h>
#include <hip/hip_bf16.h>
#include <math.h>
#include <stdint.h>

typedef __attribute__((ext_vector_type(4))) float f32x4;
typedef __attribute__((ext_vector_type(8))) short s16x8;
typedef __attribute__((ext_vector_type(4))) short s16x4;

struct sh2 { short hi, lo; };

// fp32 -> bf16 hi/lo split. hi = bf16(x) (RNE), lo = bf16(x - hi).
__device__ __forceinline__ sh2 splitf(float x)
{
    __hip_bfloat16 h = __float2bfloat16(x);
    float hf = __bfloat162float(h);
    __hip_bfloat16 l = __float2bfloat16(x - hf);
    sh2 r;
    r.hi = __builtin_bit_cast(short, h);
    r.lo = __builtin_bit_cast(short, l);
    return r;
}

// async global->LDS 16B copy (wave-uniform LDS base; lane writes base+lane*16)
typedef const __attribute__((address_space(1))) void gvoid_t;
typedef __attribute__((address_space(3))) void lvoid_t;
__device__ __forceinline__ void gld_lds16(const void* g, void* l)
{
    __builtin_amdgcn_global_load_lds((gvoid_t*)(uintptr_t)g,
                                     (lvoid_t*)(uintptr_t)l, 16, 0, 0);
}

// ============================================================================
// split-bf16 MFMA GEMM: C = alpha*(A @ B^T) [+bias] [ReLU]
// A pre-split (Ahi/Alo bf16, M x K). BF=0: B fp32 (N x K), split inline.
// BF=1: B pre-split. EPI=0 fp32 C [RELU]; EPI=1 split C; EPI=2 in-proj
// (cols<8192 -> split C; cols>=8192 -> split TRANSPOSED vT).
// Split-K: SK>1 -> blockIdx.z = batch*SK + sk; computes K/SK chunk and writes
// RAW fp32 partial (alpha applied, no bias/relu/split) at Cf + z*sC, ld=ldc.
// 2-phase double-buffered pipeline; one barrier per K-step; chunk-XOR bank
// swizzle on SOURCE address; XCD-chunked block swizzle.
// ============================================================================
template<int BF, int EPI, bool RELU>
__global__ __launch_bounds__(256, 2) void mfma_gemm(
    const short* __restrict__ Ahi, const short* __restrict__ Alo, int lda, long sA,
    const float* __restrict__ Bf, const short* __restrict__ Bhi,
    const short* __restrict__ Blo, int ldb, long sB,
    float* __restrict__ Cf, short* __restrict__ Chi, short* __restrict__ Clo,
    short* __restrict__ Thi, short* __restrict__ Tlo, int ldc, int ldT, long sC,
    int K, int SK, float alpha, const float* __restrict__ bias)
{
    __shared__ short SH[2][16384];
    const int zf = blockIdx.z;
    const int sk = (SK > 1) ? (zf % SK) : 0;
    const int bz = (SK > 1) ? (zf / SK) : zf;
    const int Kc = K / SK;            // chunk length (multiple of 32)
    const int kb = sk * Kc;
    Ahi += (long)bz * sA; Alo += (long)bz * sA;
    if (BF == 0) Bf += (long)bz * sB; else { Bhi += (long)bz * sB; Blo += (long)bz * sB; }
    const long cofs = (long)((SK > 1) ? zf : bz) * sC;

    // ---- bijective XCD-chunked swizzle, m-fastest decode (B-panel reuse) ----
    const int GX = gridDim.x, GY = gridDim.y;
    const int nwg = GX * GY;
    const int bid = blockIdx.x + GX * blockIdx.y;
    const int q8 = nwg >> 3, r8 = nwg & 7;
    const int xcd = bid & 7, sl = bid >> 3;
    const int t = (xcd < r8) ? (xcd * (q8 + 1) + sl)
                             : (r8 * (q8 + 1) + (xcd - r8) * q8 + sl);
    const int m0 = (t % GY) * 128, n0 = (t / GY) * 128;

    const int tid = threadIdx.x;
    const int lane = tid & 63, wave = tid >> 6;
    const int wr = (wave >> 1) * 64, wc = (wave & 1) * 64;
    const int lrow = lane & 15, lk = lane >> 4;
    const int cswz8 = (lk ^ ((lrow >> 1) & 3)) << 3;   // frag-read chunk swizzle

    // ---- gload_lds staging geometry (pre-split operands) ----
    const int rA0 = wave * 16 + (lane >> 2);
    const int rA1 = rA0 + 64;
    const int sc0 = ((lane & 3) ^ ((rA0 >> 1) & 3)) * 8;
    const int sc1 = ((lane & 3) ^ ((rA1 >> 1) & 3)) * 8;
    const long gA0 = (long)(m0 + rA0) * lda + sc0;
    const long gA1 = (long)(m0 + rA1) * lda + sc1;
    long gB0 = 0, gB1 = 0;
    if (BF == 1) {
        gB0 = (long)(n0 + rA0) * ldb + sc0;
        gB1 = (long)(n0 + rA1) * ldb + sc1;
    }
    const int lw0 = wave * 512, lw1 = wave * 512 + 2048;

    // ---- BF=0 fp32-B staging coords (issue-early/write-late) ----
    const int brow = tid & 127;
    const int bkc0 = (tid >> 7) * 8;
    const int bkc1 = bkc0 + 16;
    const int bw0 = brow * 32 + (((bkc0 >> 3) ^ ((brow >> 1) & 3)) << 3);
    const int bw1 = brow * 32 + (((bkc1 >> 3) ^ ((brow >> 1) & 3)) << 3);
    const float* bpr = (BF == 0) ? Bf + (long)(n0 + brow) * ldb : nullptr;

    f32x4 acc[4][4];
#pragma unroll
    for (int i = 0; i < 4; i++)
#pragma unroll
        for (int j = 0; j < 4; j++) acc[i][j] = (f32x4){0.f, 0.f, 0.f, 0.f};

    float4 rb0a, rb0b, rb1a, rb1b;

    // ================= prologue: stage chunk-first tile into buf 0 =========
    {
        short* S = &SH[0][0];
        gld_lds16(Ahi + gA0 + kb, S + lw0);
        gld_lds16(Ahi + gA1 + kb, S + lw1);
        gld_lds16(Alo + gA0 + kb, S + 4096 + lw0);
        gld_lds16(Alo + gA1 + kb, S + 4096 + lw1);
        if constexpr (BF == 1) {
            gld_lds16(Bhi + gB0 + kb, S + 8192 + lw0);
            gld_lds16(Bhi + gB1 + kb, S + 8192 + lw1);
            gld_lds16(Blo + gB0 + kb, S + 12288 + lw0);
            gld_lds16(Blo + gB1 + kb, S + 12288 + lw1);
        } else {
            rb0a = *(const float4*)(bpr + kb + bkc0);
            rb0b = *(const float4*)(bpr + kb + bkc0 + 4);
            rb1a = *(const float4*)(bpr + kb + bkc1);
            rb1b = *(const float4*)(bpr + kb + bkc1 + 4);
            s16x8 h, l; sh2 p;
            p = splitf(rb0a.x); h[0] = p.hi; l[0] = p.lo;
            p = splitf(rb0a.y); h[1] = p.hi; l[1] = p.lo;
            p = splitf(rb0a.z); h[2] = p.hi; l[2] = p.lo;
            p = splitf(rb0a.w); h[3] = p.hi; l[3] = p.lo;
            p = splitf(rb0b.x); h[4] = p.hi; l[4] = p.lo;
            p = splitf(rb0b.y); h[5] = p.hi; l[5] = p.lo;
            p = splitf(rb0b.z); h[6] = p.hi; l[6] = p.lo;
            p = splitf(rb0b.w); h[7] = p.hi; l[7] = p.lo;
            *(s16x8*)&S[8192 + bw0] = h;
            *(s16x8*)&S[12288 + bw0] = l;
            p = splitf(rb1a.x); h[0] = p.hi; l[0] = p.lo;
            p = splitf(rb1a.y); h[1] = p.hi; l[1] = p.lo;
            p = splitf(rb1a.z); h[2] = p.hi; l[2] = p.lo;
            p = splitf(rb1a.w); h[3] = p.hi; l[3] = p.lo;
            p = splitf(rb1b.x); h[4] = p.hi; l[4] = p.lo;
            p = splitf(rb1b.y); h[5] = p.hi; l[5] = p.lo;
            p = splitf(rb1b.z); h[6] = p.hi; l[6] = p.lo;
            p = splitf(rb1b.w); h[7] = p.hi; l[7] = p.lo;
            *(s16x8*)&S[8192 + bw1] = h;
            *(s16x8*)&S[12288 + bw1] = l;
        }
    }
    __syncthreads();

    // ========================== main K loop ==========================
    int cur = 0;
    const int kend = kb + Kc;
    for (int k0 = kb; k0 < kend; k0 += 32) {
        const int kn = k0 + 32;
        const bool nx = (kn < kend);
        short* SN = &SH[cur ^ 1][0];
        if (nx) {
            gld_lds16(Ahi + gA0 + kn, SN + lw0);
            gld_lds16(Ahi + gA1 + kn, SN + lw1);
            gld_lds16(Alo + gA0 + kn, SN + 4096 + lw0);
            gld_lds16(Alo + gA1 + kn, SN + 4096 + lw1);
            if constexpr (BF == 1) {
                gld_lds16(Bhi + gB0 + kn, SN + 8192 + lw0);
                gld_lds16(Bhi + gB1 + kn, SN + 8192 + lw1);
                gld_lds16(Blo + gB0 + kn, SN + 12288 + lw0);
                gld_lds16(Blo + gB1 + kn, SN + 12288 + lw1);
            } else {
                rb0a = *(const float4*)(bpr + kn + bkc0);
                rb0b = *(const float4*)(bpr + kn + bkc0 + 4);
                rb1a = *(const float4*)(bpr + kn + bkc1);
                rb1b = *(const float4*)(bpr + kn + bkc1 + 4);
            }
        }
        const short* S = &SH[cur][0];
        s16x8 ah[4], al[4];
#pragma unroll
        for (int m = 0; m < 4; m++) {
            const int idx = (wr + m * 16 + lrow) * 32 + cswz8;
            ah[m] = *(const s16x8*)&S[idx];
            al[m] = *(const s16x8*)&S[4096 + idx];
        }
#pragma unroll
        for (int n = 0; n < 4; n++) {
            const int idx = (wc + n * 16 + lrow) * 32 + cswz8;
            const s16x8 bh = *(const s16x8*)&S[8192 + idx];
            const s16x8 bl = *(const s16x8*)&S[12288 + idx];
#pragma unroll
            for (int m = 0; m < 4; m++) {
                acc[m][n] = __builtin_amdgcn_mfma_f32_16x16x32_bf16(ah[m], bh, acc[m][n], 0, 0, 0);
                acc[m][n] = __builtin_amdgcn_mfma_f32_16x16x32_bf16(ah[m], bl, acc[m][n], 0, 0, 0);
                acc[m][n] = __builtin_amdgcn_mfma_f32_16x16x32_bf16(al[m], bh, acc[m][n], 0, 0, 0);
            }
        }
        if (BF == 0 && nx) {
            s16x8 h, l; sh2 p;
            p = splitf(rb0a.x); h[0] = p.hi; l[0] = p.lo;
            p = splitf(rb0a.y); h[1] = p.hi; l[1] = p.lo;
            p = splitf(rb0a.z); h[2] = p.hi; l[2] = p.lo;
            p = splitf(rb0a.w); h[3] = p.hi; l[3] = p.lo;
            p = splitf(rb0b.x); h[4] = p.hi; l[4] = p.lo;
            p = splitf(rb0b.y); h[5] = p.hi; l[5] = p.lo;
            p = splitf(rb0b.z); h[6] = p.hi; l[6] = p.lo;
            p = splitf(rb0b.w); h[7] = p.hi; l[7] = p.lo;
            *(s16x8*)&SN[8192 + bw0] = h;
            *(s16x8*)&SN[12288 + bw0] = l;
            p = splitf(rb1a.x); h[0] = p.hi; l[0] = p.lo;
            p = splitf(rb1a.y); h[1] = p.hi; l[1] = p.lo;
            p = splitf(rb1a.z); h[2] = p.hi; l[2] = p.lo;
            p = splitf(rb1a.w); h[3] = p.hi; l[3] = p.lo;
            p = splitf(rb1b.x); h[4] = p.hi; l[4] = p.lo;
            p = splitf(rb1b.y); h[5] = p.hi; l[5] = p.lo;
            p = splitf(rb1b.z); h[6] = p.hi; l[6] = p.lo;
            p = splitf(rb1b.w); h[7] = p.hi; l[7] = p.lo;
            *(s16x8*)&SN[8192 + bw1] = h;
            *(s16x8*)&SN[12288 + bw1] = l;
        }
        __syncthreads();
        cur ^= 1;
    }
    // ---- epilogue: C/D layout col=lane&15, row=(lane>>4)*4+r ----
#pragma unroll
    for (int n = 0; n < 4; n++) {
        const int col = n0 + wc + n * 16 + lrow;
        const float bv = (SK == 1 && bias) ? bias[col] : 0.f;
#pragma unroll
        for (int m = 0; m < 4; m++) {
            const int row = m0 + wr + m * 16 + lk * 4;
            if (SK > 1) {
                // raw fp32 partial (alpha applied, no bias/relu/split)
#pragma unroll
                for (int r = 0; r < 4; r++)
                    Cf[cofs + (long)(row + r) * ldc + col] = acc[m][n][r] * alpha;
            } else if constexpr (EPI == 0) {
#pragma unroll
                for (int r = 0; r < 4; r++) {
                    float v = acc[m][n][r] * alpha + bv;
                    if (RELU) v = fmaxf(v, 0.f);
                    Cf[cofs + (long)(row + r) * ldc + col] = v;
                }
            } else if constexpr (EPI == 1) {
#pragma unroll
                for (int r = 0; r < 4; r++) {
                    float v = acc[m][n][r] * alpha + bv;
                    sh2 p = splitf(v);
                    Chi[cofs + (long)(row + r) * ldc + col] = p.hi;
                    Clo[cofs + (long)(row + r) * ldc + col] = p.lo;
                }
            } else {
                if (n0 < 8192) {
#pragma unroll
                    for (int r = 0; r < 4; r++) {
                        float v = acc[m][n][r] + bv;
                        sh2 p = splitf(v);
                        Chi[(long)(row + r) * ldc + col] = p.hi;
                        Clo[(long)(row + r) * ldc + col] = p.lo;
                    }
                } else {
                    s16x4 h4, l4;
#pragma unroll
                    for (int r = 0; r < 4; r++) {
                        float v = acc[m][n][r] + bv;
                        sh2 p = splitf(v);
                        h4[r] = p.hi; l4[r] = p.lo;
                    }
                    const long tof = (long)(col - 8192) * ldT + row;
                    *(s16x4*)&Thi[tof] = h4;
                    *(s16x4*)&Tlo[tof] = l4;
                }
            }
        }
    }
}

// ============================================================================
// split-K reducer: sums SK partials (zstride apart) in fixed order, applies
// epilogue. grid (total/1024, BZ). Per-batch output col offset = colstep*bz.
// ============================================================================
template<int EPI, bool RELU>
__global__ __launch_bounds__(256) void reduce_k(
    const float* __restrict__ P, long zstride, int SK, int total,
    int Ninner, int ldc, int colstep,
    float* __restrict__ Cf, short* __restrict__ Chi, short* __restrict__ Clo,
    const float* __restrict__ bias)
{
    const int bz = blockIdx.y;
    const long pbase = (long)bz * SK * zstride;
    const int e = (blockIdx.x * 256 + threadIdx.x) * 4;
    if (e >= total) return;
    const float* p = P + pbase + e;
    float4 s = *(const float4*)p;
    for (int k = 1; k < SK; k++) {
        float4 tv = *(const float4*)(p + (long)k * zstride);
        s.x += tv.x; s.y += tv.y; s.z += tv.z; s.w += tv.w;
    }
    const int r = e / Ninner, c = e % Ninner;
    const int col0 = colstep * bz + c;
    const long ob = (long)r * ldc + col0;
    float v[4] = {s.x, s.y, s.z, s.w};
#pragma unroll
    for (int j = 0; j < 4; j++) {
        float x = v[j] + (bias ? bias[col0 + j] : 0.f);
        if (RELU) x = fmaxf(x, 0.f);
        if constexpr (EPI == 0) {
            Cf[ob + j] = x;
        } else {
            sh2 pp = splitf(x);
            Chi[ob + j] = pp.hi;
            Clo[ob + j] = pp.lo;
        }
    }
}

// ============================================================================
// split rows: dhi/dlo[r,:4096] = split(src[map? map[r] : r, :4096])
// ============================================================================
__global__ __launch_bounds__(256) void split_rows(
    const float* __restrict__ src, const int* __restrict__ map,
    short* __restrict__ dhi, short* __restrict__ dlo)
{
    const int r = blockIdx.x;
    const int sr = map ? map[r] : r;
    const float4* s = (const float4*)(src + (long)sr * 4096);
    const long db = (long)r * 4096;
    for (int i = threadIdx.x; i < 1024; i += 256) {
        float4 f = s[i];
        s16x4 h, l;
        sh2 p;
        p = splitf(f.x); h[0] = p.hi; l[0] = p.lo;
        p = splitf(f.y); h[1] = p.hi; l[1] = p.lo;
        p = splitf(f.z); h[2] = p.hi; l[2] = p.lo;
        p = splitf(f.w); h[3] = p.hi; l[3] = p.lo;
        *(s16x4*)&dhi[db + i * 4] = h;
        *(s16x4*)&dlo[db + i * 4] = l;
    }
}

// ============================================================================
// row softmax (jax.nn.softmax: exp(x-max)/sum, exact div) -> split probs
// ============================================================================
__global__ __launch_bounds__(256) void softmax_split(
    const float* __restrict__ x, short* __restrict__ phi, short* __restrict__ plo,
    int cols)
{
    const long rb = (long)blockIdx.x * cols;
    const float4* xr = (const float4*)(x + rb);
    const int t = threadIdx.x;
    const int n4 = cols >> 2;
    __shared__ float red[256];
    float mx = -INFINITY;
    for (int i = t; i < n4; i += 256) {
        float4 f = xr[i];
        mx = fmaxf(fmaxf(mx, fmaxf(f.x, f.y)), fmaxf(f.z, f.w));
    }
    red[t] = mx; __syncthreads();
    for (int off = 128; off; off >>= 1) { if (t < off) red[t] = fmaxf(red[t], red[t + off]); __syncthreads(); }
    mx = red[0]; __syncthreads();
    float4 ebuf[2];
    float s = 0.f;
    int nb = 0;
    for (int i = t; i < n4; i += 256) {
        float4 f = xr[i];
        f.x = expf(f.x - mx); f.y = expf(f.y - mx); f.z = expf(f.z - mx); f.w = expf(f.w - mx);
        ebuf[nb++] = f;
        s += f.x + f.y + f.z + f.w;
    }
    red[t] = s; __syncthreads();
    for (int off = 128; off; off >>= 1) { if (t < off) red[t] += red[t + off]; __syncthreads(); }
    s = red[0];
    nb = 0;
    for (int i = t; i < n4; i += 256) {
        float4 f = ebuf[nb++];
        f.x /= s; f.y /= s; f.z /= s; f.w /= s;
        s16x4 h, l;
        sh2 p;
        p = splitf(f.x); h[0] = p.hi; l[0] = p.lo;
        p = splitf(f.y); h[1] = p.hi; l[1] = p.lo;
        p = splitf(f.z); h[2] = p.hi; l[2] = p.lo;
        p = splitf(f.w); h[3] = p.hi; l[3] = p.lo;
        *(s16x4*)&phi[rb + i * 4] = h;
        *(s16x4*)&plo[rb + i * 4] = l;
    }
}

// logits[r] = H[r,:2048] . w2 + b2
__global__ __launch_bounds__(256) void gemv_kernel(
    const float* __restrict__ H, const float* __restrict__ w2,
    const float* __restrict__ b2, float* __restrict__ logits)
{
    const int r = blockIdx.x, t = threadIdx.x;
    const float* row = H + (long)r * 2048;
    float s = 0.f;
    for (int c = t; c < 2048; c += 256) s += row[c] * w2[c];
    __shared__ float red[256];
    red[t] = s; __syncthreads();
    for (int off = 128; off; off >>= 1) { if (t < off) red[t] += red[t + off]; __syncthreads(); }
    if (!t) logits[r] = red[0] + b2[0];
}

// exact lax.top_k: bitonic full sort, desc by val, ties idx asc. blockDim==n.
__global__ void topk_kernel(const float* __restrict__ vals, int n, int k, int* __restrict__ out)
{
    __shared__ float sv[1024];
    __shared__ int   si[1024];
    const int t = threadIdx.x;
    sv[t] = vals[t]; si[t] = t;
    for (int size = 2; size <= n; size <<= 1) {
        for (int stride = size >> 1; stride > 0; stride >>= 1) {
            __syncthreads();
            const int j = t ^ stride;
            if (j > t) {
                float av = sv[t], bv = sv[j];
                int ai = si[t], bi = si[j];
                const bool before = (av > bv) || (av == bv && ai < bi);
                const bool dir = ((t & size) == 0);
                if (dir ? !before : before) { sv[t] = bv; si[t] = bi; sv[j] = av; si[j] = ai; }
            }
        }
    }
    __syncthreads();
    if (t < k) out[t] = si[t];
}

__global__ void gather_sel_kernel(const int* __restrict__ idx1, const int* __restrict__ idx2,
                                  int* __restrict__ selidx)
{
    const int t = threadIdx.x;
    if (t < 256) selidx[t] = idx1[idx2[t]];
}

// complement of 256 selected indices within [0,1024), ascending
__global__ void complement_kernel(const int* __restrict__ selidx, int* __restrict__ remidx)
{
    __shared__ int mask[1024];
    __shared__ int scan[1024];
    const int t = threadIdx.x;
    mask[t] = 0;
    __syncthreads();
    if (t < 256) mask[selidx[t]] = 1;
    __syncthreads();
    const int keep = 1 - mask[t];
    scan[t] = keep;
    __syncthreads();
    for (int off = 1; off < 1024; off <<= 1) {
        int v = scan[t];
        if (t >= off) v += scan[t - off];
        __syncthreads();
        scan[t] = v;
        __syncthreads();
    }
    if (keep) remidx[scan[t] - 1] = t;
}

__global__ __launch_bounds__(256) void gather_rows_kernel(
    float* __restrict__ dst, const float* __restrict__ src,
    const int* __restrict__ map, int ncols)
{
    const int r = blockIdx.x;
    const int sr = map[r];
    const float4* s = (const float4*)(src + (long)sr * ncols);
    float4* d = (float4*)(dst + (long)r * ncols);
    for (int i = threadIdx.x; i < ncols / 4; i += 256) d[i] = s[i];
}

__global__ __launch_bounds__(256) void rownorm_kernel(
    const float* __restrict__ x, float* __restrict__ out)
{
    const int r = blockIdx.x, t = threadIdx.x;
    const float* row = x + (long)r * 4096;
    float s = 0.f;
    for (int c = t; c < 4096; c += 256) { float v = row[c]; s += v * v; }
    __shared__ float red[256];
    red[t] = s; __syncthreads();
    for (int off = 128; off; off >>= 1) { if (t < off) red[t] += red[t + off]; __syncthreads(); }
    if (!t) out[r] = sqrtf(red[0]);
}

__global__ __launch_bounds__(256) void argmax_kernel(
    const float* __restrict__ S, const float* __restrict__ nr,
    const float* __restrict__ ns, int* __restrict__ best)
{
    const int r = blockIdx.x, t = threadIdx.x;
    float v = S[(long)r * 256 + t] / fmaxf(nr[r] * ns[t], 1e-8f);
    __shared__ float bv[256];
    __shared__ int bi[256];
    bv[t] = v; bi[t] = t; __syncthreads();
    for (int off = 128; off; off >>= 1) {
        if (t < off) {
            float ov = bv[t + off]; int oi = bi[t + off];
            if (ov > bv[t] || (ov == bv[t] && oi < bi[t])) { bv[t] = ov; bi[t] = oi; }
        }
        __syncthreads();
    }
    if (!t) best[r] = bi[0];
}

__global__ __launch_bounds__(256) void merge_kernel(
    const float* __restrict__ selb, const float* __restrict__ rem,
    const int* __restrict__ best, const float* __restrict__ nr,
    const float* __restrict__ ns, float* __restrict__ out)
{
    const int j = blockIdx.x, t = threadIdx.x;
    __shared__ int sbest[768];
    __shared__ float snr[768];
    __shared__ float red[256];
    for (int i = t; i < 768; i += 256) { sbest[i] = best[i]; snr[i] = nr[i]; }
    __syncthreads();
    float acc[16];
#pragma unroll
    for (int d = 0; d < 16; d++) acc[d] = 0.f;
    int cnt = 0; float smax = 0.f;
    const int base = t * 16;
    for (int i = 0; i < 768; i++) {
        if (sbest[i] == j) {
            cnt++;
            smax = fmaxf(smax, snr[i]);
            const float* rp = rem + (long)i * 4096 + base;
#pragma unroll
            for (int d = 0; d < 16; d += 4) {
                float4 x4 = *(const float4*)(rp + d);
                acc[d] += x4.x; acc[d + 1] += x4.y; acc[d + 2] += x4.z; acc[d + 3] += x4.w;
            }
        }
    }
    const float* sp = selb + (long)j * 4096 + base;
    float mean[16]; float ss = 0.f;
    const float denom = (float)(cnt + 1);
#pragma unroll
    for (int d = 0; d < 16; d++) { mean[d] = (sp[d] + acc[d]) / denom; ss += mean[d] * mean[d]; }
    red[t] = ss; __syncthreads();
    for (int off = 128; off; off >>= 1) { if (t < off) red[t] += red[t + off]; __syncthreads(); }
    const float nm = sqrtf(red[0]);
    const float mx = fmaxf(ns[j], cnt > 0 ? smax : 0.f);
    float* op = out + (long)j * 4096 + base;
#pragma unroll
    for (int d = 0; d < 16; d++) op[d] = (cnt > 0) ? (mean[d] / nm) * mx : sp[d];
}

// ============================================================================
// host orchestration
// ============================================================================
extern "C" void kernel_launch(void* const* d_in, const int* in_sizes, int n_in,
                              void* d_out, int out_size, void* d_ws, size_t ws_size,
                              hipStream_t stream)
{
    const float* vf   = (const float*)d_in[0];   // 1024 x 4096
    const float* te   = (const float*)d_in[1];   // 128 x 4096
    const float* inw  = (const float*)d_in[3];   // 4 x 12288 x 4096
    const float* inb  = (const float*)d_in[4];   // 4 x 12288
    const float* outw = (const float*)d_in[5];   // 4 x 4096 x 4096
    const float* outb = (const float*)d_in[6];   // 4 x 4096
    const float* w1   = (const float*)d_in[7];   // 2 x 2048 x 4096
    const float* b1   = (const float*)d_in[8];   // 2 x 2048
    const float* w2   = (const float*)d_in[9];   // 2 x 2048
    const float* b2   = (const float*)d_in[10];  // 2
    float* out = (float*)d_out;                  // 256 x 4096
    char* base = (char*)d_ws;

    // regions (bytes): total 94,404,608 <= proven ws capacity
    char* qkR = base;                 // 37,748,736 : qk split / probs / partials
    char* vTR = base + 37748736;      // 18,874,368 : vT split
    char* scR = vTR + 18874368;       // 37,748,736 : comb/scor/o/g/hbuf/final
    float* smalls = (float*)(scR + 37748736);    // 32 KiB of small buffers

    short* qkhi = (short*)qkR;
    short* qklo = (short*)(qkR + 18874368);
    short* vThi = (short*)vTR;
    short* vTlo = (short*)(vTR + 9437184);
    float* hbuf = (float*)scR;   // MLP out: scR head is dead by MLP time

    float* logits = smalls;                      // 1024
    float* nr     = smalls + 1024;               // 768
    float* ns     = smalls + 1792;               // 256
    int* idx1   = (int*)(smalls + 2048);         // 512
    int* idx2   = (int*)(smalls + 2560);         // 256
    int* selidx = (int*)(smalls + 2816);         // 256
    int* remidx = (int*)(smalls + 3072);         // 768
    int* best   = (int*)(smalls + 3840);         // 768

    const float scl = (float)(1.0 / sqrt(512.0));

    for (int m = 0; m < 2; m++) {
        const int Mq  = m ? 512 : 1024;
        const int Mkv = m ? 640 : 1152;
        const float* Wqkv = inw + (size_t)(2 * m) * 12288 * 4096;
        const float* bqkv = inb + (size_t)(2 * m) * 12288;
        const float* ow = outw + (size_t)(2 * m) * 4096 * 4096;
        const float* ob = outb + (size_t)(2 * m) * 4096;

        // ---- comb split (A of in-proj), lives at scR head ----
        short* chi = (short*)scR;
        short* clo = (short*)(scR + (size_t)Mkv * 4096 * 2);
        if (m == 0) {
            split_rows<<<1024, 256, 0, stream>>>(vf, nullptr, chi, clo);
            split_rows<<<128, 256, 0, stream>>>(te, nullptr,
                chi + (size_t)1024 * 4096, clo + (size_t)1024 * 4096);
        } else {
            split_rows<<<512, 256, 0, stream>>>(vf, idx1, chi, clo);
            split_rows<<<128, 256, 0, stream>>>(te, nullptr,
                chi + (size_t)512 * 4096, clo + (size_t)512 * 4096);
        }
        // ---- fused in-proj: q,k -> qk split; v -> vT split (transposed) ----
        mfma_gemm<0, 2, false><<<dim3(96, Mkv / 128, 1), 256, 0, stream>>>(
            chi, clo, 4096, 0, Wqkv, nullptr, nullptr, 4096, 0,
            nullptr, qkhi, qklo, vThi, vTlo, 8192, 1152, 0, 4096, 1, 1.f, bqkv);
        // ---- scores[h] = scl * q_h @ k_h^T (fp32) ----
        float* scor = (float*)(m ? (scR + 10485760) : scR);
        mfma_gemm<1, 0, false><<<dim3(Mkv / 128, Mq / 128, 8), 256, 0, stream>>>(
            qkhi, qklo, 8192, 512, nullptr, qkhi + 4096, qklo + 4096, 8192, 512,
            scor, nullptr, nullptr, nullptr, nullptr, Mkv, 0, (long)Mq * Mkv,
            512, 1, scl, nullptr);
        // ---- softmax -> split probs (qk region; qk dead after QK) ----
        short* phi = (short*)qkR;
        short* plo = (short*)(qkR + (size_t)8 * Mq * Mkv * 2);
        softmax_split<<<8 * Mq, 256, 0, stream>>>(scor, phi, plo, Mkv);
        // ---- PV: o = probs @ vT^T -> obuf split ----
        short* ohi = (short*)scR;
        short* olo = (short*)(scR + (size_t)Mq * 4096 * 2);
        if (m == 0) {
            mfma_gemm<1, 1, false><<<dim3(4, 8, 8), 256, 0, stream>>>(
                phi, plo, Mkv, (long)Mq * Mkv, nullptr, vThi, vTlo, 1152, 512L * 1152,
                nullptr, ohi, olo, nullptr, nullptr, 4096, 0, 512, Mkv, 1, 1.f, nullptr);
        } else {
            // split-K=2: partials at qkR+20MB (probs live below), 16 x 512x512
            float* Ppv = (float*)(qkR + 20971520);
            mfma_gemm<1, 0, false><<<dim3(4, 4, 16), 256, 0, stream>>>(
                phi, plo, Mkv, (long)Mq * Mkv, nullptr, vThi, vTlo, 1152, 512L * 1152,
                Ppv, nullptr, nullptr, nullptr, nullptr, 512, 0, 262144,
                Mkv, 2, 1.f, nullptr);
            reduce_k<1, false><<<dim3(256, 8), 256, 0, stream>>>(
                Ppv, 262144, 2, 262144, 512, 4096, 512, nullptr, ohi, olo, nullptr);
        }
        // ---- out-proj: g = o @ ow^T + ob -> gbuf split (split-K=2) ----
        short* ghi = (short*)(scR + (size_t)Mq * 4096 * 4);
        short* glo = (short*)(scR + (size_t)Mq * 4096 * 6);
        {
            float* Pg = (float*)qkR;             // probs dead now
            const long zst = (long)Mq * 4096;
            mfma_gemm<0, 0, false><<<dim3(32, Mq / 128, 2), 256, 0, stream>>>(
                ohi, olo, 4096, 0, ow, nullptr, nullptr, 4096, 0,
                Pg, nullptr, nullptr, nullptr, nullptr, 4096, 0, zst,
                4096, 2, 1.f, nullptr);
            reduce_k<1, false><<<dim3((int)(zst / 1024), 1), 256, 0, stream>>>(
                Pg, zst, 2, (int)zst, 4096, 4096, 0, nullptr, ghi, glo, ob);
        }
        // ---- MLP: h = relu(g @ w1^T + b1) -> hbuf fp32 (split-K=4) ----
        {
            float* Pm = (float*)(qkR + 8388608);
            const long zst = (long)Mq * 2048;
            mfma_gemm<0, 0, false><<<dim3(16, Mq / 128, 4), 256, 0, stream>>>(
                ghi, glo, 4096, 0, w1 + (size_t)m * 2048 * 4096, nullptr, nullptr, 4096, 0,
                Pm, nullptr, nullptr, nullptr, nullptr, 2048, 0, zst,
                4096, 4, 1.f, nullptr);
            reduce_k<0, true><<<dim3((int)(zst / 1024), 1), 256, 0, stream>>>(
                Pm, zst, 4, (int)zst, 2048, 2048, 0, hbuf, nullptr, nullptr,
                b1 + (size_t)m * 2048);
        }
        gemv_kernel<<<Mq, 256, 0, stream>>>(hbuf, w2 + (size_t)m * 2048, b2 + m, logits);
        if (m == 0) topk_kernel<<<1, 1024, 0, stream>>>(logits, 1024, 512, idx1);
        else        topk_kernel<<<1, 512, 0, stream>>>(logits, 512, 256, idx2);
    }

    // ---- merge phase ----
    short* remhi = (short*)scR;
    short* remlo = (short*)(scR + 6291456);
    short* selhi = (short*)(scR + 12582912);
    short* sello = (short*)(scR + 14680064);
    float* rem_f = (float*)(scR + 16777216);
    float* sel_f = (float*)(scR + 29360128);
    float* Smat  = (float*)(scR + 33554432);

    gather_sel_kernel<<<1, 256, 0, stream>>>(idx1, idx2, selidx);
    complement_kernel<<<1, 1024, 0, stream>>>(selidx, remidx);
    split_rows<<<768, 256, 0, stream>>>(vf, remidx, remhi, remlo);
    split_rows<<<256, 256, 0, stream>>>(vf, selidx, selhi, sello);
    gather_rows_kernel<<<768, 256, 0, stream>>>(rem_f, vf, remidx, 4096);
    gather_rows_kernel<<<256, 256, 0, stream>>>(sel_f, vf, selidx, 4096);
    rownorm_kernel<<<768, 256, 0, stream>>>(rem_f, nr);
    rownorm_kernel<<<256, 256, 0, stream>>>(sel_f, ns);
    // S = rem @ selb^T (split-K=8: 12 -> 96 blocks)
    {
        float* Ps = (float*)qkR;
        mfma_gemm<1, 0, false><<<dim3(2, 6, 8), 256, 0, stream>>>(
            remhi, remlo, 4096, 0, nullptr, selhi, sello, 4096, 0,
            Ps, nullptr, nullptr, nullptr, nullptr, 256, 0, 196608,
            4096, 8, 1.f, nullptr);
        reduce_k<0, false><<<dim3(192, 1), 256, 0, stream>>>(
            Ps, 196608, 8, 196608, 256, 256, 0, Smat, nullptr, nullptr, nullptr);
    }
    argmax_kernel<<<768, 256, 0, stream>>>(Smat, nr, ns, best);
    merge_kernel<<<256, 256, 0, stream>>>(sel_f, rem_f, best, nr, ns, out);
}

// Round 8
// 1301.191 us; speedup vs baseline: 5.5330x; 1.0755x over previous
//
#include <hip/hip_runtime.h>
#include <hip/hip_bf16.h>
#include <math.h>
#include <stdint.h>

typedef __attribute__((ext_vector_type(4))) float f32x4;
typedef __attribute__((ext_vector_type(8))) short s16x8;
typedef __attribute__((ext_vector_type(4))) short s16x4;

struct sh2 { short hi, lo; };

// fp32 -> bf16 hi/lo split. hi = bf16(x) (RNE), lo = bf16(x - hi).
__device__ __forceinline__ sh2 splitf(float x)
{
    __hip_bfloat16 h = __float2bfloat16(x);
    float hf = __bfloat162float(h);
    __hip_bfloat16 l = __float2bfloat16(x - hf);
    sh2 r;
    r.hi = __builtin_bit_cast(short, h);
    r.lo = __builtin_bit_cast(short, l);
    return r;
}

__device__ __forceinline__ void split8(const float4& a, const float4& b,
                                       s16x8& h, s16x8& l)
{
    sh2 p;
    p = splitf(a.x); h[0] = p.hi; l[0] = p.lo;
    p = splitf(a.y); h[1] = p.hi; l[1] = p.lo;
    p = splitf(a.z); h[2] = p.hi; l[2] = p.lo;
    p = splitf(a.w); h[3] = p.hi; l[3] = p.lo;
    p = splitf(b.x); h[4] = p.hi; l[4] = p.lo;
    p = splitf(b.y); h[5] = p.hi; l[5] = p.lo;
    p = splitf(b.z); h[6] = p.hi; l[6] = p.lo;
    p = splitf(b.w); h[7] = p.hi; l[7] = p.lo;
}

// async global->LDS 16B copy (wave-uniform LDS base; lane writes base+lane*16)
typedef const __attribute__((address_space(1))) void gvoid_t;
typedef __attribute__((address_space(3))) void lvoid_t;
__device__ __forceinline__ void gld_lds16(const void* g, void* l)
{
    __builtin_amdgcn_global_load_lds((gvoid_t*)(uintptr_t)g,
                                     (lvoid_t*)(uintptr_t)l, 16, 0, 0);
}

// ============================================================================
// split-bf16 MFMA GEMM (128x128 tile): C = alpha*(A @ B^T) [+bias] [ReLU]
// A pre-split. BF=0: B fp32 (N x K), split inline. BF=1: B pre-split.
// EPI=0 fp32 C [RELU]; EPI=1 split C; EPI=2 in-proj (q/k split C, v split
// TRANSPOSED vT). Split-K: SK>1 writes raw fp32 partials.
// 2-phase double-buffered; chunk-XOR bank swizzle on SOURCE; XCD block swizzle.
// ============================================================================
template<int BF, int EPI, bool RELU>
__global__ __launch_bounds__(256, 2) void mfma_gemm(
    const short* __restrict__ Ahi, const short* __restrict__ Alo, int lda, long sA,
    const float* __restrict__ Bf, const short* __restrict__ Bhi,
    const short* __restrict__ Blo, int ldb, long sB,
    float* __restrict__ Cf, short* __restrict__ Chi, short* __restrict__ Clo,
    short* __restrict__ Thi, short* __restrict__ Tlo, int ldc, int ldT, long sC,
    int K, int SK, float alpha, const float* __restrict__ bias)
{
    __shared__ short SH[2][16384];
    const int zf = blockIdx.z;
    const int sk = (SK > 1) ? (zf % SK) : 0;
    const int bz = (SK > 1) ? (zf / SK) : zf;
    const int Kc = K / SK;
    const int kb = sk * Kc;
    Ahi += (long)bz * sA; Alo += (long)bz * sA;
    if (BF == 0) Bf += (long)bz * sB; else { Bhi += (long)bz * sB; Blo += (long)bz * sB; }
    const long cofs = (long)((SK > 1) ? zf : bz) * sC;

    const int GX = gridDim.x, GY = gridDim.y;
    const int nwg = GX * GY;
    const int bid = blockIdx.x + GX * blockIdx.y;
    const int q8 = nwg >> 3, r8 = nwg & 7;
    const int xcd = bid & 7, sl = bid >> 3;
    const int t = (xcd < r8) ? (xcd * (q8 + 1) + sl)
                             : (r8 * (q8 + 1) + (xcd - r8) * q8 + sl);
    const int m0 = (t % GY) * 128, n0 = (t / GY) * 128;

    const int tid = threadIdx.x;
    const int lane = tid & 63, wave = tid >> 6;
    const int wr = (wave >> 1) * 64, wc = (wave & 1) * 64;
    const int lrow = lane & 15, lk = lane >> 4;
    const int cswz8 = (lk ^ ((lrow >> 1) & 3)) << 3;

    const int rA0 = wave * 16 + (lane >> 2);
    const int rA1 = rA0 + 64;
    const int sc0 = ((lane & 3) ^ ((rA0 >> 1) & 3)) * 8;
    const int sc1 = ((lane & 3) ^ ((rA1 >> 1) & 3)) * 8;
    const long gA0 = (long)(m0 + rA0) * lda + sc0;
    const long gA1 = (long)(m0 + rA1) * lda + sc1;
    long gB0 = 0, gB1 = 0;
    if (BF == 1) {
        gB0 = (long)(n0 + rA0) * ldb + sc0;
        gB1 = (long)(n0 + rA1) * ldb + sc1;
    }
    const int lw0 = wave * 512, lw1 = wave * 512 + 2048;

    const int brow = tid & 127;
    const int bkc0 = (tid >> 7) * 8;
    const int bkc1 = bkc0 + 16;
    const int bw0 = brow * 32 + (((bkc0 >> 3) ^ ((brow >> 1) & 3)) << 3);
    const int bw1 = brow * 32 + (((bkc1 >> 3) ^ ((brow >> 1) & 3)) << 3);
    const float* bpr = (BF == 0) ? Bf + (long)(n0 + brow) * ldb : nullptr;

    f32x4 acc[4][4];
#pragma unroll
    for (int i = 0; i < 4; i++)
#pragma unroll
        for (int j = 0; j < 4; j++) acc[i][j] = (f32x4){0.f, 0.f, 0.f, 0.f};

    float4 rb0a, rb0b, rb1a, rb1b;

    {
        short* S = &SH[0][0];
        gld_lds16(Ahi + gA0 + kb, S + lw0);
        gld_lds16(Ahi + gA1 + kb, S + lw1);
        gld_lds16(Alo + gA0 + kb, S + 4096 + lw0);
        gld_lds16(Alo + gA1 + kb, S + 4096 + lw1);
        if constexpr (BF == 1) {
            gld_lds16(Bhi + gB0 + kb, S + 8192 + lw0);
            gld_lds16(Bhi + gB1 + kb, S + 8192 + lw1);
            gld_lds16(Blo + gB0 + kb, S + 12288 + lw0);
            gld_lds16(Blo + gB1 + kb, S + 12288 + lw1);
        } else {
            rb0a = *(const float4*)(bpr + kb + bkc0);
            rb0b = *(const float4*)(bpr + kb + bkc0 + 4);
            rb1a = *(const float4*)(bpr + kb + bkc1);
            rb1b = *(const float4*)(bpr + kb + bkc1 + 4);
            s16x8 h, l;
            split8(rb0a, rb0b, h, l);
            *(s16x8*)&S[8192 + bw0] = h;
            *(s16x8*)&S[12288 + bw0] = l;
            split8(rb1a, rb1b, h, l);
            *(s16x8*)&S[8192 + bw1] = h;
            *(s16x8*)&S[12288 + bw1] = l;
        }
    }
    __syncthreads();

    int cur = 0;
    const int kend = kb + Kc;
    for (int k0 = kb; k0 < kend; k0 += 32) {
        const int kn = k0 + 32;
        const bool nx = (kn < kend);
        short* SN = &SH[cur ^ 1][0];
        if (nx) {
            gld_lds16(Ahi + gA0 + kn, SN + lw0);
            gld_lds16(Ahi + gA1 + kn, SN + lw1);
            gld_lds16(Alo + gA0 + kn, SN + 4096 + lw0);
            gld_lds16(Alo + gA1 + kn, SN + 4096 + lw1);
            if constexpr (BF == 1) {
                gld_lds16(Bhi + gB0 + kn, SN + 8192 + lw0);
                gld_lds16(Bhi + gB1 + kn, SN + 8192 + lw1);
                gld_lds16(Blo + gB0 + kn, SN + 12288 + lw0);
                gld_lds16(Blo + gB1 + kn, SN + 12288 + lw1);
            } else {
                rb0a = *(const float4*)(bpr + kn + bkc0);
                rb0b = *(const float4*)(bpr + kn + bkc0 + 4);
                rb1a = *(const float4*)(bpr + kn + bkc1);
                rb1b = *(const float4*)(bpr + kn + bkc1 + 4);
            }
        }
        const short* S = &SH[cur][0];
        s16x8 ah[4], al[4];
#pragma unroll
        for (int m = 0; m < 4; m++) {
            const int idx = (wr + m * 16 + lrow) * 32 + cswz8;
            ah[m] = *(const s16x8*)&S[idx];
            al[m] = *(const s16x8*)&S[4096 + idx];
        }
#pragma unroll
        for (int n = 0; n < 4; n++) {
            const int idx = (wc + n * 16 + lrow) * 32 + cswz8;
            const s16x8 bh = *(const s16x8*)&S[8192 + idx];
            const s16x8 bl = *(const s16x8*)&S[12288 + idx];
#pragma unroll
            for (int m = 0; m < 4; m++) {
                acc[m][n] = __builtin_amdgcn_mfma_f32_16x16x32_bf16(ah[m], bh, acc[m][n], 0, 0, 0);
                acc[m][n] = __builtin_amdgcn_mfma_f32_16x16x32_bf16(ah[m], bl, acc[m][n], 0, 0, 0);
                acc[m][n] = __builtin_amdgcn_mfma_f32_16x16x32_bf16(al[m], bh, acc[m][n], 0, 0, 0);
            }
        }
        if (BF == 0 && nx) {
            s16x8 h, l;
            split8(rb0a, rb0b, h, l);
            *(s16x8*)&SN[8192 + bw0] = h;
            *(s16x8*)&SN[12288 + bw0] = l;
            split8(rb1a, rb1b, h, l);
            *(s16x8*)&SN[8192 + bw1] = h;
            *(s16x8*)&SN[12288 + bw1] = l;
        }
        __syncthreads();
        cur ^= 1;
    }
#pragma unroll
    for (int n = 0; n < 4; n++) {
        const int col = n0 + wc + n * 16 + lrow;
        const float bv = (SK == 1 && bias) ? bias[col] : 0.f;
#pragma unroll
        for (int m = 0; m < 4; m++) {
            const int row = m0 + wr + m * 16 + lk * 4;
            if (SK > 1) {
#pragma unroll
                for (int r = 0; r < 4; r++)
                    Cf[cofs + (long)(row + r) * ldc + col] = acc[m][n][r] * alpha;
            } else if constexpr (EPI == 0) {
#pragma unroll
                for (int r = 0; r < 4; r++) {
                    float v = acc[m][n][r] * alpha + bv;
                    if (RELU) v = fmaxf(v, 0.f);
                    Cf[cofs + (long)(row + r) * ldc + col] = v;
                }
            } else if constexpr (EPI == 1) {
#pragma unroll
                for (int r = 0; r < 4; r++) {
                    float v = acc[m][n][r] * alpha + bv;
                    sh2 p = splitf(v);
                    Chi[cofs + (long)(row + r) * ldc + col] = p.hi;
                    Clo[cofs + (long)(row + r) * ldc + col] = p.lo;
                }
            } else {
                if (n0 < 8192) {
#pragma unroll
                    for (int r = 0; r < 4; r++) {
                        float v = acc[m][n][r] + bv;
                        sh2 p = splitf(v);
                        Chi[(long)(row + r) * ldc + col] = p.hi;
                        Clo[(long)(row + r) * ldc + col] = p.lo;
                    }
                } else {
                    s16x4 h4, l4;
#pragma unroll
                    for (int r = 0; r < 4; r++) {
                        float v = acc[m][n][r] + bv;
                        sh2 p = splitf(v);
                        h4[r] = p.hi; l4[r] = p.lo;
                    }
                    const long tof = (long)(col - 8192) * ldT + row;
                    *(s16x4*)&Thi[tof] = h4;
                    *(s16x4*)&Tlo[tof] = l4;
                }
            }
        }
    }
}

// ============================================================================
// 256x256-tile split-bf16 GEMM, BF=0 (fp32 B), EPI=2 (in-proj), 8 waves,
// 128 KB dbuf LDS (1 block/CU). Per-wave 64x128 output -> LDS bytes/MFMA
// 341 vs 512 for the 128^2 tile (this kernel is LDS-BW-bound). M padded to
// 256 multiple; rows >= Mreal guarded at write (garbage-in discarded).
// ============================================================================
__global__ __launch_bounds__(512, 2) void mfma_gemm256(
    const short* __restrict__ Ahi, const short* __restrict__ Alo, int lda,
    const float* __restrict__ Bf, int ldb,
    short* __restrict__ Chi, short* __restrict__ Clo,
    short* __restrict__ Thi, short* __restrict__ Tlo, int ldc, int ldT,
    int K, int Mreal, const float* __restrict__ bias)
{
    // per buffer (shorts): Ah[0..8191] Al[8192..] Bh[16384..] Bl[24576..]
    __shared__ short SH[2][32768];

    const int GX = gridDim.x, GY = gridDim.y;
    const int nwg = GX * GY;
    const int bid = blockIdx.x + GX * blockIdx.y;
    const int q8 = nwg >> 3, r8 = nwg & 7;
    const int xcd = bid & 7, sl = bid >> 3;
    const int t = (xcd < r8) ? (xcd * (q8 + 1) + sl)
                             : (r8 * (q8 + 1) + (xcd - r8) * q8 + sl);
    const int m0 = (t % GY) * 256, n0 = (t / GY) * 256;

    const int tid = threadIdx.x;
    const int lane = tid & 63, wave = tid >> 6;
    const int wr = (wave >> 1) * 64, wc = (wave & 1) * 128;
    const int lrow = lane & 15, lk = lane >> 4;
    const int cswz8 = (lk ^ ((lrow >> 1) & 3)) << 3;

    // A staging: per array 16 KB = 8 waves x 2 gload_lds calls (16 rows/call)
    const int rA0 = wave * 32 + (lane >> 2);
    const int rA1 = rA0 + 16;
    const int sc0 = ((lane & 3) ^ ((rA0 >> 1) & 3)) * 8;
    const int sc1 = ((lane & 3) ^ ((rA1 >> 1) & 3)) * 8;
    const long gA0 = (long)(m0 + rA0) * lda + sc0;
    const long gA1 = (long)(m0 + rA1) * lda + sc1;
    const int lw0 = wave * 1024, lw1 = wave * 1024 + 512;

    // B staging: thread t -> row t&255, fp32 cols bk..bk+15 (2 swizzled chunks)
    const int brow = tid & 255;
    const int bk = (tid >> 8) * 16;
    const int bw0 = brow * 32 + ((((bk >> 3) + 0) ^ ((brow >> 1) & 3)) << 3);
    const int bw1 = brow * 32 + ((((bk >> 3) + 1) ^ ((brow >> 1) & 3)) << 3);
    const float* bpr = Bf + (long)(n0 + brow) * ldb + bk;

    f32x4 acc[4][8];
#pragma unroll
    for (int i = 0; i < 4; i++)
#pragma unroll
        for (int j = 0; j < 8; j++) acc[i][j] = (f32x4){0.f, 0.f, 0.f, 0.f};

    float4 rb0, rb1, rb2, rb3;

    // prologue: stage tile 0
    {
        short* S = &SH[0][0];
        gld_lds16(Ahi + gA0, S + lw0);
        gld_lds16(Ahi + gA1, S + lw1);
        gld_lds16(Alo + gA0, S + 8192 + lw0);
        gld_lds16(Alo + gA1, S + 8192 + lw1);
        rb0 = *(const float4*)(bpr + 0);
        rb1 = *(const float4*)(bpr + 4);
        rb2 = *(const float4*)(bpr + 8);
        rb3 = *(const float4*)(bpr + 12);
        s16x8 h, l;
        split8(rb0, rb1, h, l);
        *(s16x8*)&S[16384 + bw0] = h;
        *(s16x8*)&S[24576 + bw0] = l;
        split8(rb2, rb3, h, l);
        *(s16x8*)&S[16384 + bw1] = h;
        *(s16x8*)&S[24576 + bw1] = l;
    }
    __syncthreads();

    int cur = 0;
    for (int k0 = 0; k0 < K; k0 += 32) {
        const int kn = k0 + 32;
        const bool nx = (kn < K);
        short* SN = &SH[cur ^ 1][0];
        if (nx) {
            gld_lds16(Ahi + gA0 + kn, SN + lw0);
            gld_lds16(Ahi + gA1 + kn, SN + lw1);
            gld_lds16(Alo + gA0 + kn, SN + 8192 + lw0);
            gld_lds16(Alo + gA1 + kn, SN + 8192 + lw1);
            rb0 = *(const float4*)(bpr + kn + 0);
            rb1 = *(const float4*)(bpr + kn + 4);
            rb2 = *(const float4*)(bpr + kn + 8);
            rb3 = *(const float4*)(bpr + kn + 12);
        }
        const short* S = &SH[cur][0];
        s16x8 ah[4], al[4];
#pragma unroll
        for (int m = 0; m < 4; m++) {
            const int idx = (wr + m * 16 + lrow) * 32 + cswz8;
            ah[m] = *(const s16x8*)&S[idx];
            al[m] = *(const s16x8*)&S[8192 + idx];
        }
#pragma unroll
        for (int n = 0; n < 8; n++) {
            const int idx = (wc + n * 16 + lrow) * 32 + cswz8;
            const s16x8 bh = *(const s16x8*)&S[16384 + idx];
            const s16x8 bl = *(const s16x8*)&S[24576 + idx];
#pragma unroll
            for (int m = 0; m < 4; m++) {
                acc[m][n] = __builtin_amdgcn_mfma_f32_16x16x32_bf16(ah[m], bh, acc[m][n], 0, 0, 0);
                acc[m][n] = __builtin_amdgcn_mfma_f32_16x16x32_bf16(ah[m], bl, acc[m][n], 0, 0, 0);
                acc[m][n] = __builtin_amdgcn_mfma_f32_16x16x32_bf16(al[m], bh, acc[m][n], 0, 0, 0);
            }
        }
        if (nx) {
            s16x8 h, l;
            split8(rb0, rb1, h, l);
            *(s16x8*)&SN[16384 + bw0] = h;
            *(s16x8*)&SN[24576 + bw0] = l;
            split8(rb2, rb3, h, l);
            *(s16x8*)&SN[16384 + bw1] = h;
            *(s16x8*)&SN[24576 + bw1] = l;
        }
        __syncthreads();
        cur ^= 1;
    }
    // epilogue (EPI=2): q/k split rows; v transposed; guard rows >= Mreal
#pragma unroll
    for (int n = 0; n < 8; n++) {
        const int col = n0 + wc + n * 16 + lrow;
        const float bv = bias[col];
#pragma unroll
        for (int m = 0; m < 4; m++) {
            const int row = m0 + wr + m * 16 + lk * 4;
            if (row < Mreal) {
                if (n0 < 8192) {
#pragma unroll
                    for (int r = 0; r < 4; r++) {
                        float v = acc[m][n][r] + bv;
                        sh2 p = splitf(v);
                        Chi[(long)(row + r) * ldc + col] = p.hi;
                        Clo[(long)(row + r) * ldc + col] = p.lo;
                    }
                } else {
                    s16x4 h4, l4;
#pragma unroll
                    for (int r = 0; r < 4; r++) {
                        float v = acc[m][n][r] + bv;
                        sh2 p = splitf(v);
                        h4[r] = p.hi; l4[r] = p.lo;
                    }
                    const long tof = (long)(col - 8192) * ldT + row;
                    *(s16x4*)&Thi[tof] = h4;
                    *(s16x4*)&Tlo[tof] = l4;
                }
            }
        }
    }
}

// ============================================================================
// split-K reducer: sums SK partials (zstride apart) in fixed order + epilogue
// ============================================================================
template<int EPI, bool RELU>
__global__ __launch_bounds__(256) void reduce_k(
    const float* __restrict__ P, long zstride, int SK, int total,
    int Ninner, int ldc, int colstep,
    float* __restrict__ Cf, short* __restrict__ Chi, short* __restrict__ Clo,
    const float* __restrict__ bias)
{
    const int bz = blockIdx.y;
    const long pbase = (long)bz * SK * zstride;
    const int e = (blockIdx.x * 256 + threadIdx.x) * 4;
    if (e >= total) return;
    const float* p = P + pbase + e;
    float4 s = *(const float4*)p;
    for (int k = 1; k < SK; k++) {
        float4 tv = *(const float4*)(p + (long)k * zstride);
        s.x += tv.x; s.y += tv.y; s.z += tv.z; s.w += tv.w;
    }
    const int r = e / Ninner, c = e % Ninner;
    const int col0 = colstep * bz + c;
    const long ob = (long)r * ldc + col0;
    float v[4] = {s.x, s.y, s.z, s.w};
#pragma unroll
    for (int j = 0; j < 4; j++) {
        float x = v[j] + (bias ? bias[col0 + j] : 0.f);
        if (RELU) x = fmaxf(x, 0.f);
        if constexpr (EPI == 0) {
            Cf[ob + j] = x;
        } else {
            sh2 pp = splitf(x);
            Chi[ob + j] = pp.hi;
            Clo[ob + j] = pp.lo;
        }
    }
}

// split rows: dhi/dlo[r,:4096] = split(src[map? map[r] : r, :4096])
__global__ __launch_bounds__(256) void split_rows(
    const float* __restrict__ src, const int* __restrict__ map,
    short* __restrict__ dhi, short* __restrict__ dlo)
{
    const int r = blockIdx.x;
    const int sr = map ? map[r] : r;
    const float4* s = (const float4*)(src + (long)sr * 4096);
    const long db = (long)r * 4096;
    for (int i = threadIdx.x; i < 1024; i += 256) {
        float4 f = s[i];
        s16x4 h, l;
        sh2 p;
        p = splitf(f.x); h[0] = p.hi; l[0] = p.lo;
        p = splitf(f.y); h[1] = p.hi; l[1] = p.lo;
        p = splitf(f.z); h[2] = p.hi; l[2] = p.lo;
        p = splitf(f.w); h[3] = p.hi; l[3] = p.lo;
        *(s16x4*)&dhi[db + i * 4] = h;
        *(s16x4*)&dlo[db + i * 4] = l;
    }
}

// row softmax (jax.nn.softmax) -> split probs
__global__ __launch_bounds__(256) void softmax_split(
    const float* __restrict__ x, short* __restrict__ phi, short* __restrict__ plo,
    int cols)
{
    const long rb = (long)blockIdx.x * cols;
    const float4* xr = (const float4*)(x + rb);
    const int t = threadIdx.x;
    const int n4 = cols >> 2;
    __shared__ float red[256];
    float mx = -INFINITY;
    for (int i = t; i < n4; i += 256) {
        float4 f = xr[i];
        mx = fmaxf(fmaxf(mx, fmaxf(f.x, f.y)), fmaxf(f.z, f.w));
    }
    red[t] = mx; __syncthreads();
    for (int off = 128; off; off >>= 1) { if (t < off) red[t] = fmaxf(red[t], red[t + off]); __syncthreads(); }
    mx = red[0]; __syncthreads();
    float4 ebuf[2];
    float s = 0.f;
    int nb = 0;
    for (int i = t; i < n4; i += 256) {
        float4 f = xr[i];
        f.x = expf(f.x - mx); f.y = expf(f.y - mx); f.z = expf(f.z - mx); f.w = expf(f.w - mx);
        ebuf[nb++] = f;
        s += f.x + f.y + f.z + f.w;
    }
    red[t] = s; __syncthreads();
    for (int off = 128; off; off >>= 1) { if (t < off) red[t] += red[t + off]; __syncthreads(); }
    s = red[0];
    nb = 0;
    for (int i = t; i < n4; i += 256) {
        float4 f = ebuf[nb++];
        f.x /= s; f.y /= s; f.z /= s; f.w /= s;
        s16x4 h, l;
        sh2 p;
        p = splitf(f.x); h[0] = p.hi; l[0] = p.lo;
        p = splitf(f.y); h[1] = p.hi; l[1] = p.lo;
        p = splitf(f.z); h[2] = p.hi; l[2] = p.lo;
        p = splitf(f.w); h[3] = p.hi; l[3] = p.lo;
        *(s16x4*)&phi[rb + i * 4] = h;
        *(s16x4*)&plo[rb + i * 4] = l;
    }
}

// logits[r] = H[r,:2048] . w2 + b2
__global__ __launch_bounds__(256) void gemv_kernel(
    const float* __restrict__ H, const float* __restrict__ w2,
    const float* __restrict__ b2, float* __restrict__ logits)
{
    const int r = blockIdx.x, t = threadIdx.x;
    const float* row = H + (long)r * 2048;
    float s = 0.f;
    for (int c = t; c < 2048; c += 256) s += row[c] * w2[c];
    __shared__ float red[256];
    red[t] = s; __syncthreads();
    for (int off = 128; off; off >>= 1) { if (t < off) red[t] += red[t + off]; __syncthreads(); }
    if (!t) logits[r] = red[0] + b2[0];
}

// exact lax.top_k: bitonic full sort, desc by val, ties idx asc. blockDim==n.
__global__ void topk_kernel(const float* __restrict__ vals, int n, int k, int* __restrict__ out)
{
    __shared__ float sv[1024];
    __shared__ int   si[1024];
    const int t = threadIdx.x;
    sv[t] = vals[t]; si[t] = t;
    for (int size = 2; size <= n; size <<= 1) {
        for (int stride = size >> 1; stride > 0; stride >>= 1) {
            __syncthreads();
            const int j = t ^ stride;
            if (j > t) {
                float av = sv[t], bv = sv[j];
                int ai = si[t], bi = si[j];
                const bool before = (av > bv) || (av == bv && ai < bi);
                const bool dir = ((t & size) == 0);
                if (dir ? !before : before) { sv[t] = bv; si[t] = bi; sv[j] = av; si[j] = ai; }
            }
        }
    }
    __syncthreads();
    if (t < k) out[t] = si[t];
}

__global__ void gather_sel_kernel(const int* __restrict__ idx1, const int* __restrict__ idx2,
                                  int* __restrict__ selidx)
{
    const int t = threadIdx.x;
    if (t < 256) selidx[t] = idx1[idx2[t]];
}

// complement of 256 selected indices within [0,1024), ascending
__global__ void complement_kernel(const int* __restrict__ selidx, int* __restrict__ remidx)
{
    __shared__ int mask[1024];
    __shared__ int scan[1024];
    const int t = threadIdx.x;
    mask[t] = 0;
    __syncthreads();
    if (t < 256) mask[selidx[t]] = 1;
    __syncthreads();
    const int keep = 1 - mask[t];
    scan[t] = keep;
    __syncthreads();
    for (int off = 1; off < 1024; off <<= 1) {
        int v = scan[t];
        if (t >= off) v += scan[t - off];
        __syncthreads();
        scan[t] = v;
        __syncthreads();
    }
    if (keep) remidx[scan[t] - 1] = t;
}

__global__ __launch_bounds__(256) void gather_rows_kernel(
    float* __restrict__ dst, const float* __restrict__ src,
    const int* __restrict__ map, int ncols)
{
    const int r = blockIdx.x;
    const int sr = map[r];
    const float4* s = (const float4*)(src + (long)sr * ncols);
    float4* d = (float4*)(dst + (long)r * ncols);
    for (int i = threadIdx.x; i < ncols / 4; i += 256) d[i] = s[i];
}

__global__ __launch_bounds__(256) void rownorm_kernel(
    const float* __restrict__ x, float* __restrict__ out)
{
    const int r = blockIdx.x, t = threadIdx.x;
    const float* row = x + (long)r * 4096;
    float s = 0.f;
    for (int c = t; c < 4096; c += 256) { float v = row[c]; s += v * v; }
    __shared__ float red[256];
    red[t] = s; __syncthreads();
    for (int off = 128; off; off >>= 1) { if (t < off) red[t] += red[t + off]; __syncthreads(); }
    if (!t) out[r] = sqrtf(red[0]);
}

__global__ __launch_bounds__(256) void argmax_kernel(
    const float* __restrict__ S, const float* __restrict__ nr,
    const float* __restrict__ ns, int* __restrict__ best)
{
    const int r = blockIdx.x, t = threadIdx.x;
    float v = S[(long)r * 256 + t] / fmaxf(nr[r] * ns[t], 1e-8f);
    __shared__ float bv[256];
    __shared__ int bi[256];
    bv[t] = v; bi[t] = t; __syncthreads();
    for (int off = 128; off; off >>= 1) {
        if (t < off) {
            float ov = bv[t + off]; int oi = bi[t + off];
            if (ov > bv[t] || (ov == bv[t] && oi < bi[t])) { bv[t] = ov; bi[t] = oi; }
        }
        __syncthreads();
    }
    if (!t) best[r] = bi[0];
}

__global__ __launch_bounds__(256) void merge_kernel(
    const float* __restrict__ selb, const float* __restrict__ rem,
    const int* __restrict__ best, const float* __restrict__ nr,
    const float* __restrict__ ns, float* __restrict__ out)
{
    const int j = blockIdx.x, t = threadIdx.x;
    __shared__ int sbest[768];
    __shared__ float snr[768];
    __shared__ float red[256];
    for (int i = t; i < 768; i += 256) { sbest[i] = best[i]; snr[i] = nr[i]; }
    __syncthreads();
    float acc[16];
#pragma unroll
    for (int d = 0; d < 16; d++) acc[d] = 0.f;
    int cnt = 0; float smax = 0.f;
    const int base = t * 16;
    for (int i = 0; i < 768; i++) {
        if (sbest[i] == j) {
            cnt++;
            smax = fmaxf(smax, snr[i]);
            const float* rp = rem + (long)i * 4096 + base;
#pragma unroll
            for (int d = 0; d < 16; d += 4) {
                float4 x4 = *(const float4*)(rp + d);
                acc[d] += x4.x; acc[d + 1] += x4.y; acc[d + 2] += x4.z; acc[d + 3] += x4.w;
            }
        }
    }
    const float* sp = selb + (long)j * 4096 + base;
    float mean[16]; float ss = 0.f;
    const float denom = (float)(cnt + 1);
#pragma unroll
    for (int d = 0; d < 16; d++) { mean[d] = (sp[d] + acc[d]) / denom; ss += mean[d] * mean[d]; }
    red[t] = ss; __syncthreads();
    for (int off = 128; off; off >>= 1) { if (t < off) red[t] += red[t + off]; __syncthreads(); }
    const float nm = sqrtf(red[0]);
    const float mx = fmaxf(ns[j], cnt > 0 ? smax : 0.f);
    float* op = out + (long)j * 4096 + base;
#pragma unroll
    for (int d = 0; d < 16; d++) op[d] = (cnt > 0) ? (mean[d] / nm) * mx : sp[d];
}

// ============================================================================
// host orchestration
// ============================================================================
extern "C" void kernel_launch(void* const* d_in, const int* in_sizes, int n_in,
                              void* d_out, int out_size, void* d_ws, size_t ws_size,
                              hipStream_t stream)
{
    const float* vf   = (const float*)d_in[0];   // 1024 x 4096
    const float* te   = (const float*)d_in[1];   // 128 x 4096
    const float* inw  = (const float*)d_in[3];   // 4 x 12288 x 4096
    const float* inb  = (const float*)d_in[4];   // 4 x 12288
    const float* outw = (const float*)d_in[5];   // 4 x 4096 x 4096
    const float* outb = (const float*)d_in[6];   // 4 x 4096
    const float* w1   = (const float*)d_in[7];   // 2 x 2048 x 4096
    const float* b1   = (const float*)d_in[8];   // 2 x 2048
    const float* w2   = (const float*)d_in[9];   // 2 x 2048
    const float* b2   = (const float*)d_in[10];  // 2
    float* out = (float*)d_out;                  // 256 x 4096
    char* base = (char*)d_ws;

    char* qkR = base;                 // 37,748,736 : qk split / probs / partials
    char* vTR = base + 37748736;      // 18,874,368 : vT split
    char* scR = vTR + 18874368;       // 37,748,736 : comb/scor/o/g/hbuf/final
    float* smalls = (float*)(scR + 37748736);    // 32 KiB of small buffers

    short* qkhi = (short*)qkR;
    short* qklo = (short*)(qkR + 18874368);
    short* vThi = (short*)vTR;
    short* vTlo = (short*)(vTR + 9437184);
    float* hbuf = (float*)scR;

    float* logits = smalls;
    float* nr     = smalls + 1024;
    float* ns     = smalls + 1792;
    int* idx1   = (int*)(smalls + 2048);
    int* idx2   = (int*)(smalls + 2560);
    int* selidx = (int*)(smalls + 2816);
    int* remidx = (int*)(smalls + 3072);
    int* best   = (int*)(smalls + 3840);

    const float scl = (float)(1.0 / sqrt(512.0));

    for (int m = 0; m < 2; m++) {
        const int Mq  = m ? 512 : 1024;
        const int Mkv = m ? 640 : 1152;
        const float* Wqkv = inw + (size_t)(2 * m) * 12288 * 4096;
        const float* bqkv = inb + (size_t)(2 * m) * 12288;
        const float* ow = outw + (size_t)(2 * m) * 4096 * 4096;
        const float* ob = outb + (size_t)(2 * m) * 4096;

        // ---- comb split (A of in-proj), lives at scR head ----
        short* chi = (short*)scR;
        short* clo = (short*)(scR + (size_t)Mkv * 4096 * 2);
        if (m == 0) {
            split_rows<<<1024, 256, 0, stream>>>(vf, nullptr, chi, clo);
            split_rows<<<128, 256, 0, stream>>>(te, nullptr,
                chi + (size_t)1024 * 4096, clo + (size_t)1024 * 4096);
        } else {
            split_rows<<<512, 256, 0, stream>>>(vf, idx1, chi, clo);
            split_rows<<<128, 256, 0, stream>>>(te, nullptr,
                chi + (size_t)512 * 4096, clo + (size_t)512 * 4096);
        }
        // ---- fused in-proj: q,k -> qk split; v -> vT split (transposed) ----
        if (m == 0) {
            // 256^2 tile, M padded 1152->1280 (guarded), 240 blocks @ 1/CU
            mfma_gemm256<<<dim3(48, 5, 1), 512, 0, stream>>>(
                chi, clo, 4096, Wqkv, 4096, qkhi, qklo, vThi, vTlo,
                8192, 1152, 4096, 1152, bqkv);
        } else {
            mfma_gemm<0, 2, false><<<dim3(96, Mkv / 128, 1), 256, 0, stream>>>(
                chi, clo, 4096, 0, Wqkv, nullptr, nullptr, 4096, 0,
                nullptr, qkhi, qklo, vThi, vTlo, 8192, 1152, 0, 4096, 1, 1.f, bqkv);
        }
        // ---- scores[h] = scl * q_h @ k_h^T (fp32) ----
        float* scor = (float*)(m ? (scR + 10485760) : scR);
        mfma_gemm<1, 0, false><<<dim3(Mkv / 128, Mq / 128, 8), 256, 0, stream>>>(
            qkhi, qklo, 8192, 512, nullptr, qkhi + 4096, qklo + 4096, 8192, 512,
            scor, nullptr, nullptr, nullptr, nullptr, Mkv, 0, (long)Mq * Mkv,
            512, 1, scl, nullptr);
        // ---- softmax -> split probs ----
        short* phi = (short*)qkR;
        short* plo = (short*)(qkR + (size_t)8 * Mq * Mkv * 2);
        softmax_split<<<8 * Mq, 256, 0, stream>>>(scor, phi, plo, Mkv);
        // ---- PV: o = probs @ vT^T -> obuf split ----
        short* ohi = (short*)scR;
        short* olo = (short*)(scR + (size_t)Mq * 4096 * 2);
        if (m == 0) {
            mfma_gemm<1, 1, false><<<dim3(4, 8, 8), 256, 0, stream>>>(
                phi, plo, Mkv, (long)Mq * Mkv, nullptr, vThi, vTlo, 1152, 512L * 1152,
                nullptr, ohi, olo, nullptr, nullptr, 4096, 0, 512, Mkv, 1, 1.f, nullptr);
        } else {
            float* Ppv = (float*)(qkR + 20971520);
            mfma_gemm<1, 0, false><<<dim3(4, 4, 16), 256, 0, stream>>>(
                phi, plo, Mkv, (long)Mq * Mkv, nullptr, vThi, vTlo, 1152, 512L * 1152,
                Ppv, nullptr, nullptr, nullptr, nullptr, 512, 0, 262144,
                Mkv, 2, 1.f, nullptr);
            reduce_k<1, false><<<dim3(256, 8), 256, 0, stream>>>(
                Ppv, 262144, 2, 262144, 512, 4096, 512, nullptr, ohi, olo, nullptr);
        }
        // ---- out-proj: g = o @ ow^T + ob -> gbuf split (split-K=2) ----
        short* ghi = (short*)(scR + (size_t)Mq * 4096 * 4);
        short* glo = (short*)(scR + (size_t)Mq * 4096 * 6);
        {
            float* Pg = (float*)qkR;
            const long zst = (long)Mq * 4096;
            mfma_gemm<0, 0, false><<<dim3(32, Mq / 128, 2), 256, 0, stream>>>(
                ohi, olo, 4096, 0, ow, nullptr, nullptr, 4096, 0,
                Pg, nullptr, nullptr, nullptr, nullptr, 4096, 0, zst,
                4096, 2, 1.f, nullptr);
            reduce_k<1, false><<<dim3((int)(zst / 1024), 1), 256, 0, stream>>>(
                Pg, zst, 2, (int)zst, 4096, 4096, 0, nullptr, ghi, glo, ob);
        }
        // ---- MLP: h = relu(g @ w1^T + b1) -> hbuf fp32 (split-K=4) ----
        {
            float* Pm = (float*)(qkR + 8388608);
            const long zst = (long)Mq * 2048;
            mfma_gemm<0, 0, false><<<dim3(16, Mq / 128, 4), 256, 0, stream>>>(
                ghi, glo, 4096, 0, w1 + (size_t)m * 2048 * 4096, nullptr, nullptr, 4096, 0,
                Pm, nullptr, nullptr, nullptr, nullptr, 2048, 0, zst,
                4096, 4, 1.f, nullptr);
            reduce_k<0, true><<<dim3((int)(zst / 1024), 1), 256, 0, stream>>>(
                Pm, zst, 4, (int)zst, 2048, 2048, 0, hbuf, nullptr, nullptr,
                b1 + (size_t)m * 2048);
        }
        gemv_kernel<<<Mq, 256, 0, stream>>>(hbuf, w2 + (size_t)m * 2048, b2 + m, logits);
        if (m == 0) topk_kernel<<<1, 1024, 0, stream>>>(logits, 1024, 512, idx1);
        else        topk_kernel<<<1, 512, 0, stream>>>(logits, 512, 256, idx2);
    }

    // ---- merge phase ----
    short* remhi = (short*)scR;
    short* remlo = (short*)(scR + 6291456);
    short* selhi = (short*)(scR + 12582912);
    short* sello = (short*)(scR + 14680064);
    float* rem_f = (float*)(scR + 16777216);
    float* sel_f = (float*)(scR + 29360128);
    float* Smat  = (float*)(scR + 33554432);

    gather_sel_kernel<<<1, 256, 0, stream>>>(idx1, idx2, selidx);
    complement_kernel<<<1, 1024, 0, stream>>>(selidx, remidx);
    split_rows<<<768, 256, 0, stream>>>(vf, remidx, remhi, remlo);
    split_rows<<<256, 256, 0, stream>>>(vf, selidx, selhi, sello);
    gather_rows_kernel<<<768, 256, 0, stream>>>(rem_f, vf, remidx, 4096);
    gather_rows_kernel<<<256, 256, 0, stream>>>(sel_f, vf, selidx, 4096);
    rownorm_kernel<<<768, 256, 0, stream>>>(rem_f, nr);
    rownorm_kernel<<<256, 256, 0, stream>>>(sel_f, ns);
    // S = rem @ selb^T (split-K=8)
    {
        float* Ps = (float*)qkR;
        mfma_gemm<1, 0, false><<<dim3(2, 6, 8), 256, 0, stream>>>(
            remhi, remlo, 4096, 0, nullptr, selhi, sello, 4096, 0,
            Ps, nullptr, nullptr, nullptr, nullptr, 256, 0, 196608,
            4096, 8, 1.f, nullptr);
        reduce_k<0, false><<<dim3(192, 1), 256, 0, stream>>>(
            Ps, 196608, 8, 196608, 256, 256, 0, Smat, nullptr, nullptr, nullptr);
    }
    argmax_kernel<<<768, 256, 0, stream>>>(Smat, nr, ns, best);
    merge_kernel<<<256, 256, 0, stream>>>(sel_f, rem_f, best, nr, ns, out);
}